// Round 1
// baseline (596.576 us; speedup 1.0000x reference)
//
#include <hip/hip_runtime.h>
#include <math.h>

// ---------------------------------------------------------------------------
// MultiGCN: 3-layer GCN, N=50000, E=800000, D=H=128, C=40, f32.
// Strategy: build CSR by dst once per call (atomic count + block scan + fill),
// then per layer: dense GEMM (W staged in LDS, 4x4 register tile) followed by
// a gather-based aggregation (one wave per node, no atomics) with fused
// bias + ReLU + residual (layers 1,2) or bias + log_softmax (layer 3).
// ---------------------------------------------------------------------------

#define HD 128   // hidden / input feature dim
#define NC 40    // classes

__device__ __forceinline__ float4 fma4(float s, float4 w, float4 a) {
  a.x = fmaf(s, w.x, a.x);
  a.y = fmaf(s, w.y, a.y);
  a.z = fmaf(s, w.z, a.z);
  a.w = fmaf(s, w.w, a.w);
  return a;
}

// ---- CSR build ------------------------------------------------------------

__global__ void k_init(int* __restrict__ cnt, int* __restrict__ cursor, int n) {
  int i = blockIdx.x * 256 + threadIdx.x;
  if (i < n) { cnt[i] = 0; cursor[i] = 0; }
}

__global__ void k_count(const int* __restrict__ dst, int* __restrict__ cnt, int E) {
  int e = blockIdx.x * 256 + threadIdx.x;
  if (e < E) atomicAdd(&cnt[dst[e]], 1);
}

__global__ void k_dinv(const int* __restrict__ cnt, float* __restrict__ dinv, int n) {
  int i = blockIdx.x * 256 + threadIdx.x;
  if (i < n) dinv[i] = rsqrtf((float)(cnt[i] + 1));  // +1 self loop
}

// single-block exclusive scan (n up to ~1M is fine; here n=50000)
__global__ __launch_bounds__(1024) void k_scan(const int* __restrict__ cnt,
                                               int* __restrict__ row_start,
                                               int n, int E) {
  __shared__ int sh[1024];
  __shared__ int carry_sh;
  const int tid = threadIdx.x;
  if (tid == 0) carry_sh = 0;
  __syncthreads();
  for (int base = 0; base < n; base += 1024) {
    int i = base + tid;
    int v = (i < n) ? cnt[i] : 0;
    sh[tid] = v;
    __syncthreads();
    for (int off = 1; off < 1024; off <<= 1) {
      int t = (tid >= off) ? sh[tid - off] : 0;
      __syncthreads();
      sh[tid] += t;
      __syncthreads();
    }
    int incl = sh[tid];
    int carry = carry_sh;
    if (i < n) row_start[i] = carry + incl - v;  // exclusive
    __syncthreads();
    if (tid == 1023) carry_sh = carry + sh[1023];
    __syncthreads();
  }
  if (tid == 0) row_start[n] = E;
}

__global__ void k_fill(const int* __restrict__ src, const int* __restrict__ dst,
                       const int* __restrict__ row_start, int* __restrict__ cursor,
                       int* __restrict__ csr, int E) {
  int e = blockIdx.x * 256 + threadIdx.x;
  if (e < E) {
    int d = dst[e];
    int pos = row_start[d] + atomicAdd(&cursor[d], 1);
    csr[pos] = src[e];
  }
}

// ---- dense GEMM: out[n x 128] = A[n x 128] @ W[128 x 128] -----------------
// block = 256 threads: 32 col-groups (4 cols) x 8 row-groups (4 rows)
// W fully staged in LDS (64 KiB).

__global__ __launch_bounds__(256) void gemm_k128_f128(
    const float* __restrict__ A, const float* __restrict__ W,
    float* __restrict__ out, int n) {
  __shared__ float shW[HD * HD];
  {
    const float4* Wv = (const float4*)W;
    float4* shWv = (float4*)shW;
    for (int t = threadIdx.x; t < HD * HD / 4; t += 256) shWv[t] = Wv[t];
  }
  __syncthreads();

  const int jg = (threadIdx.x & 31) * 4;  // col offset 0..124
  const int rs = threadIdx.x >> 5;        // 0..7
  const int row0 = blockIdx.x * 32 + rs * 4;
  const int nm1 = n - 1;
  const float* a0 = A + (size_t)min(row0 + 0, nm1) * HD;
  const float* a1 = A + (size_t)min(row0 + 1, nm1) * HD;
  const float* a2 = A + (size_t)min(row0 + 2, nm1) * HD;
  const float* a3 = A + (size_t)min(row0 + 3, nm1) * HD;

  float4 acc0 = make_float4(0.f, 0.f, 0.f, 0.f);
  float4 acc1 = acc0, acc2 = acc0, acc3 = acc0;

#pragma unroll 4
  for (int k = 0; k < HD; k += 4) {
    const float* wb = shW + k * HD + jg;
    float4 w0 = *(const float4*)(wb);
    float4 w1 = *(const float4*)(wb + HD);
    float4 w2 = *(const float4*)(wb + 2 * HD);
    float4 w3 = *(const float4*)(wb + 3 * HD);
    float4 x0 = *(const float4*)(a0 + k);
    float4 x1 = *(const float4*)(a1 + k);
    float4 x2 = *(const float4*)(a2 + k);
    float4 x3 = *(const float4*)(a3 + k);
    acc0 = fma4(x0.w, w3, fma4(x0.z, w2, fma4(x0.y, w1, fma4(x0.x, w0, acc0))));
    acc1 = fma4(x1.w, w3, fma4(x1.z, w2, fma4(x1.y, w1, fma4(x1.x, w0, acc1))));
    acc2 = fma4(x2.w, w3, fma4(x2.z, w2, fma4(x2.y, w1, fma4(x2.x, w0, acc2))));
    acc3 = fma4(x3.w, w3, fma4(x3.z, w2, fma4(x3.y, w1, fma4(x3.x, w0, acc3))));
  }
  if (row0 + 0 < n) *(float4*)(out + (size_t)(row0 + 0) * HD + jg) = acc0;
  if (row0 + 1 < n) *(float4*)(out + (size_t)(row0 + 1) * HD + jg) = acc1;
  if (row0 + 2 < n) *(float4*)(out + (size_t)(row0 + 2) * HD + jg) = acc2;
  if (row0 + 3 < n) *(float4*)(out + (size_t)(row0 + 3) * HD + jg) = acc3;
}

// ---- dense GEMM: out[n x 40] = A[n x 128] @ W[128 x 40] -------------------

__global__ __launch_bounds__(256) void gemm_k128_f40(
    const float* __restrict__ A, const float* __restrict__ W,
    float* __restrict__ out, int n) {
  int idx = blockIdx.x * 256 + threadIdx.x;
  if (idx >= n * NC) return;
  int i = idx / NC;
  int j = idx - i * NC;
  const float* a = A + (size_t)i * HD;
  float acc = 0.f;
#pragma unroll 8
  for (int k = 0; k < HD; k += 4) {
    float4 xv = *(const float4*)(a + k);
    acc = fmaf(xv.x, W[(k + 0) * NC + j], acc);
    acc = fmaf(xv.y, W[(k + 1) * NC + j], acc);
    acc = fmaf(xv.z, W[(k + 2) * NC + j], acc);
    acc = fmaf(xv.w, W[(k + 3) * NC + j], acc);
  }
  out[idx] = acc;
}

// ---- aggregation, F=128: one wave per node, fused bias+ReLU+residual ------

__global__ __launch_bounds__(256) void agg_f128(
    const float* __restrict__ xw, const float* __restrict__ resid,
    const float* __restrict__ bias, const float* __restrict__ dinv,
    const int* __restrict__ row_start, const int* __restrict__ csr,
    float* __restrict__ out, int n) {
  int node = (blockIdx.x * 256 + threadIdx.x) >> 6;
  if (node >= n) return;
  int lane = threadIdx.x & 63;
  int f = lane * 2;
  float di = dinv[node];
  float sw = di * di;
  float2 sv = *(const float2*)(xw + (size_t)node * HD + f);
  float ax = fmaf(sv.x, sw, bias[f]);
  float ay = fmaf(sv.y, sw, bias[f + 1]);
  int k = row_start[node];
  const int end = row_start[node + 1];
  for (; k < end; ++k) {
    int s = csr[k];
    float w = dinv[s] * di;
    float2 v = *(const float2*)(xw + (size_t)s * HD + f);
    ax = fmaf(v.x, w, ax);
    ay = fmaf(v.y, w, ay);
  }
  float2 r = *(const float2*)(resid + (size_t)node * HD + f);
  float2 o;
  o.x = fmaxf(ax, 0.f) + r.x;
  o.y = fmaxf(ay, 0.f) + r.y;
  *(float2*)(out + (size_t)node * HD + f) = o;
}

// ---- aggregation, F=40 + log_softmax: one wave per node -------------------

__global__ __launch_bounds__(256) void agg_f40_lsm(
    const float* __restrict__ xw, const float* __restrict__ dinv,
    const int* __restrict__ row_start, const int* __restrict__ csr,
    const float* __restrict__ bias, float* __restrict__ out, int n) {
  int node = (blockIdx.x * 256 + threadIdx.x) >> 6;
  if (node >= n) return;
  int lane = threadIdx.x & 63;
  const bool active = lane < NC;
  float di = dinv[node];
  float acc = 0.f;
  if (active) acc = fmaf(xw[(size_t)node * NC + lane], di * di, bias[lane]);
  int k = row_start[node];
  const int end = row_start[node + 1];
  for (; k < end; ++k) {
    int s = csr[k];
    float w = dinv[s] * di;
    if (active) acc = fmaf(xw[(size_t)s * NC + lane], w, acc);
  }
  // log_softmax over lanes 0..39
  float m = active ? acc : -3.0e38f;
  for (int off = 32; off >= 1; off >>= 1) m = fmaxf(m, __shfl_xor(m, off, 64));
  float e = active ? expf(acc - m) : 0.f;
  float ssum = e;
  for (int off = 32; off >= 1; off >>= 1) ssum += __shfl_xor(ssum, off, 64);
  if (active) out[(size_t)node * NC + lane] = acc - m - logf(ssum);
}

// ---------------------------------------------------------------------------

extern "C" void kernel_launch(void* const* d_in, const int* in_sizes, int n_in,
                              void* d_out, int out_size, void* d_ws, size_t ws_size,
                              hipStream_t stream) {
  const float* x  = (const float*)d_in[0];
  const int*   ei = (const int*)d_in[1];
  const float* W1 = (const float*)d_in[2];
  const float* b1 = (const float*)d_in[3];
  const float* W2 = (const float*)d_in[4];
  const float* b2 = (const float*)d_in[5];
  const float* W3 = (const float*)d_in[6];
  const float* b3 = (const float*)d_in[7];
  float* out = (float*)d_out;

  const int n = in_sizes[0] / HD;  // 50000
  const int E = in_sizes[1] / 2;   // 800000
  const int* src = ei;
  const int* dst = ei + E;

  // workspace carve (all 256B-aligned)
  char* ws = (char*)d_ws;
  size_t off = 0;
  auto carve = [&](size_t bytes) -> void* {
    void* p = ws + off;
    off += (bytes + 255) & ~(size_t)255;
    return p;
  };
  int*   cnt       = (int*)carve((size_t)n * 4);
  int*   cursor    = (int*)carve((size_t)n * 4);
  int*   row_start = (int*)carve((size_t)(n + 1) * 4);
  float* dinv      = (float*)carve((size_t)n * 4);
  int*   csr       = (int*)carve((size_t)E * 4);
  float* bufA      = (float*)carve((size_t)n * HD * 4);  // xw scratch
  float* bufB      = (float*)carve((size_t)n * HD * 4);  // h scratch

  const int gn  = (n + 255) / 256;
  const int gE  = (E + 255) / 256;
  const int gW  = (n + 3) / 4;            // one wave per node, 4 waves/block
  const int gG  = (n + 31) / 32;          // 32 rows per gemm block
  const int g40 = (n * NC + 255) / 256;

  // CSR build
  k_init<<<gn, 256, 0, stream>>>(cnt, cursor, n);
  k_count<<<gE, 256, 0, stream>>>(dst, cnt, E);
  k_dinv<<<gn, 256, 0, stream>>>(cnt, dinv, n);
  k_scan<<<1, 1024, 0, stream>>>(cnt, row_start, n, E);
  k_fill<<<gE, 256, 0, stream>>>(src, dst, row_start, cursor, csr, E);

  // layer 1: xw = x@W1 -> bufA ; h1 = relu(agg)+x -> bufB
  gemm_k128_f128<<<gG, 256, 0, stream>>>(x, W1, bufA, n);
  agg_f128<<<gW, 256, 0, stream>>>(bufA, x, b1, dinv, row_start, csr, bufB, n);

  // layer 2: xw = h1@W2 -> bufA ; h2 = relu(agg)+h1 -> bufB (in-place resid OK:
  // residual row is only read by its owning wave; gathers touch bufA only)
  gemm_k128_f128<<<gG, 256, 0, stream>>>(bufB, W2, bufA, n);
  agg_f128<<<gW, 256, 0, stream>>>(bufA, bufB, b2, dinv, row_start, csr, bufB, n);

  // layer 3: xw = h2@W3 -> bufA(:, :40) ; out = log_softmax(agg + b3)
  gemm_k128_f40<<<g40, 256, 0, stream>>>(bufB, W3, bufA, n);
  agg_f40_lsm<<<gW, 256, 0, stream>>>(bufA, dinv, row_start, csr, b3, out, n);
}

// Round 2
// 377.956 us; speedup vs baseline: 1.5784x; 1.5784x over previous
//
#include <hip/hip_runtime.h>
#include <math.h>

// ---------------------------------------------------------------------------
// MultiGCN: 3-layer GCN, N=50000, E=800000, D=H=128, C=40.
// Round 2: (a) GEMM outputs (gather buffers) stored bf16 -> halves gather
// traffic; (b) serial single-block scan replaced by block-scan + one global
// atomic for base allocation (CSR rows need unique slots, not monotone
// order); (c) edge loops unrolled x4 for memory-level parallelism.
// Residual chain and final output remain f32.
// ---------------------------------------------------------------------------

#define HD 128   // hidden / input feature dim
#define NC 40    // classes

__device__ __forceinline__ float4 fma4(float s, float4 w, float4 a) {
  a.x = fmaf(s, w.x, a.x);
  a.y = fmaf(s, w.y, a.y);
  a.z = fmaf(s, w.z, a.z);
  a.w = fmaf(s, w.w, a.w);
  return a;
}

// f32 -> bf16 with round-to-nearest-even (finite values only)
__device__ __forceinline__ unsigned short f2bf(float f) {
  unsigned int u = __float_as_uint(f);
  u += 0x7FFFu + ((u >> 16) & 1u);
  return (unsigned short)(u >> 16);
}
__device__ __forceinline__ unsigned int packbf2(float a, float b) {
  return (unsigned int)f2bf(a) | ((unsigned int)f2bf(b) << 16);
}
__device__ __forceinline__ float2 bf2f2(unsigned int v) {
  float2 r;
  r.x = __uint_as_float(v << 16);
  r.y = __uint_as_float(v & 0xFFFF0000u);
  return r;
}
__device__ __forceinline__ float bf2f(unsigned short v) {
  return __uint_as_float((unsigned int)v << 16);
}

// ---- CSR build ------------------------------------------------------------

__global__ void k_init(int* __restrict__ cnt, int* __restrict__ gtotal, int n) {
  int i = blockIdx.x * 256 + threadIdx.x;
  if (i < n) cnt[i] = 0;
  if (i == 0) *gtotal = 0;
}

__global__ void k_count(const int* __restrict__ dst, int* __restrict__ cnt, int E) {
  int e = blockIdx.x * 256 + threadIdx.x;
  if (e < E) atomicAdd(&cnt[dst[e]], 1);
}

// block scan + one atomic per block: assigns each node a unique contiguous
// CSR slot range (order across blocks is arbitrary -- that's fine).
__global__ __launch_bounds__(256) void k_alloc(
    const int* __restrict__ cnt, int* __restrict__ row_start,
    int* __restrict__ row_end, int* __restrict__ cursor,
    float* __restrict__ dinv, int* __restrict__ gtotal, int n) {
  __shared__ int sh[256];
  __shared__ int base_sh;
  const int tid = threadIdx.x;
  int i = blockIdx.x * 256 + tid;
  int v = (i < n) ? cnt[i] : 0;
  sh[tid] = v;
  __syncthreads();
  for (int off = 1; off < 256; off <<= 1) {
    int t = (tid >= off) ? sh[tid - off] : 0;
    __syncthreads();
    sh[tid] += t;
    __syncthreads();
  }
  if (tid == 255) base_sh = atomicAdd(gtotal, sh[255]);
  __syncthreads();
  if (i < n) {
    int start = base_sh + sh[tid] - v;
    row_start[i] = start;
    cursor[i] = start;
    row_end[i] = start + v;
    dinv[i] = rsqrtf((float)(v + 1));  // +1 self loop
  }
}

__global__ void k_fill(const int* __restrict__ src, const int* __restrict__ dst,
                       int* __restrict__ cursor, int* __restrict__ csr, int E) {
  int e = blockIdx.x * 256 + threadIdx.x;
  if (e < E) {
    int pos = atomicAdd(&cursor[dst[e]], 1);
    csr[pos] = src[e];
  }
}

// ---- dense GEMM: out[n x 128](bf16) = A[n x 128](f32) @ W[128 x 128] ------
// block = 256 threads: 32 col-groups (4 cols) x 8 row-groups (4 rows)
// W fully staged in LDS (64 KiB).

__global__ __launch_bounds__(256) void gemm_k128_f128(
    const float* __restrict__ A, const float* __restrict__ W,
    unsigned short* __restrict__ out, int n) {
  __shared__ float shW[HD * HD];
  {
    const float4* Wv = (const float4*)W;
    float4* shWv = (float4*)shW;
    for (int t = threadIdx.x; t < HD * HD / 4; t += 256) shWv[t] = Wv[t];
  }
  __syncthreads();

  const int jg = (threadIdx.x & 31) * 4;  // col offset 0..124
  const int rs = threadIdx.x >> 5;        // 0..7
  const int row0 = blockIdx.x * 32 + rs * 4;
  const int nm1 = n - 1;
  const float* a0 = A + (size_t)min(row0 + 0, nm1) * HD;
  const float* a1 = A + (size_t)min(row0 + 1, nm1) * HD;
  const float* a2 = A + (size_t)min(row0 + 2, nm1) * HD;
  const float* a3 = A + (size_t)min(row0 + 3, nm1) * HD;

  float4 acc0 = make_float4(0.f, 0.f, 0.f, 0.f);
  float4 acc1 = acc0, acc2 = acc0, acc3 = acc0;

#pragma unroll 4
  for (int k = 0; k < HD; k += 4) {
    const float* wb = shW + k * HD + jg;
    float4 w0 = *(const float4*)(wb);
    float4 w1 = *(const float4*)(wb + HD);
    float4 w2 = *(const float4*)(wb + 2 * HD);
    float4 w3 = *(const float4*)(wb + 3 * HD);
    float4 x0 = *(const float4*)(a0 + k);
    float4 x1 = *(const float4*)(a1 + k);
    float4 x2 = *(const float4*)(a2 + k);
    float4 x3 = *(const float4*)(a3 + k);
    acc0 = fma4(x0.w, w3, fma4(x0.z, w2, fma4(x0.y, w1, fma4(x0.x, w0, acc0))));
    acc1 = fma4(x1.w, w3, fma4(x1.z, w2, fma4(x1.y, w1, fma4(x1.x, w0, acc1))));
    acc2 = fma4(x2.w, w3, fma4(x2.z, w2, fma4(x2.y, w1, fma4(x2.x, w0, acc2))));
    acc3 = fma4(x3.w, w3, fma4(x3.z, w2, fma4(x3.y, w1, fma4(x3.x, w0, acc3))));
  }
  uint2 p;
  if (row0 + 0 < n) {
    p.x = packbf2(acc0.x, acc0.y); p.y = packbf2(acc0.z, acc0.w);
    *(uint2*)(out + (size_t)(row0 + 0) * HD + jg) = p;
  }
  if (row0 + 1 < n) {
    p.x = packbf2(acc1.x, acc1.y); p.y = packbf2(acc1.z, acc1.w);
    *(uint2*)(out + (size_t)(row0 + 1) * HD + jg) = p;
  }
  if (row0 + 2 < n) {
    p.x = packbf2(acc2.x, acc2.y); p.y = packbf2(acc2.z, acc2.w);
    *(uint2*)(out + (size_t)(row0 + 2) * HD + jg) = p;
  }
  if (row0 + 3 < n) {
    p.x = packbf2(acc3.x, acc3.y); p.y = packbf2(acc3.z, acc3.w);
    *(uint2*)(out + (size_t)(row0 + 3) * HD + jg) = p;
  }
}

// ---- dense GEMM: out[n x 40](bf16) = A[n x 128](f32) @ W[128 x 40] --------

__global__ __launch_bounds__(256) void gemm_k128_f40(
    const float* __restrict__ A, const float* __restrict__ W,
    unsigned short* __restrict__ out, int n) {
  int idx = blockIdx.x * 256 + threadIdx.x;
  if (idx >= n * NC) return;
  int i = idx / NC;
  int j = idx - i * NC;
  const float* a = A + (size_t)i * HD;
  float acc = 0.f;
#pragma unroll 8
  for (int k = 0; k < HD; k += 4) {
    float4 xv = *(const float4*)(a + k);
    acc = fmaf(xv.x, W[(k + 0) * NC + j], acc);
    acc = fmaf(xv.y, W[(k + 1) * NC + j], acc);
    acc = fmaf(xv.z, W[(k + 2) * NC + j], acc);
    acc = fmaf(xv.w, W[(k + 3) * NC + j], acc);
  }
  out[idx] = f2bf(acc);
}

// ---- aggregation, F=128 (bf16 gathers): wave per node, x4 unrolled --------

__global__ __launch_bounds__(256) void agg_f128(
    const unsigned short* __restrict__ xw, const float* __restrict__ resid,
    const float* __restrict__ bias, const float* __restrict__ dinv,
    const int* __restrict__ row_start, const int* __restrict__ row_end,
    const int* __restrict__ csr, float* __restrict__ out, int n) {
  int node = (blockIdx.x * 256 + threadIdx.x) >> 6;
  if (node >= n) return;
  int lane = threadIdx.x & 63;
  int f = lane * 2;
  float di = dinv[node];
  float2 bv = *(const float2*)(bias + f);
  float2 sv = bf2f2(*(const unsigned int*)(xw + (size_t)node * HD + f));
  float sw = di * di;
  float ax = fmaf(sv.x, sw, bv.x);
  float ay = fmaf(sv.y, sw, bv.y);
  int k = row_start[node];
  const int end = row_end[node];
  for (; k + 4 <= end; k += 4) {
    int s0 = csr[k], s1 = csr[k + 1], s2 = csr[k + 2], s3 = csr[k + 3];
    float w0 = dinv[s0] * di, w1 = dinv[s1] * di;
    float w2 = dinv[s2] * di, w3 = dinv[s3] * di;
    unsigned int u0 = *(const unsigned int*)(xw + (size_t)s0 * HD + f);
    unsigned int u1 = *(const unsigned int*)(xw + (size_t)s1 * HD + f);
    unsigned int u2 = *(const unsigned int*)(xw + (size_t)s2 * HD + f);
    unsigned int u3 = *(const unsigned int*)(xw + (size_t)s3 * HD + f);
    float2 v0 = bf2f2(u0), v1 = bf2f2(u1), v2 = bf2f2(u2), v3 = bf2f2(u3);
    ax = fmaf(v0.x, w0, ax); ay = fmaf(v0.y, w0, ay);
    ax = fmaf(v1.x, w1, ax); ay = fmaf(v1.y, w1, ay);
    ax = fmaf(v2.x, w2, ax); ay = fmaf(v2.y, w2, ay);
    ax = fmaf(v3.x, w3, ax); ay = fmaf(v3.y, w3, ay);
  }
  for (; k < end; ++k) {
    int s = csr[k];
    float w = dinv[s] * di;
    float2 v = bf2f2(*(const unsigned int*)(xw + (size_t)s * HD + f));
    ax = fmaf(v.x, w, ax);
    ay = fmaf(v.y, w, ay);
  }
  float2 r = *(const float2*)(resid + (size_t)node * HD + f);
  float2 o;
  o.x = fmaxf(ax, 0.f) + r.x;
  o.y = fmaxf(ay, 0.f) + r.y;
  *(float2*)(out + (size_t)node * HD + f) = o;
}

// ---- aggregation, F=40 (bf16 gathers) + log_softmax: wave per node --------

__global__ __launch_bounds__(256) void agg_f40_lsm(
    const unsigned short* __restrict__ xw, const float* __restrict__ dinv,
    const int* __restrict__ row_start, const int* __restrict__ row_end,
    const int* __restrict__ csr, const float* __restrict__ bias,
    float* __restrict__ out, int n) {
  int node = (blockIdx.x * 256 + threadIdx.x) >> 6;
  if (node >= n) return;
  int lane = threadIdx.x & 63;
  const bool active = lane < NC;
  float di = dinv[node];
  float acc = 0.f;
  if (active) acc = fmaf(bf2f(xw[(size_t)node * NC + lane]), di * di, bias[lane]);
  int k = row_start[node];
  const int end = row_end[node];
  for (; k + 4 <= end; k += 4) {
    int s0 = csr[k], s1 = csr[k + 1], s2 = csr[k + 2], s3 = csr[k + 3];
    float w0 = dinv[s0] * di, w1 = dinv[s1] * di;
    float w2 = dinv[s2] * di, w3 = dinv[s3] * di;
    if (active) {
      float v0 = bf2f(xw[(size_t)s0 * NC + lane]);
      float v1 = bf2f(xw[(size_t)s1 * NC + lane]);
      float v2 = bf2f(xw[(size_t)s2 * NC + lane]);
      float v3 = bf2f(xw[(size_t)s3 * NC + lane]);
      acc = fmaf(v0, w0, acc);
      acc = fmaf(v1, w1, acc);
      acc = fmaf(v2, w2, acc);
      acc = fmaf(v3, w3, acc);
    }
  }
  for (; k < end; ++k) {
    int s = csr[k];
    float w = dinv[s] * di;
    if (active) acc = fmaf(bf2f(xw[(size_t)s * NC + lane]), w, acc);
  }
  // log_softmax over lanes 0..39
  float m = active ? acc : -3.0e38f;
  for (int off = 32; off >= 1; off >>= 1) m = fmaxf(m, __shfl_xor(m, off, 64));
  float e = active ? expf(acc - m) : 0.f;
  float ssum = e;
  for (int off = 32; off >= 1; off >>= 1) ssum += __shfl_xor(ssum, off, 64);
  if (active) out[(size_t)node * NC + lane] = acc - m - logf(ssum);
}

// ---------------------------------------------------------------------------

extern "C" void kernel_launch(void* const* d_in, const int* in_sizes, int n_in,
                              void* d_out, int out_size, void* d_ws, size_t ws_size,
                              hipStream_t stream) {
  const float* x  = (const float*)d_in[0];
  const int*   ei = (const int*)d_in[1];
  const float* W1 = (const float*)d_in[2];
  const float* b1 = (const float*)d_in[3];
  const float* W2 = (const float*)d_in[4];
  const float* b2 = (const float*)d_in[5];
  const float* W3 = (const float*)d_in[6];
  const float* b3 = (const float*)d_in[7];
  float* out = (float*)d_out;

  const int n = in_sizes[0] / HD;  // 50000
  const int E = in_sizes[1] / 2;   // 800000
  const int* src = ei;
  const int* dst = ei + E;

  // workspace carve (all 256B-aligned)
  char* ws = (char*)d_ws;
  size_t off = 0;
  auto carve = [&](size_t bytes) -> void* {
    void* p = ws + off;
    off += (bytes + 255) & ~(size_t)255;
    return p;
  };
  int*   cnt       = (int*)carve((size_t)n * 4);
  int*   cursor    = (int*)carve((size_t)n * 4);
  int*   row_start = (int*)carve((size_t)n * 4);
  int*   row_end   = (int*)carve((size_t)n * 4);
  float* dinv      = (float*)carve((size_t)n * 4);
  int*   gtotal    = (int*)carve(256);
  int*   csr       = (int*)carve((size_t)E * 4);
  unsigned short* xwb = (unsigned short*)carve((size_t)n * HD * 2);  // bf16 xw
  float* bufB      = (float*)carve((size_t)n * HD * 4);              // h (f32)

  const int gn  = (n + 255) / 256;
  const int gE  = (E + 255) / 256;
  const int gW  = (n + 3) / 4;            // one wave per node, 4 waves/block
  const int gG  = (n + 31) / 32;          // 32 rows per gemm block
  const int g40 = (n * NC + 255) / 256;

  // CSR build
  k_init<<<gn, 256, 0, stream>>>(cnt, gtotal, n);
  k_count<<<gE, 256, 0, stream>>>(dst, cnt, E);
  k_alloc<<<gn, 256, 0, stream>>>(cnt, row_start, row_end, cursor, dinv, gtotal, n);
  k_fill<<<gE, 256, 0, stream>>>(src, dst, cursor, csr, E);

  // layer 1: xw = x@W1 -> xwb(bf16) ; h1 = relu(agg)+x -> bufB
  gemm_k128_f128<<<gG, 256, 0, stream>>>(x, W1, xwb, n);
  agg_f128<<<gW, 256, 0, stream>>>(xwb, x, b1, dinv, row_start, row_end, csr, bufB, n);

  // layer 2: xw = h1@W2 -> xwb ; h2 = relu(agg)+h1 -> bufB (in-place resid OK)
  gemm_k128_f128<<<gG, 256, 0, stream>>>(bufB, W2, xwb, n);
  agg_f128<<<gW, 256, 0, stream>>>(xwb, bufB, b2, dinv, row_start, row_end, csr, bufB, n);

  // layer 3: xw = h2@W3 -> xwb(:, :40) ; out = log_softmax(agg + b3)
  gemm_k128_f40<<<g40, 256, 0, stream>>>(bufB, W3, xwb, n);
  agg_f40_lsm<<<gW, 256, 0, stream>>>(xwb, dinv, row_start, row_end, csr, b3, out, n);
}

// Round 3
// 317.045 us; speedup vs baseline: 1.8817x; 1.1921x over previous
//
#include <hip/hip_runtime.h>
#include <math.h>

// ---------------------------------------------------------------------------
// MultiGCN: 3-layer GCN, N=50000, E=800000, D=H=128, C=40.
// Round 3: (a) gemm_k128_f40 rewritten as register-tiled (4x4/thread, W in
// 20KB LDS, block=320) -- was VMEM-issue-bound at 70us; (b) gemm_k128_f128
// now 8 rows/thread (64 rows/block) to amortize W staging; (c) agg_f128
// unrolled x8 with split accumulators for more loads in flight.
// Gather buffers bf16; residual chain and output f32.
// ---------------------------------------------------------------------------

#define HD 128   // hidden / input feature dim
#define NC 40    // classes

__device__ __forceinline__ float4 fma4(float s, float4 w, float4 a) {
  a.x = fmaf(s, w.x, a.x);
  a.y = fmaf(s, w.y, a.y);
  a.z = fmaf(s, w.z, a.z);
  a.w = fmaf(s, w.w, a.w);
  return a;
}

// f32 -> bf16 round-to-nearest-even (finite values only)
__device__ __forceinline__ unsigned short f2bf(float f) {
  unsigned int u = __float_as_uint(f);
  u += 0x7FFFu + ((u >> 16) & 1u);
  return (unsigned short)(u >> 16);
}
__device__ __forceinline__ unsigned int packbf2(float a, float b) {
  return (unsigned int)f2bf(a) | ((unsigned int)f2bf(b) << 16);
}
__device__ __forceinline__ float2 bf2f2(unsigned int v) {
  float2 r;
  r.x = __uint_as_float(v << 16);
  r.y = __uint_as_float(v & 0xFFFF0000u);
  return r;
}
__device__ __forceinline__ float bf2f(unsigned short v) {
  return __uint_as_float((unsigned int)v << 16);
}

// ---- CSR build ------------------------------------------------------------

__global__ void k_init(int* __restrict__ cnt, int* __restrict__ gtotal, int n) {
  int i = blockIdx.x * 256 + threadIdx.x;
  if (i < n) cnt[i] = 0;
  if (i == 0) *gtotal = 0;
}

__global__ void k_count(const int* __restrict__ dst, int* __restrict__ cnt, int E) {
  int e = blockIdx.x * 256 + threadIdx.x;
  if (e < E) atomicAdd(&cnt[dst[e]], 1);
}

// block scan + one atomic per block: unique contiguous CSR slot ranges
// (cross-block order arbitrary -- fine).
__global__ __launch_bounds__(256) void k_alloc(
    const int* __restrict__ cnt, int* __restrict__ row_start,
    int* __restrict__ row_end, int* __restrict__ cursor,
    float* __restrict__ dinv, int* __restrict__ gtotal, int n) {
  __shared__ int sh[256];
  __shared__ int base_sh;
  const int tid = threadIdx.x;
  int i = blockIdx.x * 256 + tid;
  int v = (i < n) ? cnt[i] : 0;
  sh[tid] = v;
  __syncthreads();
  for (int off = 1; off < 256; off <<= 1) {
    int t = (tid >= off) ? sh[tid - off] : 0;
    __syncthreads();
    sh[tid] += t;
    __syncthreads();
  }
  if (tid == 255) base_sh = atomicAdd(gtotal, sh[255]);
  __syncthreads();
  if (i < n) {
    int start = base_sh + sh[tid] - v;
    row_start[i] = start;
    cursor[i] = start;
    row_end[i] = start + v;
    dinv[i] = rsqrtf((float)(v + 1));  // +1 self loop
  }
}

__global__ void k_fill(const int* __restrict__ src, const int* __restrict__ dst,
                       int* __restrict__ cursor, int* __restrict__ csr, int E) {
  int e = blockIdx.x * 256 + threadIdx.x;
  if (e < E) {
    int pos = atomicAdd(&cursor[dst[e]], 1);
    csr[pos] = src[e];
  }
}

// ---- dense GEMM: out[n x 128](bf16) = A[n x 128](f32) @ W[128 x 128] ------
// block = 256 threads: 32 col-groups (4 cols) x 8 row-groups (8 rows each).
// W fully staged in LDS (64 KiB); 64 rows per block.

__global__ __launch_bounds__(256) void gemm_k128_f128(
    const float* __restrict__ A, const float* __restrict__ W,
    unsigned short* __restrict__ out, int n) {
  __shared__ float shW[HD * HD];
  {
    const float4* Wv = (const float4*)W;
    float4* shWv = (float4*)shW;
    for (int t = threadIdx.x; t < HD * HD / 4; t += 256) shWv[t] = Wv[t];
  }
  __syncthreads();

  const int jg = (threadIdx.x & 31) * 4;       // col offset 0..124
  const int rs = threadIdx.x >> 5;             // 0..7
  const int row0 = blockIdx.x * 64 + rs * 8;   // 8 rows per thread
  const int nm1 = n - 1;
  const float* a[8];
#pragma unroll
  for (int r = 0; r < 8; ++r) a[r] = A + (size_t)min(row0 + r, nm1) * HD;

  float4 acc[8];
#pragma unroll
  for (int r = 0; r < 8; ++r) acc[r] = make_float4(0.f, 0.f, 0.f, 0.f);

  for (int k = 0; k < HD; k += 4) {
    const float* wb = shW + k * HD + jg;
    float4 w0 = *(const float4*)(wb);
    float4 w1 = *(const float4*)(wb + HD);
    float4 w2 = *(const float4*)(wb + 2 * HD);
    float4 w3 = *(const float4*)(wb + 3 * HD);
#pragma unroll
    for (int r = 0; r < 8; ++r) {
      float4 xv = *(const float4*)(a[r] + k);
      acc[r] = fma4(xv.w, w3, fma4(xv.z, w2, fma4(xv.y, w1, fma4(xv.x, w0, acc[r]))));
    }
  }
#pragma unroll
  for (int r = 0; r < 8; ++r) {
    if (row0 + r < n) {
      uint2 p;
      p.x = packbf2(acc[r].x, acc[r].y);
      p.y = packbf2(acc[r].z, acc[r].w);
      *(uint2*)(out + (size_t)(row0 + r) * HD + jg) = p;
    }
  }
}

// ---- dense GEMM: out[n x 40](bf16) = A[n x 128](f32) @ W[128 x 40] --------
// block = 320 threads: 10 col-groups (4 cols) x 32 row-groups (4 rows each).
// W fully staged in LDS (20 KiB); 128 rows per block.

__global__ __launch_bounds__(320) void gemm_k128_f40(
    const float* __restrict__ A, const float* __restrict__ W,
    unsigned short* __restrict__ out, int n) {
  __shared__ float shW[HD * NC];
  {
    const float4* Wv = (const float4*)W;
    float4* shWv = (float4*)shW;
    for (int t = threadIdx.x; t < HD * NC / 4; t += 320) shWv[t] = Wv[t];
  }
  __syncthreads();

  const int cg = threadIdx.x % 10;
  const int rg = threadIdx.x / 10;             // 0..31
  const int jg = cg * 4;                       // col offset 0..36
  const int row0 = blockIdx.x * 128 + rg * 4;
  const int nm1 = n - 1;
  const float* a[4];
#pragma unroll
  for (int r = 0; r < 4; ++r) a[r] = A + (size_t)min(row0 + r, nm1) * HD;

  float4 acc[4];
#pragma unroll
  for (int r = 0; r < 4; ++r) acc[r] = make_float4(0.f, 0.f, 0.f, 0.f);

  for (int k = 0; k < HD; k += 4) {
    const float* wb = shW + k * NC + jg;
    float4 w0 = *(const float4*)(wb);
    float4 w1 = *(const float4*)(wb + NC);
    float4 w2 = *(const float4*)(wb + 2 * NC);
    float4 w3 = *(const float4*)(wb + 3 * NC);
#pragma unroll
    for (int r = 0; r < 4; ++r) {
      float4 xv = *(const float4*)(a[r] + k);
      acc[r] = fma4(xv.w, w3, fma4(xv.z, w2, fma4(xv.y, w1, fma4(xv.x, w0, acc[r]))));
    }
  }
#pragma unroll
  for (int r = 0; r < 4; ++r) {
    if (row0 + r < n) {
      uint2 p;
      p.x = packbf2(acc[r].x, acc[r].y);
      p.y = packbf2(acc[r].z, acc[r].w);
      *(uint2*)(out + (size_t)(row0 + r) * NC + jg) = p;
    }
  }
}

// ---- aggregation, F=128 (bf16 gathers): wave per node, x8 unrolled --------

__global__ __launch_bounds__(256) void agg_f128(
    const unsigned short* __restrict__ xw, const float* __restrict__ resid,
    const float* __restrict__ bias, const float* __restrict__ dinv,
    const int* __restrict__ row_start, const int* __restrict__ row_end,
    const int* __restrict__ csr, float* __restrict__ out, int n) {
  int node = (blockIdx.x * 256 + threadIdx.x) >> 6;
  if (node >= n) return;
  int lane = threadIdx.x & 63;
  int f = lane * 2;
  float di = dinv[node];
  float2 bv = *(const float2*)(bias + f);
  float2 sv = bf2f2(*(const unsigned int*)(xw + (size_t)node * HD + f));
  float sw = di * di;
  float axA = fmaf(sv.x, sw, bv.x);
  float ayA = fmaf(sv.y, sw, bv.y);
  float axB = 0.f, ayB = 0.f;
  int k = row_start[node];
  const int end = row_end[node];
  for (; k + 8 <= end; k += 8) {
    int s0 = csr[k],     s1 = csr[k + 1], s2 = csr[k + 2], s3 = csr[k + 3];
    int s4 = csr[k + 4], s5 = csr[k + 5], s6 = csr[k + 6], s7 = csr[k + 7];
    float w0 = dinv[s0] * di, w1 = dinv[s1] * di;
    float w2 = dinv[s2] * di, w3 = dinv[s3] * di;
    float w4 = dinv[s4] * di, w5 = dinv[s5] * di;
    float w6 = dinv[s6] * di, w7 = dinv[s7] * di;
    unsigned int u0 = *(const unsigned int*)(xw + (size_t)s0 * HD + f);
    unsigned int u1 = *(const unsigned int*)(xw + (size_t)s1 * HD + f);
    unsigned int u2 = *(const unsigned int*)(xw + (size_t)s2 * HD + f);
    unsigned int u3 = *(const unsigned int*)(xw + (size_t)s3 * HD + f);
    unsigned int u4 = *(const unsigned int*)(xw + (size_t)s4 * HD + f);
    unsigned int u5 = *(const unsigned int*)(xw + (size_t)s5 * HD + f);
    unsigned int u6 = *(const unsigned int*)(xw + (size_t)s6 * HD + f);
    unsigned int u7 = *(const unsigned int*)(xw + (size_t)s7 * HD + f);
    float2 v0 = bf2f2(u0), v1 = bf2f2(u1), v2 = bf2f2(u2), v3 = bf2f2(u3);
    float2 v4 = bf2f2(u4), v5 = bf2f2(u5), v6 = bf2f2(u6), v7 = bf2f2(u7);
    axA = fmaf(v0.x, w0, axA); ayA = fmaf(v0.y, w0, ayA);
    axB = fmaf(v1.x, w1, axB); ayB = fmaf(v1.y, w1, ayB);
    axA = fmaf(v2.x, w2, axA); ayA = fmaf(v2.y, w2, ayA);
    axB = fmaf(v3.x, w3, axB); ayB = fmaf(v3.y, w3, ayB);
    axA = fmaf(v4.x, w4, axA); ayA = fmaf(v4.y, w4, ayA);
    axB = fmaf(v5.x, w5, axB); ayB = fmaf(v5.y, w5, ayB);
    axA = fmaf(v6.x, w6, axA); ayA = fmaf(v6.y, w6, ayA);
    axB = fmaf(v7.x, w7, axB); ayB = fmaf(v7.y, w7, ayB);
  }
  for (; k + 4 <= end; k += 4) {
    int s0 = csr[k], s1 = csr[k + 1], s2 = csr[k + 2], s3 = csr[k + 3];
    float w0 = dinv[s0] * di, w1 = dinv[s1] * di;
    float w2 = dinv[s2] * di, w3 = dinv[s3] * di;
    unsigned int u0 = *(const unsigned int*)(xw + (size_t)s0 * HD + f);
    unsigned int u1 = *(const unsigned int*)(xw + (size_t)s1 * HD + f);
    unsigned int u2 = *(const unsigned int*)(xw + (size_t)s2 * HD + f);
    unsigned int u3 = *(const unsigned int*)(xw + (size_t)s3 * HD + f);
    float2 v0 = bf2f2(u0), v1 = bf2f2(u1), v2 = bf2f2(u2), v3 = bf2f2(u3);
    axA = fmaf(v0.x, w0, axA); ayA = fmaf(v0.y, w0, ayA);
    axB = fmaf(v1.x, w1, axB); ayB = fmaf(v1.y, w1, ayB);
    axA = fmaf(v2.x, w2, axA); ayA = fmaf(v2.y, w2, ayA);
    axB = fmaf(v3.x, w3, axB); ayB = fmaf(v3.y, w3, ayB);
  }
  for (; k < end; ++k) {
    int s = csr[k];
    float w = dinv[s] * di;
    float2 v = bf2f2(*(const unsigned int*)(xw + (size_t)s * HD + f));
    axA = fmaf(v.x, w, axA);
    ayA = fmaf(v.y, w, ayA);
  }
  float ax = axA + axB, ay = ayA + ayB;
  float2 r = *(const float2*)(resid + (size_t)node * HD + f);
  float2 o;
  o.x = fmaxf(ax, 0.f) + r.x;
  o.y = fmaxf(ay, 0.f) + r.y;
  *(float2*)(out + (size_t)node * HD + f) = o;
}

// ---- aggregation, F=40 (bf16 gathers) + log_softmax: wave per node --------

__global__ __launch_bounds__(256) void agg_f40_lsm(
    const unsigned short* __restrict__ xw, const float* __restrict__ dinv,
    const int* __restrict__ row_start, const int* __restrict__ row_end,
    const int* __restrict__ csr, const float* __restrict__ bias,
    float* __restrict__ out, int n) {
  int node = (blockIdx.x * 256 + threadIdx.x) >> 6;
  if (node >= n) return;
  int lane = threadIdx.x & 63;
  const bool active = lane < NC;
  float di = dinv[node];
  float acc = 0.f;
  if (active) acc = fmaf(bf2f(xw[(size_t)node * NC + lane]), di * di, bias[lane]);
  int k = row_start[node];
  const int end = row_end[node];
  for (; k + 4 <= end; k += 4) {
    int s0 = csr[k], s1 = csr[k + 1], s2 = csr[k + 2], s3 = csr[k + 3];
    float w0 = dinv[s0] * di, w1 = dinv[s1] * di;
    float w2 = dinv[s2] * di, w3 = dinv[s3] * di;
    if (active) {
      float v0 = bf2f(xw[(size_t)s0 * NC + lane]);
      float v1 = bf2f(xw[(size_t)s1 * NC + lane]);
      float v2 = bf2f(xw[(size_t)s2 * NC + lane]);
      float v3 = bf2f(xw[(size_t)s3 * NC + lane]);
      acc = fmaf(v0, w0, acc);
      acc = fmaf(v1, w1, acc);
      acc = fmaf(v2, w2, acc);
      acc = fmaf(v3, w3, acc);
    }
  }
  for (; k < end; ++k) {
    int s = csr[k];
    float w = dinv[s] * di;
    if (active) acc = fmaf(bf2f(xw[(size_t)s * NC + lane]), w, acc);
  }
  // log_softmax over lanes 0..39
  float m = active ? acc : -3.0e38f;
  for (int off = 32; off >= 1; off >>= 1) m = fmaxf(m, __shfl_xor(m, off, 64));
  float e = active ? expf(acc - m) : 0.f;
  float ssum = e;
  for (int off = 32; off >= 1; off >>= 1) ssum += __shfl_xor(ssum, off, 64);
  if (active) out[(size_t)node * NC + lane] = acc - m - logf(ssum);
}

// ---------------------------------------------------------------------------

extern "C" void kernel_launch(void* const* d_in, const int* in_sizes, int n_in,
                              void* d_out, int out_size, void* d_ws, size_t ws_size,
                              hipStream_t stream) {
  const float* x  = (const float*)d_in[0];
  const int*   ei = (const int*)d_in[1];
  const float* W1 = (const float*)d_in[2];
  const float* b1 = (const float*)d_in[3];
  const float* W2 = (const float*)d_in[4];
  const float* b2 = (const float*)d_in[5];
  const float* W3 = (const float*)d_in[6];
  const float* b3 = (const float*)d_in[7];
  float* out = (float*)d_out;

  const int n = in_sizes[0] / HD;  // 50000
  const int E = in_sizes[1] / 2;   // 800000
  const int* src = ei;
  const int* dst = ei + E;

  // workspace carve (all 256B-aligned)
  char* ws = (char*)d_ws;
  size_t off = 0;
  auto carve = [&](size_t bytes) -> void* {
    void* p = ws + off;
    off += (bytes + 255) & ~(size_t)255;
    return p;
  };
  int*   cnt       = (int*)carve((size_t)n * 4);
  int*   cursor    = (int*)carve((size_t)n * 4);
  int*   row_start = (int*)carve((size_t)n * 4);
  int*   row_end   = (int*)carve((size_t)n * 4);
  float* dinv      = (float*)carve((size_t)n * 4);
  int*   gtotal    = (int*)carve(256);
  int*   csr       = (int*)carve((size_t)E * 4);
  unsigned short* xwb = (unsigned short*)carve((size_t)n * HD * 2);  // bf16 xw
  float* bufB      = (float*)carve((size_t)n * HD * 4);              // h (f32)

  const int gn   = (n + 255) / 256;
  const int gE   = (E + 255) / 256;
  const int gW   = (n + 3) / 4;           // one wave per node, 4 waves/block
  const int gG   = (n + 63) / 64;         // 64 rows per f128 gemm block
  const int g40  = (n + 127) / 128;       // 128 rows per f40 gemm block

  // CSR build
  k_init<<<gn, 256, 0, stream>>>(cnt, gtotal, n);
  k_count<<<gE, 256, 0, stream>>>(dst, cnt, E);
  k_alloc<<<gn, 256, 0, stream>>>(cnt, row_start, row_end, cursor, dinv, gtotal, n);
  k_fill<<<gE, 256, 0, stream>>>(src, dst, cursor, csr, E);

  // layer 1: xw = x@W1 -> xwb(bf16) ; h1 = relu(agg)+x -> bufB
  gemm_k128_f128<<<gG, 256, 0, stream>>>(x, W1, xwb, n);
  agg_f128<<<gW, 256, 0, stream>>>(xwb, x, b1, dinv, row_start, row_end, csr, bufB, n);

  // layer 2: xw = h1@W2 -> xwb ; h2 = relu(agg)+h1 -> bufB (in-place resid OK)
  gemm_k128_f128<<<gG, 256, 0, stream>>>(bufB, W2, xwb, n);
  agg_f128<<<gW, 256, 0, stream>>>(xwb, bufB, b2, dinv, row_start, row_end, csr, bufB, n);

  // layer 3: xw = h2@W3 -> xwb(:, :40) ; out = log_softmax(agg + b3)
  gemm_k128_f40<<<g40, 320, 0, stream>>>(bufB, W3, xwb, n);
  agg_f40_lsm<<<gW, 256, 0, stream>>>(xwb, dinv, row_start, row_end, csr, b3, out, n);
}

// Round 4
// 282.121 us; speedup vs baseline: 2.1146x; 1.1238x over previous
//
#include <hip/hip_runtime.h>
#include <math.h>

// ---------------------------------------------------------------------------
// MultiGCN: 3-layer GCN, N=50000, E=800000, D=H=128, C=40.
// Round 4: CSR-build overhaul. (a) k_count's atomicAdd return value is the
// edge's within-node rank -> k_fill needs NO atomics; (b) both edge kernels
// process 4 edges/thread (4 independent memory ops in flight -- they are
// latency-bound at 0.3% VALU); (c) CSR entries are (src, norm) int2 packs,
// so agg passes do zero random dinv reads. Gather buffers bf16.
// ---------------------------------------------------------------------------

#define HD 128   // hidden / input feature dim
#define NC 40    // classes

__device__ __forceinline__ float4 fma4(float s, float4 w, float4 a) {
  a.x = fmaf(s, w.x, a.x);
  a.y = fmaf(s, w.y, a.y);
  a.z = fmaf(s, w.z, a.z);
  a.w = fmaf(s, w.w, a.w);
  return a;
}

// f32 -> bf16 round-to-nearest-even (finite values only)
__device__ __forceinline__ unsigned short f2bf(float f) {
  unsigned int u = __float_as_uint(f);
  u += 0x7FFFu + ((u >> 16) & 1u);
  return (unsigned short)(u >> 16);
}
__device__ __forceinline__ unsigned int packbf2(float a, float b) {
  return (unsigned int)f2bf(a) | ((unsigned int)f2bf(b) << 16);
}
__device__ __forceinline__ float2 bf2f2(unsigned int v) {
  float2 r;
  r.x = __uint_as_float(v << 16);
  r.y = __uint_as_float(v & 0xFFFF0000u);
  return r;
}
__device__ __forceinline__ float bf2f(unsigned short v) {
  return __uint_as_float((unsigned int)v << 16);
}

// ---- CSR build ------------------------------------------------------------

__global__ void k_init(int* __restrict__ cnt, int* __restrict__ gtotal, int n) {
  int i = blockIdx.x * 256 + threadIdx.x;
  if (i < n) cnt[i] = 0;
  if (i == 0) *gtotal = 0;
}

// count + record per-edge rank (atomicAdd return value), 4 edges/thread
__global__ __launch_bounds__(256) void k_count_rank(
    const int* __restrict__ dst, int* __restrict__ cnt,
    int* __restrict__ rank, int E) {
  int t = blockIdx.x * 256 + threadIdx.x;
  int nt = gridDim.x * 256;
  int e0 = t, e1 = t + nt, e2 = t + 2 * nt, e3 = t + 3 * nt;
  int d0 = (e0 < E) ? dst[e0] : 0;
  int d1 = (e1 < E) ? dst[e1] : 0;
  int d2 = (e2 < E) ? dst[e2] : 0;
  int d3 = (e3 < E) ? dst[e3] : 0;
  int r0 = 0, r1 = 0, r2 = 0, r3 = 0;
  if (e0 < E) r0 = atomicAdd(&cnt[d0], 1);
  if (e1 < E) r1 = atomicAdd(&cnt[d1], 1);
  if (e2 < E) r2 = atomicAdd(&cnt[d2], 1);
  if (e3 < E) r3 = atomicAdd(&cnt[d3], 1);
  if (e0 < E) rank[e0] = r0;
  if (e1 < E) rank[e1] = r1;
  if (e2 < E) rank[e2] = r2;
  if (e3 < E) rank[e3] = r3;
}

// block scan + one atomic per block: unique contiguous CSR slot ranges
// (cross-block order arbitrary -- fine). nodeinfo = {row_start, dinv bits}.
__global__ __launch_bounds__(256) void k_alloc(
    const int* __restrict__ cnt, int* __restrict__ row_start,
    int* __restrict__ row_end, int2* __restrict__ nodeinfo,
    float* __restrict__ dinv, int* __restrict__ gtotal, int n) {
  __shared__ int sh[256];
  __shared__ int base_sh;
  const int tid = threadIdx.x;
  int i = blockIdx.x * 256 + tid;
  int v = (i < n) ? cnt[i] : 0;
  sh[tid] = v;
  __syncthreads();
  for (int off = 1; off < 256; off <<= 1) {
    int t = (tid >= off) ? sh[tid - off] : 0;
    __syncthreads();
    sh[tid] += t;
    __syncthreads();
  }
  if (tid == 255) base_sh = atomicAdd(gtotal, sh[255]);
  __syncthreads();
  if (i < n) {
    int start = base_sh + sh[tid] - v;
    float dv = rsqrtf((float)(v + 1));  // +1 self loop
    row_start[i] = start;
    row_end[i] = start + v;
    dinv[i] = dv;
    nodeinfo[i] = make_int2(start, __float_as_int(dv));
  }
}

// fill: no atomics -- pos = row_start[dst] + rank[e]; entry = {src, norm}
__global__ __launch_bounds__(256) void k_fill(
    const int* __restrict__ src, const int* __restrict__ dst,
    const int* __restrict__ rank, const int2* __restrict__ nodeinfo,
    const float* __restrict__ dinv, int2* __restrict__ csr2, int E) {
  int t = blockIdx.x * 256 + threadIdx.x;
  int nt = gridDim.x * 256;
#pragma unroll
  for (int q = 0; q < 4; ++q) {
    int e = t + q * nt;
    if (e < E) {
      int d = dst[e];
      int s = src[e];
      int r = rank[e];
      int2 ni = nodeinfo[d];
      float norm = dinv[s] * __int_as_float(ni.y);
      csr2[ni.x + r] = make_int2(s, __float_as_int(norm));
    }
  }
}

// ---- dense GEMM: out[n x 128](bf16) = A[n x 128](f32) @ W[128 x 128] ------
// block = 256 threads: 32 col-groups (4 cols) x 8 row-groups (8 rows each).
// W fully staged in LDS (64 KiB); 64 rows per block.

__global__ __launch_bounds__(256) void gemm_k128_f128(
    const float* __restrict__ A, const float* __restrict__ W,
    unsigned short* __restrict__ out, int n) {
  __shared__ float shW[HD * HD];
  {
    const float4* Wv = (const float4*)W;
    float4* shWv = (float4*)shW;
    for (int t = threadIdx.x; t < HD * HD / 4; t += 256) shWv[t] = Wv[t];
  }
  __syncthreads();

  const int jg = (threadIdx.x & 31) * 4;       // col offset 0..124
  const int rs = threadIdx.x >> 5;             // 0..7
  const int row0 = blockIdx.x * 64 + rs * 8;   // 8 rows per thread
  const int nm1 = n - 1;
  const float* a[8];
#pragma unroll
  for (int r = 0; r < 8; ++r) a[r] = A + (size_t)min(row0 + r, nm1) * HD;

  float4 acc[8];
#pragma unroll
  for (int r = 0; r < 8; ++r) acc[r] = make_float4(0.f, 0.f, 0.f, 0.f);

  for (int k = 0; k < HD; k += 4) {
    const float* wb = shW + k * HD + jg;
    float4 w0 = *(const float4*)(wb);
    float4 w1 = *(const float4*)(wb + HD);
    float4 w2 = *(const float4*)(wb + 2 * HD);
    float4 w3 = *(const float4*)(wb + 3 * HD);
#pragma unroll
    for (int r = 0; r < 8; ++r) {
      float4 xv = *(const float4*)(a[r] + k);
      acc[r] = fma4(xv.w, w3, fma4(xv.z, w2, fma4(xv.y, w1, fma4(xv.x, w0, acc[r]))));
    }
  }
#pragma unroll
  for (int r = 0; r < 8; ++r) {
    if (row0 + r < n) {
      uint2 p;
      p.x = packbf2(acc[r].x, acc[r].y);
      p.y = packbf2(acc[r].z, acc[r].w);
      *(uint2*)(out + (size_t)(row0 + r) * HD + jg) = p;
    }
  }
}

// ---- dense GEMM: out[n x 40](bf16) = A[n x 128](f32) @ W[128 x 40] --------
// block = 320 threads: 10 col-groups (4 cols) x 32 row-groups (4 rows each).
// W fully staged in LDS (20 KiB); 128 rows per block.

__global__ __launch_bounds__(320) void gemm_k128_f40(
    const float* __restrict__ A, const float* __restrict__ W,
    unsigned short* __restrict__ out, int n) {
  __shared__ float shW[HD * NC];
  {
    const float4* Wv = (const float4*)W;
    float4* shWv = (float4*)shW;
    for (int t = threadIdx.x; t < HD * NC / 4; t += 320) shWv[t] = Wv[t];
  }
  __syncthreads();

  const int cg = threadIdx.x % 10;
  const int rg = threadIdx.x / 10;             // 0..31
  const int jg = cg * 4;                       // col offset 0..36
  const int row0 = blockIdx.x * 128 + rg * 4;
  const int nm1 = n - 1;
  const float* a[4];
#pragma unroll
  for (int r = 0; r < 4; ++r) a[r] = A + (size_t)min(row0 + r, nm1) * HD;

  float4 acc[4];
#pragma unroll
  for (int r = 0; r < 4; ++r) acc[r] = make_float4(0.f, 0.f, 0.f, 0.f);

  for (int k = 0; k < HD; k += 4) {
    const float* wb = shW + k * NC + jg;
    float4 w0 = *(const float4*)(wb);
    float4 w1 = *(const float4*)(wb + NC);
    float4 w2 = *(const float4*)(wb + 2 * NC);
    float4 w3 = *(const float4*)(wb + 3 * NC);
#pragma unroll
    for (int r = 0; r < 4; ++r) {
      float4 xv = *(const float4*)(a[r] + k);
      acc[r] = fma4(xv.w, w3, fma4(xv.z, w2, fma4(xv.y, w1, fma4(xv.x, w0, acc[r]))));
    }
  }
#pragma unroll
  for (int r = 0; r < 4; ++r) {
    if (row0 + r < n) {
      uint2 p;
      p.x = packbf2(acc[r].x, acc[r].y);
      p.y = packbf2(acc[r].z, acc[r].w);
      *(uint2*)(out + (size_t)(row0 + r) * NC + jg) = p;
    }
  }
}

// ---- aggregation, F=128 (bf16 gathers, packed norm): wave per node --------

__global__ __launch_bounds__(256) void agg_f128(
    const unsigned short* __restrict__ xw, const float* __restrict__ resid,
    const float* __restrict__ bias, const float* __restrict__ dinv,
    const int* __restrict__ row_start, const int* __restrict__ row_end,
    const int2* __restrict__ csr2, float* __restrict__ out, int n) {
  int node = (blockIdx.x * 256 + threadIdx.x) >> 6;
  if (node >= n) return;
  int lane = threadIdx.x & 63;
  int f = lane * 2;
  float di = dinv[node];
  float2 bv = *(const float2*)(bias + f);
  float2 sv = bf2f2(*(const unsigned int*)(xw + (size_t)node * HD + f));
  float sw = di * di;
  float axA = fmaf(sv.x, sw, bv.x);
  float ayA = fmaf(sv.y, sw, bv.y);
  float axB = 0.f, ayB = 0.f;
  int k = row_start[node];
  const int end = row_end[node];
  for (; k + 8 <= end; k += 8) {
    int2 c0 = csr2[k],     c1 = csr2[k + 1], c2 = csr2[k + 2], c3 = csr2[k + 3];
    int2 c4 = csr2[k + 4], c5 = csr2[k + 5], c6 = csr2[k + 6], c7 = csr2[k + 7];
    unsigned int u0 = *(const unsigned int*)(xw + (size_t)c0.x * HD + f);
    unsigned int u1 = *(const unsigned int*)(xw + (size_t)c1.x * HD + f);
    unsigned int u2 = *(const unsigned int*)(xw + (size_t)c2.x * HD + f);
    unsigned int u3 = *(const unsigned int*)(xw + (size_t)c3.x * HD + f);
    unsigned int u4 = *(const unsigned int*)(xw + (size_t)c4.x * HD + f);
    unsigned int u5 = *(const unsigned int*)(xw + (size_t)c5.x * HD + f);
    unsigned int u6 = *(const unsigned int*)(xw + (size_t)c6.x * HD + f);
    unsigned int u7 = *(const unsigned int*)(xw + (size_t)c7.x * HD + f);
    float2 v0 = bf2f2(u0), v1 = bf2f2(u1), v2 = bf2f2(u2), v3 = bf2f2(u3);
    float2 v4 = bf2f2(u4), v5 = bf2f2(u5), v6 = bf2f2(u6), v7 = bf2f2(u7);
    float w0 = __int_as_float(c0.y), w1 = __int_as_float(c1.y);
    float w2 = __int_as_float(c2.y), w3 = __int_as_float(c3.y);
    float w4 = __int_as_float(c4.y), w5 = __int_as_float(c5.y);
    float w6 = __int_as_float(c6.y), w7 = __int_as_float(c7.y);
    axA = fmaf(v0.x, w0, axA); ayA = fmaf(v0.y, w0, ayA);
    axB = fmaf(v1.x, w1, axB); ayB = fmaf(v1.y, w1, ayB);
    axA = fmaf(v2.x, w2, axA); ayA = fmaf(v2.y, w2, ayA);
    axB = fmaf(v3.x, w3, axB); ayB = fmaf(v3.y, w3, ayB);
    axA = fmaf(v4.x, w4, axA); ayA = fmaf(v4.y, w4, ayA);
    axB = fmaf(v5.x, w5, axB); ayB = fmaf(v5.y, w5, ayB);
    axA = fmaf(v6.x, w6, axA); ayA = fmaf(v6.y, w6, ayA);
    axB = fmaf(v7.x, w7, axB); ayB = fmaf(v7.y, w7, ayB);
  }
  for (; k + 4 <= end; k += 4) {
    int2 c0 = csr2[k], c1 = csr2[k + 1], c2 = csr2[k + 2], c3 = csr2[k + 3];
    unsigned int u0 = *(const unsigned int*)(xw + (size_t)c0.x * HD + f);
    unsigned int u1 = *(const unsigned int*)(xw + (size_t)c1.x * HD + f);
    unsigned int u2 = *(const unsigned int*)(xw + (size_t)c2.x * HD + f);
    unsigned int u3 = *(const unsigned int*)(xw + (size_t)c3.x * HD + f);
    float2 v0 = bf2f2(u0), v1 = bf2f2(u1), v2 = bf2f2(u2), v3 = bf2f2(u3);
    float w0 = __int_as_float(c0.y), w1 = __int_as_float(c1.y);
    float w2 = __int_as_float(c2.y), w3 = __int_as_float(c3.y);
    axA = fmaf(v0.x, w0, axA); ayA = fmaf(v0.y, w0, ayA);
    axB = fmaf(v1.x, w1, axB); ayB = fmaf(v1.y, w1, ayB);
    axA = fmaf(v2.x, w2, axA); ayA = fmaf(v2.y, w2, ayA);
    axB = fmaf(v3.x, w3, axB); ayB = fmaf(v3.y, w3, ayB);
  }
  for (; k < end; ++k) {
    int2 c = csr2[k];
    float w = __int_as_float(c.y);
    float2 v = bf2f2(*(const unsigned int*)(xw + (size_t)c.x * HD + f));
    axA = fmaf(v.x, w, axA);
    ayA = fmaf(v.y, w, ayA);
  }
  float ax = axA + axB, ay = ayA + ayB;
  float2 r = *(const float2*)(resid + (size_t)node * HD + f);
  float2 o;
  o.x = fmaxf(ax, 0.f) + r.x;
  o.y = fmaxf(ay, 0.f) + r.y;
  *(float2*)(out + (size_t)node * HD + f) = o;
}

// ---- aggregation, F=40 (bf16, packed norm) + log_softmax ------------------

__global__ __launch_bounds__(256) void agg_f40_lsm(
    const unsigned short* __restrict__ xw, const float* __restrict__ dinv,
    const int* __restrict__ row_start, const int* __restrict__ row_end,
    const int2* __restrict__ csr2, const float* __restrict__ bias,
    float* __restrict__ out, int n) {
  int node = (blockIdx.x * 256 + threadIdx.x) >> 6;
  if (node >= n) return;
  int lane = threadIdx.x & 63;
  const bool active = lane < NC;
  float di = dinv[node];
  float acc = 0.f;
  if (active) acc = fmaf(bf2f(xw[(size_t)node * NC + lane]), di * di, bias[lane]);
  int k = row_start[node];
  const int end = row_end[node];
  for (; k + 4 <= end; k += 4) {
    int2 c0 = csr2[k], c1 = csr2[k + 1], c2 = csr2[k + 2], c3 = csr2[k + 3];
    if (active) {
      float v0 = bf2f(xw[(size_t)c0.x * NC + lane]);
      float v1 = bf2f(xw[(size_t)c1.x * NC + lane]);
      float v2 = bf2f(xw[(size_t)c2.x * NC + lane]);
      float v3 = bf2f(xw[(size_t)c3.x * NC + lane]);
      acc = fmaf(v0, __int_as_float(c0.y), acc);
      acc = fmaf(v1, __int_as_float(c1.y), acc);
      acc = fmaf(v2, __int_as_float(c2.y), acc);
      acc = fmaf(v3, __int_as_float(c3.y), acc);
    }
  }
  for (; k < end; ++k) {
    int2 c = csr2[k];
    if (active) acc = fmaf(bf2f(xw[(size_t)c.x * NC + lane]), __int_as_float(c.y), acc);
  }
  // log_softmax over lanes 0..39
  float m = active ? acc : -3.0e38f;
  for (int off = 32; off >= 1; off >>= 1) m = fmaxf(m, __shfl_xor(m, off, 64));
  float e = active ? expf(acc - m) : 0.f;
  float ssum = e;
  for (int off = 32; off >= 1; off >>= 1) ssum += __shfl_xor(ssum, off, 64);
  if (active) out[(size_t)node * NC + lane] = acc - m - logf(ssum);
}

// ---------------------------------------------------------------------------

extern "C" void kernel_launch(void* const* d_in, const int* in_sizes, int n_in,
                              void* d_out, int out_size, void* d_ws, size_t ws_size,
                              hipStream_t stream) {
  const float* x  = (const float*)d_in[0];
  const int*   ei = (const int*)d_in[1];
  const float* W1 = (const float*)d_in[2];
  const float* b1 = (const float*)d_in[3];
  const float* W2 = (const float*)d_in[4];
  const float* b2 = (const float*)d_in[5];
  const float* W3 = (const float*)d_in[6];
  const float* b3 = (const float*)d_in[7];
  float* out = (float*)d_out;

  const int n = in_sizes[0] / HD;  // 50000
  const int E = in_sizes[1] / 2;   // 800000
  const int* src = ei;
  const int* dst = ei + E;

  // workspace carve (all 256B-aligned)
  char* ws = (char*)d_ws;
  size_t off = 0;
  auto carve = [&](size_t bytes) -> void* {
    void* p = ws + off;
    off += (bytes + 255) & ~(size_t)255;
    return p;
  };
  int*   cnt       = (int*)carve((size_t)n * 4);
  int*   row_start = (int*)carve((size_t)n * 4);
  int*   row_end   = (int*)carve((size_t)n * 4);
  float* dinv      = (float*)carve((size_t)n * 4);
  int2*  nodeinfo  = (int2*)carve((size_t)n * 8);
  int*   gtotal    = (int*)carve(256);
  int2*  csr2      = (int2*)carve((size_t)E * 8);
  unsigned short* xwb = (unsigned short*)carve((size_t)n * HD * 2);  // bf16 xw
  float* bufB      = (float*)carve((size_t)n * HD * 4);              // h (f32)
  // rank[] is only live before the first GEMM writes bufB -> alias it.
  int*   rank      = (int*)bufB;

  const int gn   = (n + 255) / 256;
  const int gE4  = (E + 1023) / 1024;     // 4 edges per thread
  const int gW   = (n + 3) / 4;           // one wave per node, 4 waves/block
  const int gG   = (n + 63) / 64;         // 64 rows per f128 gemm block
  const int g40  = (n + 127) / 128;       // 128 rows per f40 gemm block

  // CSR build
  k_init<<<gn, 256, 0, stream>>>(cnt, gtotal, n);
  k_count_rank<<<gE4, 256, 0, stream>>>(dst, cnt, rank, E);
  k_alloc<<<gn, 256, 0, stream>>>(cnt, row_start, row_end, nodeinfo, dinv, gtotal, n);
  k_fill<<<gE4, 256, 0, stream>>>(src, dst, rank, nodeinfo, dinv, csr2, E);

  // layer 1: xw = x@W1 -> xwb(bf16) ; h1 = relu(agg)+x -> bufB
  gemm_k128_f128<<<gG, 256, 0, stream>>>(x, W1, xwb, n);
  agg_f128<<<gW, 256, 0, stream>>>(xwb, x, b1, dinv, row_start, row_end, csr2, bufB, n);

  // layer 2: xw = h1@W2 -> xwb ; h2 = relu(agg)+h1 -> bufB (in-place resid OK)
  gemm_k128_f128<<<gG, 256, 0, stream>>>(bufB, W2, xwb, n);
  agg_f128<<<gW, 256, 0, stream>>>(xwb, bufB, b2, dinv, row_start, row_end, csr2, bufB, n);

  // layer 3: xw = h2@W3 -> xwb(:, :40) ; out = log_softmax(agg + b3)
  gemm_k128_f40<<<g40, 320, 0, stream>>>(bufB, W3, xwb, n);
  agg_f40_lsm<<<gW, 256, 0, stream>>>(xwb, dinv, row_start, row_end, csr2, b3, out, n);
}

// Round 5
// 281.893 us; speedup vs baseline: 2.1163x; 1.0008x over previous
//
#include <hip/hip_runtime.h>
#include <math.h>

// ---------------------------------------------------------------------------
// MultiGCN: 3-layer GCN, N=50000, E=800000, D=H=128, C=40.
// Round 5: gemm_k128_f128 retiled to 128 rows x 64 cols per block with a
// 32 KiB W column-half in LDS (was 64 KiB -> 2 blocks/CU -> 14% occupancy,
// latency-bound on per-thread A loads). Grid gains a y-dim (2 col halves).
// Everything else unchanged from round 4.
// ---------------------------------------------------------------------------

#define HD 128   // hidden / input feature dim
#define NC 40    // classes

__device__ __forceinline__ float4 fma4(float s, float4 w, float4 a) {
  a.x = fmaf(s, w.x, a.x);
  a.y = fmaf(s, w.y, a.y);
  a.z = fmaf(s, w.z, a.z);
  a.w = fmaf(s, w.w, a.w);
  return a;
}

// f32 -> bf16 round-to-nearest-even (finite values only)
__device__ __forceinline__ unsigned short f2bf(float f) {
  unsigned int u = __float_as_uint(f);
  u += 0x7FFFu + ((u >> 16) & 1u);
  return (unsigned short)(u >> 16);
}
__device__ __forceinline__ unsigned int packbf2(float a, float b) {
  return (unsigned int)f2bf(a) | ((unsigned int)f2bf(b) << 16);
}
__device__ __forceinline__ float2 bf2f2(unsigned int v) {
  float2 r;
  r.x = __uint_as_float(v << 16);
  r.y = __uint_as_float(v & 0xFFFF0000u);
  return r;
}
__device__ __forceinline__ float bf2f(unsigned short v) {
  return __uint_as_float((unsigned int)v << 16);
}

// ---- CSR build ------------------------------------------------------------

__global__ void k_init(int* __restrict__ cnt, int* __restrict__ gtotal, int n) {
  int i = blockIdx.x * 256 + threadIdx.x;
  if (i < n) cnt[i] = 0;
  if (i == 0) *gtotal = 0;
}

// count + record per-edge rank (atomicAdd return value), 4 edges/thread
__global__ __launch_bounds__(256) void k_count_rank(
    const int* __restrict__ dst, int* __restrict__ cnt,
    int* __restrict__ rank, int E) {
  int t = blockIdx.x * 256 + threadIdx.x;
  int nt = gridDim.x * 256;
  int e0 = t, e1 = t + nt, e2 = t + 2 * nt, e3 = t + 3 * nt;
  int d0 = (e0 < E) ? dst[e0] : 0;
  int d1 = (e1 < E) ? dst[e1] : 0;
  int d2 = (e2 < E) ? dst[e2] : 0;
  int d3 = (e3 < E) ? dst[e3] : 0;
  int r0 = 0, r1 = 0, r2 = 0, r3 = 0;
  if (e0 < E) r0 = atomicAdd(&cnt[d0], 1);
  if (e1 < E) r1 = atomicAdd(&cnt[d1], 1);
  if (e2 < E) r2 = atomicAdd(&cnt[d2], 1);
  if (e3 < E) r3 = atomicAdd(&cnt[d3], 1);
  if (e0 < E) rank[e0] = r0;
  if (e1 < E) rank[e1] = r1;
  if (e2 < E) rank[e2] = r2;
  if (e3 < E) rank[e3] = r3;
}

// block scan + one atomic per block: unique contiguous CSR slot ranges
// (cross-block order arbitrary -- fine). nodeinfo = {row_start, dinv bits}.
__global__ __launch_bounds__(256) void k_alloc(
    const int* __restrict__ cnt, int* __restrict__ row_start,
    int* __restrict__ row_end, int2* __restrict__ nodeinfo,
    float* __restrict__ dinv, int* __restrict__ gtotal, int n) {
  __shared__ int sh[256];
  __shared__ int base_sh;
  const int tid = threadIdx.x;
  int i = blockIdx.x * 256 + tid;
  int v = (i < n) ? cnt[i] : 0;
  sh[tid] = v;
  __syncthreads();
  for (int off = 1; off < 256; off <<= 1) {
    int t = (tid >= off) ? sh[tid - off] : 0;
    __syncthreads();
    sh[tid] += t;
    __syncthreads();
  }
  if (tid == 255) base_sh = atomicAdd(gtotal, sh[255]);
  __syncthreads();
  if (i < n) {
    int start = base_sh + sh[tid] - v;
    float dv = rsqrtf((float)(v + 1));  // +1 self loop
    row_start[i] = start;
    row_end[i] = start + v;
    dinv[i] = dv;
    nodeinfo[i] = make_int2(start, __float_as_int(dv));
  }
}

// fill: no atomics -- pos = row_start[dst] + rank[e]; entry = {src, norm}
__global__ __launch_bounds__(256) void k_fill(
    const int* __restrict__ src, const int* __restrict__ dst,
    const int* __restrict__ rank, const int2* __restrict__ nodeinfo,
    const float* __restrict__ dinv, int2* __restrict__ csr2, int E) {
  int t = blockIdx.x * 256 + threadIdx.x;
  int nt = gridDim.x * 256;
#pragma unroll
  for (int q = 0; q < 4; ++q) {
    int e = t + q * nt;
    if (e < E) {
      int d = dst[e];
      int s = src[e];
      int r = rank[e];
      int2 ni = nodeinfo[d];
      float norm = dinv[s] * __int_as_float(ni.y);
      csr2[ni.x + r] = make_int2(s, __float_as_int(norm));
    }
  }
}

// ---- dense GEMM: out[n x 128](bf16) = A[n x 128](f32) @ W[128 x 128] ------
// block = 256 threads computes 128 rows x 64 cols; W column-half staged in
// 32 KiB LDS (5 blocks/CU). grid = (ceil(n/128), 2).
// 16 col-groups (4 cols) x 16 row-groups (8 rows each).

__global__ __launch_bounds__(256) void gemm_k128_f128(
    const float* __restrict__ A, const float* __restrict__ W,
    unsigned short* __restrict__ out, int n) {
  __shared__ float shW[HD * 64];
  const int colbase = blockIdx.y * 64;
  {
    // stage W[:, colbase:colbase+64]: 8 float4 per thread, coalesced
#pragma unroll
    for (int i = 0; i < 8; ++i) {
      int flat = (i * 256 + threadIdx.x) * 4;   // 0..8188, step 4
      int r = flat >> 6;                        // row 0..127
      int c = flat & 63;                        // col 0..60
      *(float4*)(shW + flat) = *(const float4*)(W + r * HD + colbase + c);
    }
  }
  __syncthreads();

  const int jg = (threadIdx.x & 15) * 4;        // col offset in half: 0..60
  const int rs = threadIdx.x >> 4;              // 0..15
  const int row0 = blockIdx.x * 128 + rs * 8;   // 8 rows per thread
  const int nm1 = n - 1;
  const float* a[8];
#pragma unroll
  for (int r = 0; r < 8; ++r) a[r] = A + (size_t)min(row0 + r, nm1) * HD;

  float4 acc[8];
#pragma unroll
  for (int r = 0; r < 8; ++r) acc[r] = make_float4(0.f, 0.f, 0.f, 0.f);

  for (int k = 0; k < HD; k += 4) {
    const float* wb = shW + k * 64 + jg;
    float4 w0 = *(const float4*)(wb);
    float4 w1 = *(const float4*)(wb + 64);
    float4 w2 = *(const float4*)(wb + 128);
    float4 w3 = *(const float4*)(wb + 192);
#pragma unroll
    for (int r = 0; r < 8; ++r) {
      float4 xv = *(const float4*)(a[r] + k);
      acc[r] = fma4(xv.w, w3, fma4(xv.z, w2, fma4(xv.y, w1, fma4(xv.x, w0, acc[r]))));
    }
  }
#pragma unroll
  for (int r = 0; r < 8; ++r) {
    if (row0 + r < n) {
      uint2 p;
      p.x = packbf2(acc[r].x, acc[r].y);
      p.y = packbf2(acc[r].z, acc[r].w);
      *(uint2*)(out + (size_t)(row0 + r) * HD + colbase + jg) = p;
    }
  }
}

// ---- dense GEMM: out[n x 40](bf16) = A[n x 128](f32) @ W[128 x 40] --------
// block = 320 threads: 10 col-groups (4 cols) x 32 row-groups (4 rows each).
// W fully staged in LDS (20 KiB); 128 rows per block.

__global__ __launch_bounds__(320) void gemm_k128_f40(
    const float* __restrict__ A, const float* __restrict__ W,
    unsigned short* __restrict__ out, int n) {
  __shared__ float shW[HD * NC];
  {
    const float4* Wv = (const float4*)W;
    float4* shWv = (float4*)shW;
    for (int t = threadIdx.x; t < HD * NC / 4; t += 320) shWv[t] = Wv[t];
  }
  __syncthreads();

  const int cg = threadIdx.x % 10;
  const int rg = threadIdx.x / 10;             // 0..31
  const int jg = cg * 4;                       // col offset 0..36
  const int row0 = blockIdx.x * 128 + rg * 4;
  const int nm1 = n - 1;
  const float* a[4];
#pragma unroll
  for (int r = 0; r < 4; ++r) a[r] = A + (size_t)min(row0 + r, nm1) * HD;

  float4 acc[4];
#pragma unroll
  for (int r = 0; r < 4; ++r) acc[r] = make_float4(0.f, 0.f, 0.f, 0.f);

  for (int k = 0; k < HD; k += 4) {
    const float* wb = shW + k * NC + jg;
    float4 w0 = *(const float4*)(wb);
    float4 w1 = *(const float4*)(wb + NC);
    float4 w2 = *(const float4*)(wb + 2 * NC);
    float4 w3 = *(const float4*)(wb + 3 * NC);
#pragma unroll
    for (int r = 0; r < 4; ++r) {
      float4 xv = *(const float4*)(a[r] + k);
      acc[r] = fma4(xv.w, w3, fma4(xv.z, w2, fma4(xv.y, w1, fma4(xv.x, w0, acc[r]))));
    }
  }
#pragma unroll
  for (int r = 0; r < 4; ++r) {
    if (row0 + r < n) {
      uint2 p;
      p.x = packbf2(acc[r].x, acc[r].y);
      p.y = packbf2(acc[r].z, acc[r].w);
      *(uint2*)(out + (size_t)(row0 + r) * NC + jg) = p;
    }
  }
}

// ---- aggregation, F=128 (bf16 gathers, packed norm): wave per node --------

__global__ __launch_bounds__(256) void agg_f128(
    const unsigned short* __restrict__ xw, const float* __restrict__ resid,
    const float* __restrict__ bias, const float* __restrict__ dinv,
    const int* __restrict__ row_start, const int* __restrict__ row_end,
    const int2* __restrict__ csr2, float* __restrict__ out, int n) {
  int node = (blockIdx.x * 256 + threadIdx.x) >> 6;
  if (node >= n) return;
  int lane = threadIdx.x & 63;
  int f = lane * 2;
  float di = dinv[node];
  float2 bv = *(const float2*)(bias + f);
  float2 sv = bf2f2(*(const unsigned int*)(xw + (size_t)node * HD + f));
  float sw = di * di;
  float axA = fmaf(sv.x, sw, bv.x);
  float ayA = fmaf(sv.y, sw, bv.y);
  float axB = 0.f, ayB = 0.f;
  int k = row_start[node];
  const int end = row_end[node];
  for (; k + 8 <= end; k += 8) {
    int2 c0 = csr2[k],     c1 = csr2[k + 1], c2 = csr2[k + 2], c3 = csr2[k + 3];
    int2 c4 = csr2[k + 4], c5 = csr2[k + 5], c6 = csr2[k + 6], c7 = csr2[k + 7];
    unsigned int u0 = *(const unsigned int*)(xw + (size_t)c0.x * HD + f);
    unsigned int u1 = *(const unsigned int*)(xw + (size_t)c1.x * HD + f);
    unsigned int u2 = *(const unsigned int*)(xw + (size_t)c2.x * HD + f);
    unsigned int u3 = *(const unsigned int*)(xw + (size_t)c3.x * HD + f);
    unsigned int u4 = *(const unsigned int*)(xw + (size_t)c4.x * HD + f);
    unsigned int u5 = *(const unsigned int*)(xw + (size_t)c5.x * HD + f);
    unsigned int u6 = *(const unsigned int*)(xw + (size_t)c6.x * HD + f);
    unsigned int u7 = *(const unsigned int*)(xw + (size_t)c7.x * HD + f);
    float2 v0 = bf2f2(u0), v1 = bf2f2(u1), v2 = bf2f2(u2), v3 = bf2f2(u3);
    float2 v4 = bf2f2(u4), v5 = bf2f2(u5), v6 = bf2f2(u6), v7 = bf2f2(u7);
    float w0 = __int_as_float(c0.y), w1 = __int_as_float(c1.y);
    float w2 = __int_as_float(c2.y), w3 = __int_as_float(c3.y);
    float w4 = __int_as_float(c4.y), w5 = __int_as_float(c5.y);
    float w6 = __int_as_float(c6.y), w7 = __int_as_float(c7.y);
    axA = fmaf(v0.x, w0, axA); ayA = fmaf(v0.y, w0, ayA);
    axB = fmaf(v1.x, w1, axB); ayB = fmaf(v1.y, w1, ayB);
    axA = fmaf(v2.x, w2, axA); ayA = fmaf(v2.y, w2, ayA);
    axB = fmaf(v3.x, w3, axB); ayB = fmaf(v3.y, w3, ayB);
    axA = fmaf(v4.x, w4, axA); ayA = fmaf(v4.y, w4, ayA);
    axB = fmaf(v5.x, w5, axB); ayB = fmaf(v5.y, w5, ayB);
    axA = fmaf(v6.x, w6, axA); ayA = fmaf(v6.y, w6, ayA);
    axB = fmaf(v7.x, w7, axB); ayB = fmaf(v7.y, w7, ayB);
  }
  for (; k + 4 <= end; k += 4) {
    int2 c0 = csr2[k], c1 = csr2[k + 1], c2 = csr2[k + 2], c3 = csr2[k + 3];
    unsigned int u0 = *(const unsigned int*)(xw + (size_t)c0.x * HD + f);
    unsigned int u1 = *(const unsigned int*)(xw + (size_t)c1.x * HD + f);
    unsigned int u2 = *(const unsigned int*)(xw + (size_t)c2.x * HD + f);
    unsigned int u3 = *(const unsigned int*)(xw + (size_t)c3.x * HD + f);
    float2 v0 = bf2f2(u0), v1 = bf2f2(u1), v2 = bf2f2(u2), v3 = bf2f2(u3);
    float w0 = __int_as_float(c0.y), w1 = __int_as_float(c1.y);
    float w2 = __int_as_float(c2.y), w3 = __int_as_float(c3.y);
    axA = fmaf(v0.x, w0, axA); ayA = fmaf(v0.y, w0, ayA);
    axB = fmaf(v1.x, w1, axB); ayB = fmaf(v1.y, w1, ayB);
    axA = fmaf(v2.x, w2, axA); ayA = fmaf(v2.y, w2, ayA);
    axB = fmaf(v3.x, w3, axB); ayB = fmaf(v3.y, w3, ayB);
  }
  for (; k < end; ++k) {
    int2 c = csr2[k];
    float w = __int_as_float(c.y);
    float2 v = bf2f2(*(const unsigned int*)(xw + (size_t)c.x * HD + f));
    axA = fmaf(v.x, w, axA);
    ayA = fmaf(v.y, w, ayA);
  }
  float ax = axA + axB, ay = ayA + ayB;
  float2 r = *(const float2*)(resid + (size_t)node * HD + f);
  float2 o;
  o.x = fmaxf(ax, 0.f) + r.x;
  o.y = fmaxf(ay, 0.f) + r.y;
  *(float2*)(out + (size_t)node * HD + f) = o;
}

// ---- aggregation, F=40 (bf16, packed norm) + log_softmax ------------------

__global__ __launch_bounds__(256) void agg_f40_lsm(
    const unsigned short* __restrict__ xw, const float* __restrict__ dinv,
    const int* __restrict__ row_start, const int* __restrict__ row_end,
    const int2* __restrict__ csr2, const float* __restrict__ bias,
    float* __restrict__ out, int n) {
  int node = (blockIdx.x * 256 + threadIdx.x) >> 6;
  if (node >= n) return;
  int lane = threadIdx.x & 63;
  const bool active = lane < NC;
  float di = dinv[node];
  float acc = 0.f;
  if (active) acc = fmaf(bf2f(xw[(size_t)node * NC + lane]), di * di, bias[lane]);
  int k = row_start[node];
  const int end = row_end[node];
  for (; k + 4 <= end; k += 4) {
    int2 c0 = csr2[k], c1 = csr2[k + 1], c2 = csr2[k + 2], c3 = csr2[k + 3];
    if (active) {
      float v0 = bf2f(xw[(size_t)c0.x * NC + lane]);
      float v1 = bf2f(xw[(size_t)c1.x * NC + lane]);
      float v2 = bf2f(xw[(size_t)c2.x * NC + lane]);
      float v3 = bf2f(xw[(size_t)c3.x * NC + lane]);
      acc = fmaf(v0, __int_as_float(c0.y), acc);
      acc = fmaf(v1, __int_as_float(c1.y), acc);
      acc = fmaf(v2, __int_as_float(c2.y), acc);
      acc = fmaf(v3, __int_as_float(c3.y), acc);
    }
  }
  for (; k < end; ++k) {
    int2 c = csr2[k];
    if (active) acc = fmaf(bf2f(xw[(size_t)c.x * NC + lane]), __int_as_float(c.y), acc);
  }
  // log_softmax over lanes 0..39
  float m = active ? acc : -3.0e38f;
  for (int off = 32; off >= 1; off >>= 1) m = fmaxf(m, __shfl_xor(m, off, 64));
  float e = active ? expf(acc - m) : 0.f;
  float ssum = e;
  for (int off = 32; off >= 1; off >>= 1) ssum += __shfl_xor(ssum, off, 64);
  if (active) out[(size_t)node * NC + lane] = acc - m - logf(ssum);
}

// ---------------------------------------------------------------------------

extern "C" void kernel_launch(void* const* d_in, const int* in_sizes, int n_in,
                              void* d_out, int out_size, void* d_ws, size_t ws_size,
                              hipStream_t stream) {
  const float* x  = (const float*)d_in[0];
  const int*   ei = (const int*)d_in[1];
  const float* W1 = (const float*)d_in[2];
  const float* b1 = (const float*)d_in[3];
  const float* W2 = (const float*)d_in[4];
  const float* b2 = (const float*)d_in[5];
  const float* W3 = (const float*)d_in[6];
  const float* b3 = (const float*)d_in[7];
  float* out = (float*)d_out;

  const int n = in_sizes[0] / HD;  // 50000
  const int E = in_sizes[1] / 2;   // 800000
  const int* src = ei;
  const int* dst = ei + E;

  // workspace carve (all 256B-aligned)
  char* ws = (char*)d_ws;
  size_t off = 0;
  auto carve = [&](size_t bytes) -> void* {
    void* p = ws + off;
    off += (bytes + 255) & ~(size_t)255;
    return p;
  };
  int*   cnt       = (int*)carve((size_t)n * 4);
  int*   row_start = (int*)carve((size_t)n * 4);
  int*   row_end   = (int*)carve((size_t)n * 4);
  float* dinv      = (float*)carve((size_t)n * 4);
  int2*  nodeinfo  = (int2*)carve((size_t)n * 8);
  int*   gtotal    = (int*)carve(256);
  int2*  csr2      = (int2*)carve((size_t)E * 8);
  unsigned short* xwb = (unsigned short*)carve((size_t)n * HD * 2);  // bf16 xw
  float* bufB      = (float*)carve((size_t)n * HD * 4);              // h (f32)
  // rank[] is only live before the first GEMM writes bufB -> alias it.
  int*   rank      = (int*)bufB;

  const int gn   = (n + 255) / 256;
  const int gE4  = (E + 1023) / 1024;     // 4 edges per thread
  const int gW   = (n + 3) / 4;           // one wave per node, 4 waves/block
  const int g40  = (n + 127) / 128;       // 128 rows per f40 gemm block
  dim3 gG((n + 127) / 128, 2);            // 128 rows x 64-col half per block

  // CSR build
  k_init<<<gn, 256, 0, stream>>>(cnt, gtotal, n);
  k_count_rank<<<gE4, 256, 0, stream>>>(dst, cnt, rank, E);
  k_alloc<<<gn, 256, 0, stream>>>(cnt, row_start, row_end, nodeinfo, dinv, gtotal, n);
  k_fill<<<gE4, 256, 0, stream>>>(src, dst, rank, nodeinfo, dinv, csr2, E);

  // layer 1: xw = x@W1 -> xwb(bf16) ; h1 = relu(agg)+x -> bufB
  gemm_k128_f128<<<gG, 256, 0, stream>>>(x, W1, xwb, n);
  agg_f128<<<gW, 256, 0, stream>>>(xwb, x, b1, dinv, row_start, row_end, csr2, bufB, n);

  // layer 2: xw = h1@W2 -> xwb ; h2 = relu(agg)+h1 -> bufB (in-place resid OK)
  gemm_k128_f128<<<gG, 256, 0, stream>>>(bufB, W2, xwb, n);
  agg_f128<<<gW, 256, 0, stream>>>(xwb, bufB, b2, dinv, row_start, row_end, csr2, bufB, n);

  // layer 3: xw = h2@W3 -> xwb(:, :40) ; out = log_softmax(agg + b3)
  gemm_k128_f40<<<g40, 320, 0, stream>>>(bufB, W3, xwb, n);
  agg_f40_lsm<<<gW, 256, 0, stream>>>(xwb, dinv, row_start, row_end, csr2, b3, out, n);
}

// Round 6
// 230.715 us; speedup vs baseline: 2.5858x; 1.2218x over previous
//
#include <hip/hip_runtime.h>
#include <math.h>

// ---------------------------------------------------------------------------
// MultiGCN: 3-layer GCN, N=50000, E=800000, D=H=128, C=40.
// Round 6: the two 128x128 GEMMs move to MFMA (mfma_f32_16x16x32_bf16).
//  - k_wprep (once): W1,W2 -> bf16 W^T (N x K) in global, so GEMM staging is
//    coalesced 16B loads into LDS [128][136] (pad 8 bf16 -> 2-way banks, free).
//  - gemm_mfma<A_IS_F32>: 256 thr / 64 rows x 128 cols per block. A-fragments
//    come straight from global (each element read once); layer 1 converts
//    f32->bf16 in-register, layer 2 reads the bf16 hb copy that agg_f128's
//    epilogue now writes. Accum f32 in VGPR, output rounded to bf16 xwb.
// CSR build, agg kernels, f40 VALU GEMM unchanged from round 4/5.
// ---------------------------------------------------------------------------

#define HD 128   // hidden / input feature dim
#define NC 40    // classes

typedef __attribute__((ext_vector_type(8))) short bfrag;   // 8 bf16 = 4 VGPR
typedef __attribute__((ext_vector_type(4))) float facc;    // 4 f32

__device__ __forceinline__ float4 fma4(float s, float4 w, float4 a) {
  a.x = fmaf(s, w.x, a.x);
  a.y = fmaf(s, w.y, a.y);
  a.z = fmaf(s, w.z, a.z);
  a.w = fmaf(s, w.w, a.w);
  return a;
}

// f32 -> bf16 round-to-nearest-even (finite values only)
__device__ __forceinline__ unsigned short f2bf(float f) {
  unsigned int u = __float_as_uint(f);
  u += 0x7FFFu + ((u >> 16) & 1u);
  return (unsigned short)(u >> 16);
}
__device__ __forceinline__ unsigned int packbf2(float a, float b) {
  return (unsigned int)f2bf(a) | ((unsigned int)f2bf(b) << 16);
}
__device__ __forceinline__ float2 bf2f2(unsigned int v) {
  float2 r;
  r.x = __uint_as_float(v << 16);
  r.y = __uint_as_float(v & 0xFFFF0000u);
  return r;
}
__device__ __forceinline__ float bf2f(unsigned short v) {
  return __uint_as_float((unsigned int)v << 16);
}

// ---- CSR build ------------------------------------------------------------

__global__ void k_init(int* __restrict__ cnt, int* __restrict__ gtotal, int n) {
  int i = blockIdx.x * 256 + threadIdx.x;
  if (i < n) cnt[i] = 0;
  if (i == 0) *gtotal = 0;
}

__global__ __launch_bounds__(256) void k_count_rank(
    const int* __restrict__ dst, int* __restrict__ cnt,
    int* __restrict__ rank, int E) {
  int t = blockIdx.x * 256 + threadIdx.x;
  int nt = gridDim.x * 256;
  int e0 = t, e1 = t + nt, e2 = t + 2 * nt, e3 = t + 3 * nt;
  int d0 = (e0 < E) ? dst[e0] : 0;
  int d1 = (e1 < E) ? dst[e1] : 0;
  int d2 = (e2 < E) ? dst[e2] : 0;
  int d3 = (e3 < E) ? dst[e3] : 0;
  int r0 = 0, r1 = 0, r2 = 0, r3 = 0;
  if (e0 < E) r0 = atomicAdd(&cnt[d0], 1);
  if (e1 < E) r1 = atomicAdd(&cnt[d1], 1);
  if (e2 < E) r2 = atomicAdd(&cnt[d2], 1);
  if (e3 < E) r3 = atomicAdd(&cnt[d3], 1);
  if (e0 < E) rank[e0] = r0;
  if (e1 < E) rank[e1] = r1;
  if (e2 < E) rank[e2] = r2;
  if (e3 < E) rank[e3] = r3;
}

__global__ __launch_bounds__(256) void k_alloc(
    const int* __restrict__ cnt, int* __restrict__ row_start,
    int* __restrict__ row_end, int2* __restrict__ nodeinfo,
    float* __restrict__ dinv, int* __restrict__ gtotal, int n) {
  __shared__ int sh[256];
  __shared__ int base_sh;
  const int tid = threadIdx.x;
  int i = blockIdx.x * 256 + tid;
  int v = (i < n) ? cnt[i] : 0;
  sh[tid] = v;
  __syncthreads();
  for (int off = 1; off < 256; off <<= 1) {
    int t = (tid >= off) ? sh[tid - off] : 0;
    __syncthreads();
    sh[tid] += t;
    __syncthreads();
  }
  if (tid == 255) base_sh = atomicAdd(gtotal, sh[255]);
  __syncthreads();
  if (i < n) {
    int start = base_sh + sh[tid] - v;
    float dv = rsqrtf((float)(v + 1));  // +1 self loop
    row_start[i] = start;
    row_end[i] = start + v;
    dinv[i] = dv;
    nodeinfo[i] = make_int2(start, __float_as_int(dv));
  }
}

__global__ __launch_bounds__(256) void k_fill(
    const int* __restrict__ src, const int* __restrict__ dst,
    const int* __restrict__ rank, const int2* __restrict__ nodeinfo,
    const float* __restrict__ dinv, int2* __restrict__ csr2, int E) {
  int t = blockIdx.x * 256 + threadIdx.x;
  int nt = gridDim.x * 256;
#pragma unroll
  for (int q = 0; q < 4; ++q) {
    int e = t + q * nt;
    if (e < E) {
      int d = dst[e];
      int s = src[e];
      int r = rank[e];
      int2 ni = nodeinfo[d];
      float norm = dinv[s] * __int_as_float(ni.y);
      csr2[ni.x + r] = make_int2(s, __float_as_int(norm));
    }
  }
}

// ---- W prep: W (f32, K x N row-major) -> Wt (bf16, N x K row-major) -------
// grid = 2 blocks (one per weight matrix), 256 threads.

__global__ __launch_bounds__(256) void k_wprep(
    const float* __restrict__ W1, const float* __restrict__ W2,
    unsigned short* __restrict__ W1t, unsigned short* __restrict__ W2t) {
  const float* W = blockIdx.x ? W2 : W1;
  unsigned short* Wt = blockIdx.x ? W2t : W1t;
  __shared__ unsigned short sh[HD * 136];
#pragma unroll
  for (int i = 0; i < 16; ++i) {
    int f4 = i * 256 + threadIdx.x;     // float4 id 0..4095
    int r = f4 >> 5;                    // k row
    int c = (f4 & 31) * 4;              // n col
    float4 v = *(const float4*)(W + r * HD + c);
    sh[(c + 0) * 136 + r] = f2bf(v.x);
    sh[(c + 1) * 136 + r] = f2bf(v.y);
    sh[(c + 2) * 136 + r] = f2bf(v.z);
    sh[(c + 3) * 136 + r] = f2bf(v.w);
  }
  __syncthreads();
#pragma unroll
  for (int i = 0; i < 8; ++i) {
    int g = i * 256 + threadIdx.x;      // 16B chunk id 0..2047
    int nrow = g >> 4, k16 = g & 15;
    uint4 v = *(const uint4*)(&sh[nrow * 136 + k16 * 8]);
    *(uint4*)(Wt + (size_t)g * 8) = v;
  }
}

// ---- MFMA GEMM: out[n x 128](bf16) = A[n x 128] @ W[128 x 128] ------------
// Wt: bf16 W^T (N x K). Block = 256 thr (4 waves), 64 rows x 128 cols.
// Per wave: 16 rows; A-frags from global (4x b128/lane), B-frags from LDS.

template <bool A_IS_F32>
__global__ __launch_bounds__(256) void gemm_mfma_f128(
    const float* __restrict__ Af, const unsigned short* __restrict__ Ab,
    const unsigned short* __restrict__ Wt,
    unsigned short* __restrict__ out, int n) {
  __shared__ unsigned short shWt[HD * 136];   // [n][k], pad 8 bf16/row
  {
#pragma unroll
    for (int i = 0; i < 8; ++i) {
      int g = i * 256 + threadIdx.x;          // 16B chunk 0..2047
      int nrow = g >> 4, k16 = g & 15;
      uint4 v = *(const uint4*)(Wt + (size_t)g * 8);
      *(uint4*)(&shWt[nrow * 136 + k16 * 8]) = v;
    }
  }

  const int lane = threadIdx.x & 63;
  const int w = threadIdx.x >> 6;             // wave 0..3
  const int m = blockIdx.x * 64 + w * 16 + (lane & 15);
  const int mc = min(m, n - 1);
  const int kbase = (lane >> 4) * 8;          // 0,8,16,24

  // A fragments: af[kk] holds A[mc][kk*32 + kbase .. +8]
  bfrag af[4];
  if constexpr (A_IS_F32) {
    const float* ap = Af + (size_t)mc * HD + kbase;
#pragma unroll
    for (int kk = 0; kk < 4; ++kk) {
      float4 lo = *(const float4*)(ap + kk * 32);
      float4 hi = *(const float4*)(ap + kk * 32 + 4);
      bfrag a;
      a[0] = (short)f2bf(lo.x); a[1] = (short)f2bf(lo.y);
      a[2] = (short)f2bf(lo.z); a[3] = (short)f2bf(lo.w);
      a[4] = (short)f2bf(hi.x); a[5] = (short)f2bf(hi.y);
      a[6] = (short)f2bf(hi.z); a[7] = (short)f2bf(hi.w);
      af[kk] = a;
    }
  } else {
    const unsigned short* ap = Ab + (size_t)mc * HD + kbase;
#pragma unroll
    for (int kk = 0; kk < 4; ++kk) af[kk] = *(const bfrag*)(ap + kk * 32);
  }

  __syncthreads();

  facc acc[8];
#pragma unroll
  for (int c = 0; c < 8; ++c) {
    acc[c][0] = 0.f; acc[c][1] = 0.f; acc[c][2] = 0.f; acc[c][3] = 0.f;
  }

#pragma unroll
  for (int kk = 0; kk < 4; ++kk) {
#pragma unroll
    for (int c = 0; c < 8; ++c) {
      bfrag bf = *(const bfrag*)(&shWt[(c * 16 + (lane & 15)) * 136 + kk * 32 + kbase]);
      acc[c] = __builtin_amdgcn_mfma_f32_16x16x32_bf16(af[kk], bf, acc[c], 0, 0, 0);
    }
  }

  // C layout: col = lane&15, row = (lane>>4)*4 + q  (within 16x16 tile)
  const int rbase = blockIdx.x * 64 + w * 16 + (lane >> 4) * 4;
  const int col = lane & 15;
#pragma unroll
  for (int c = 0; c < 8; ++c) {
#pragma unroll
    for (int q = 0; q < 4; ++q) {
      int r = rbase + q;
      if (r < n) out[(size_t)r * HD + c * 16 + col] = f2bf(acc[c][q]);
    }
  }
}

// ---- dense GEMM: out[n x 40](bf16) = A[n x 128](f32) @ W[128 x 40] --------
// block = 320 threads: 10 col-groups (4 cols) x 32 row-groups (4 rows each).

__global__ __launch_bounds__(320) void gemm_k128_f40(
    const float* __restrict__ A, const float* __restrict__ W,
    unsigned short* __restrict__ out, int n) {
  __shared__ float shW[HD * NC];
  {
    const float4* Wv = (const float4*)W;
    float4* shWv = (float4*)shW;
    for (int t = threadIdx.x; t < HD * NC / 4; t += 320) shWv[t] = Wv[t];
  }
  __syncthreads();

  const int cg = threadIdx.x % 10;
  const int rg = threadIdx.x / 10;             // 0..31
  const int jg = cg * 4;                       // col offset 0..36
  const int row0 = blockIdx.x * 128 + rg * 4;
  const int nm1 = n - 1;
  const float* a[4];
#pragma unroll
  for (int r = 0; r < 4; ++r) a[r] = A + (size_t)min(row0 + r, nm1) * HD;

  float4 acc[4];
#pragma unroll
  for (int r = 0; r < 4; ++r) acc[r] = make_float4(0.f, 0.f, 0.f, 0.f);

  for (int k = 0; k < HD; k += 4) {
    const float* wb = shW + k * NC + jg;
    float4 w0 = *(const float4*)(wb);
    float4 w1 = *(const float4*)(wb + NC);
    float4 w2 = *(const float4*)(wb + 2 * NC);
    float4 w3 = *(const float4*)(wb + 3 * NC);
#pragma unroll
    for (int r = 0; r < 4; ++r) {
      float4 xv = *(const float4*)(a[r] + k);
      acc[r] = fma4(xv.w, w3, fma4(xv.z, w2, fma4(xv.y, w1, fma4(xv.x, w0, acc[r]))));
    }
  }
#pragma unroll
  for (int r = 0; r < 4; ++r) {
    if (row0 + r < n) {
      uint2 p;
      p.x = packbf2(acc[r].x, acc[r].y);
      p.y = packbf2(acc[r].z, acc[r].w);
      *(uint2*)(out + (size_t)(row0 + r) * NC + jg) = p;
    }
  }
}

// ---- aggregation, F=128 (bf16 gathers, packed norm): wave per node --------
// Optionally writes a bf16 copy of the output row (hb) for the next MFMA GEMM.

__global__ __launch_bounds__(256) void agg_f128(
    const unsigned short* __restrict__ xw, const float* __restrict__ resid,
    const float* __restrict__ bias, const float* __restrict__ dinv,
    const int* __restrict__ row_start, const int* __restrict__ row_end,
    const int2* __restrict__ csr2, float* __restrict__ out,
    unsigned short* __restrict__ hb, int n) {
  int node = (blockIdx.x * 256 + threadIdx.x) >> 6;
  if (node >= n) return;
  int lane = threadIdx.x & 63;
  int f = lane * 2;
  float di = dinv[node];
  float2 bv = *(const float2*)(bias + f);
  float2 sv = bf2f2(*(const unsigned int*)(xw + (size_t)node * HD + f));
  float sw = di * di;
  float axA = fmaf(sv.x, sw, bv.x);
  float ayA = fmaf(sv.y, sw, bv.y);
  float axB = 0.f, ayB = 0.f;
  int k = row_start[node];
  const int end = row_end[node];
  for (; k + 8 <= end; k += 8) {
    int2 c0 = csr2[k],     c1 = csr2[k + 1], c2 = csr2[k + 2], c3 = csr2[k + 3];
    int2 c4 = csr2[k + 4], c5 = csr2[k + 5], c6 = csr2[k + 6], c7 = csr2[k + 7];
    unsigned int u0 = *(const unsigned int*)(xw + (size_t)c0.x * HD + f);
    unsigned int u1 = *(const unsigned int*)(xw + (size_t)c1.x * HD + f);
    unsigned int u2 = *(const unsigned int*)(xw + (size_t)c2.x * HD + f);
    unsigned int u3 = *(const unsigned int*)(xw + (size_t)c3.x * HD + f);
    unsigned int u4 = *(const unsigned int*)(xw + (size_t)c4.x * HD + f);
    unsigned int u5 = *(const unsigned int*)(xw + (size_t)c5.x * HD + f);
    unsigned int u6 = *(const unsigned int*)(xw + (size_t)c6.x * HD + f);
    unsigned int u7 = *(const unsigned int*)(xw + (size_t)c7.x * HD + f);
    float2 v0 = bf2f2(u0), v1 = bf2f2(u1), v2 = bf2f2(u2), v3 = bf2f2(u3);
    float2 v4 = bf2f2(u4), v5 = bf2f2(u5), v6 = bf2f2(u6), v7 = bf2f2(u7);
    float w0 = __int_as_float(c0.y), w1 = __int_as_float(c1.y);
    float w2 = __int_as_float(c2.y), w3 = __int_as_float(c3.y);
    float w4 = __int_as_float(c4.y), w5 = __int_as_float(c5.y);
    float w6 = __int_as_float(c6.y), w7 = __int_as_float(c7.y);
    axA = fmaf(v0.x, w0, axA); ayA = fmaf(v0.y, w0, ayA);
    axB = fmaf(v1.x, w1, axB); ayB = fmaf(v1.y, w1, ayB);
    axA = fmaf(v2.x, w2, axA); ayA = fmaf(v2.y, w2, ayA);
    axB = fmaf(v3.x, w3, axB); ayB = fmaf(v3.y, w3, ayB);
    axA = fmaf(v4.x, w4, axA); ayA = fmaf(v4.y, w4, ayA);
    axB = fmaf(v5.x, w5, axB); ayB = fmaf(v5.y, w5, ayB);
    axA = fmaf(v6.x, w6, axA); ayA = fmaf(v6.y, w6, ayA);
    axB = fmaf(v7.x, w7, axB); ayB = fmaf(v7.y, w7, ayB);
  }
  for (; k + 4 <= end; k += 4) {
    int2 c0 = csr2[k], c1 = csr2[k + 1], c2 = csr2[k + 2], c3 = csr2[k + 3];
    unsigned int u0 = *(const unsigned int*)(xw + (size_t)c0.x * HD + f);
    unsigned int u1 = *(const unsigned int*)(xw + (size_t)c1.x * HD + f);
    unsigned int u2 = *(const unsigned int*)(xw + (size_t)c2.x * HD + f);
    unsigned int u3 = *(const unsigned int*)(xw + (size_t)c3.x * HD + f);
    float2 v0 = bf2f2(u0), v1 = bf2f2(u1), v2 = bf2f2(u2), v3 = bf2f2(u3);
    float w0 = __int_as_float(c0.y), w1 = __int_as_float(c1.y);
    float w2 = __int_as_float(c2.y), w3 = __int_as_float(c3.y);
    axA = fmaf(v0.x, w0, axA); ayA = fmaf(v0.y, w0, ayA);
    axB = fmaf(v1.x, w1, axB); ayB = fmaf(v1.y, w1, ayB);
    axA = fmaf(v2.x, w2, axA); ayA = fmaf(v2.y, w2, ayA);
    axB = fmaf(v3.x, w3, axB); ayB = fmaf(v3.y, w3, ayB);
  }
  for (; k < end; ++k) {
    int2 c = csr2[k];
    float w = __int_as_float(c.y);
    float2 v = bf2f2(*(const unsigned int*)(xw + (size_t)c.x * HD + f));
    axA = fmaf(v.x, w, axA);
    ayA = fmaf(v.y, w, ayA);
  }
  float ax = axA + axB, ay = ayA + ayB;
  float2 r = *(const float2*)(resid + (size_t)node * HD + f);
  float2 o;
  o.x = fmaxf(ax, 0.f) + r.x;
  o.y = fmaxf(ay, 0.f) + r.y;
  *(float2*)(out + (size_t)node * HD + f) = o;
  if (hb) *(unsigned int*)(hb + (size_t)node * HD + f) = packbf2(o.x, o.y);
}

// ---- aggregation, F=40 (bf16, packed norm) + log_softmax ------------------

__global__ __launch_bounds__(256) void agg_f40_lsm(
    const unsigned short* __restrict__ xw, const float* __restrict__ dinv,
    const int* __restrict__ row_start, const int* __restrict__ row_end,
    const int2* __restrict__ csr2, const float* __restrict__ bias,
    float* __restrict__ out, int n) {
  int node = (blockIdx.x * 256 + threadIdx.x) >> 6;
  if (node >= n) return;
  int lane = threadIdx.x & 63;
  const bool active = lane < NC;
  float di = dinv[node];
  float acc = 0.f;
  if (active) acc = fmaf(bf2f(xw[(size_t)node * NC + lane]), di * di, bias[lane]);
  int k = row_start[node];
  const int end = row_end[node];
  for (; k + 4 <= end; k += 4) {
    int2 c0 = csr2[k], c1 = csr2[k + 1], c2 = csr2[k + 2], c3 = csr2[k + 3];
    if (active) {
      float v0 = bf2f(xw[(size_t)c0.x * NC + lane]);
      float v1 = bf2f(xw[(size_t)c1.x * NC + lane]);
      float v2 = bf2f(xw[(size_t)c2.x * NC + lane]);
      float v3 = bf2f(xw[(size_t)c3.x * NC + lane]);
      acc = fmaf(v0, __int_as_float(c0.y), acc);
      acc = fmaf(v1, __int_as_float(c1.y), acc);
      acc = fmaf(v2, __int_as_float(c2.y), acc);
      acc = fmaf(v3, __int_as_float(c3.y), acc);
    }
  }
  for (; k < end; ++k) {
    int2 c = csr2[k];
    if (active) acc = fmaf(bf2f(xw[(size_t)c.x * NC + lane]), __int_as_float(c.y), acc);
  }
  // log_softmax over lanes 0..39
  float m = active ? acc : -3.0e38f;
  for (int off = 32; off >= 1; off >>= 1) m = fmaxf(m, __shfl_xor(m, off, 64));
  float e = active ? expf(acc - m) : 0.f;
  float ssum = e;
  for (int off = 32; off >= 1; off >>= 1) ssum += __shfl_xor(ssum, off, 64);
  if (active) out[(size_t)node * NC + lane] = acc - m - logf(ssum);
}

// ---------------------------------------------------------------------------

extern "C" void kernel_launch(void* const* d_in, const int* in_sizes, int n_in,
                              void* d_out, int out_size, void* d_ws, size_t ws_size,
                              hipStream_t stream) {
  const float* x  = (const float*)d_in[0];
  const int*   ei = (const int*)d_in[1];
  const float* W1 = (const float*)d_in[2];
  const float* b1 = (const float*)d_in[3];
  const float* W2 = (const float*)d_in[4];
  const float* b2 = (const float*)d_in[5];
  const float* W3 = (const float*)d_in[6];
  const float* b3 = (const float*)d_in[7];
  float* out = (float*)d_out;

  const int n = in_sizes[0] / HD;  // 50000
  const int E = in_sizes[1] / 2;   // 800000
  const int* src = ei;
  const int* dst = ei + E;

  // workspace carve (all 256B-aligned)
  char* ws = (char*)d_ws;
  size_t off = 0;
  auto carve = [&](size_t bytes) -> void* {
    void* p = ws + off;
    off += (bytes + 255) & ~(size_t)255;
    return p;
  };
  int*   cnt       = (int*)carve((size_t)n * 4);
  int*   row_start = (int*)carve((size_t)n * 4);
  int*   row_end   = (int*)carve((size_t)n * 4);
  float* dinv      = (float*)carve((size_t)n * 4);
  int2*  nodeinfo  = (int2*)carve((size_t)n * 8);
  int*   gtotal    = (int*)carve(256);
  unsigned short* w1t = (unsigned short*)carve((size_t)HD * HD * 2);
  unsigned short* w2t = (unsigned short*)carve((size_t)HD * HD * 2);
  int2*  csr2      = (int2*)carve((size_t)E * 8);
  unsigned short* xwb = (unsigned short*)carve((size_t)n * HD * 2);  // bf16 xw
  unsigned short* hb  = (unsigned short*)carve((size_t)n * HD * 2);  // bf16 h1
  float* bufB      = (float*)carve((size_t)n * HD * 4);              // h (f32)
  // rank[] is only live before the first agg writes bufB -> alias it.
  int*   rank      = (int*)bufB;

  const int gn   = (n + 255) / 256;
  const int gE4  = (E + 1023) / 1024;     // 4 edges per thread
  const int gW   = (n + 3) / 4;           // one wave per node, 4 waves/block
  const int gM   = (n + 63) / 64;         // 64 rows per mfma gemm block
  const int g40  = (n + 127) / 128;       // 128 rows per f40 gemm block

  // CSR build + weight prep
  k_init<<<gn, 256, 0, stream>>>(cnt, gtotal, n);
  k_wprep<<<2, 256, 0, stream>>>(W1, W2, w1t, w2t);
  k_count_rank<<<gE4, 256, 0, stream>>>(dst, cnt, rank, E);
  k_alloc<<<gn, 256, 0, stream>>>(cnt, row_start, row_end, nodeinfo, dinv, gtotal, n);
  k_fill<<<gE4, 256, 0, stream>>>(src, dst, rank, nodeinfo, dinv, csr2, E);

  // layer 1: xw = x@W1 -> xwb(bf16) ; h1 = relu(agg)+x -> bufB (f32) + hb (bf16)
  gemm_mfma_f128<true><<<gM, 256, 0, stream>>>(x, (const unsigned short*)nullptr, w1t, xwb, n);
  agg_f128<<<gW, 256, 0, stream>>>(xwb, x, b1, dinv, row_start, row_end, csr2, bufB, hb, n);

  // layer 2: xw = h1@W2 -> xwb ; h2 = relu(agg)+h1 -> bufB (in-place resid OK)
  gemm_mfma_f128<false><<<gM, 256, 0, stream>>>((const float*)nullptr, hb, w2t, xwb, n);
  agg_f128<<<gW, 256, 0, stream>>>(xwb, bufB, b2, dinv, row_start, row_end, csr2, bufB,
                                   (unsigned short*)nullptr, n);

  // layer 3: xw = h2@W3 -> xwb(:, :40) ; out = log_softmax(agg + b3)
  gemm_k128_f40<<<g40, 320, 0, stream>>>(bufB, W3, xwb, n);
  agg_f40_lsm<<<gW, 256, 0, stream>>>(xwb, dinv, row_start, row_end, csr2, b3, out, n);
}

// Round 7
// 229.888 us; speedup vs baseline: 2.5951x; 1.0036x over previous
//
#include <hip/hip_runtime.h>
#include <math.h>

// ---------------------------------------------------------------------------
// MultiGCN: 3-layer GCN, N=50000, E=800000, D=H=128, C=40.
// Round 7: per-row-absmax INT8 gather buffers for the two f128 aggregations.
//  - gemm_mfma_f128 epilogue: 16-lane shfl_xor row-absmax reduce, quantize
//    acc to int8 (xw8) + per-row scale (xscale). No bf16 xw buffer anymore.
//  - agg_f128 gathers 128B int8 rows (was 256B bf16): w_eff = norm*scale[src],
//    dequant 2 int8/lane via sext+cvt. Gather volume 205MB -> 102MB per layer.
//  - agg_f40 path stays bf16 (accuracy margin).
// CSR build (rank-from-count, no-atomic fill), MFMA GEMMs, f40 GEMM unchanged.
// ---------------------------------------------------------------------------

#define HD 128   // hidden / input feature dim
#define NC 40    // classes

typedef __attribute__((ext_vector_type(8))) short bfrag;   // 8 bf16 = 4 VGPR
typedef __attribute__((ext_vector_type(4))) float facc;    // 4 f32

__device__ __forceinline__ float4 fma4(float s, float4 w, float4 a) {
  a.x = fmaf(s, w.x, a.x);
  a.y = fmaf(s, w.y, a.y);
  a.z = fmaf(s, w.z, a.z);
  a.w = fmaf(s, w.w, a.w);
  return a;
}

// f32 -> bf16 round-to-nearest-even (finite values only)
__device__ __forceinline__ unsigned short f2bf(float f) {
  unsigned int u = __float_as_uint(f);
  u += 0x7FFFu + ((u >> 16) & 1u);
  return (unsigned short)(u >> 16);
}
__device__ __forceinline__ unsigned int packbf2(float a, float b) {
  return (unsigned int)f2bf(a) | ((unsigned int)f2bf(b) << 16);
}
__device__ __forceinline__ float bf2f(unsigned short v) {
  return __uint_as_float((unsigned int)v << 16);
}

// ---- CSR build ------------------------------------------------------------

__global__ void k_init(int* __restrict__ cnt, int* __restrict__ gtotal, int n) {
  int i = blockIdx.x * 256 + threadIdx.x;
  if (i < n) cnt[i] = 0;
  if (i == 0) *gtotal = 0;
}

__global__ __launch_bounds__(256) void k_count_rank(
    const int* __restrict__ dst, int* __restrict__ cnt,
    int* __restrict__ rank, int E) {
  int t = blockIdx.x * 256 + threadIdx.x;
  int nt = gridDim.x * 256;
  int e0 = t, e1 = t + nt, e2 = t + 2 * nt, e3 = t + 3 * nt;
  int d0 = (e0 < E) ? dst[e0] : 0;
  int d1 = (e1 < E) ? dst[e1] : 0;
  int d2 = (e2 < E) ? dst[e2] : 0;
  int d3 = (e3 < E) ? dst[e3] : 0;
  int r0 = 0, r1 = 0, r2 = 0, r3 = 0;
  if (e0 < E) r0 = atomicAdd(&cnt[d0], 1);
  if (e1 < E) r1 = atomicAdd(&cnt[d1], 1);
  if (e2 < E) r2 = atomicAdd(&cnt[d2], 1);
  if (e3 < E) r3 = atomicAdd(&cnt[d3], 1);
  if (e0 < E) rank[e0] = r0;
  if (e1 < E) rank[e1] = r1;
  if (e2 < E) rank[e2] = r2;
  if (e3 < E) rank[e3] = r3;
}

__global__ __launch_bounds__(256) void k_alloc(
    const int* __restrict__ cnt, int* __restrict__ row_start,
    int* __restrict__ row_end, int2* __restrict__ nodeinfo,
    float* __restrict__ dinv, int* __restrict__ gtotal, int n) {
  __shared__ int sh[256];
  __shared__ int base_sh;
  const int tid = threadIdx.x;
  int i = blockIdx.x * 256 + tid;
  int v = (i < n) ? cnt[i] : 0;
  sh[tid] = v;
  __syncthreads();
  for (int off = 1; off < 256; off <<= 1) {
    int t = (tid >= off) ? sh[tid - off] : 0;
    __syncthreads();
    sh[tid] += t;
    __syncthreads();
  }
  if (tid == 255) base_sh = atomicAdd(gtotal, sh[255]);
  __syncthreads();
  if (i < n) {
    int start = base_sh + sh[tid] - v;
    float dv = rsqrtf((float)(v + 1));  // +1 self loop
    row_start[i] = start;
    row_end[i] = start + v;
    dinv[i] = dv;
    nodeinfo[i] = make_int2(start, __float_as_int(dv));
  }
}

__global__ __launch_bounds__(256) void k_fill(
    const int* __restrict__ src, const int* __restrict__ dst,
    const int* __restrict__ rank, const int2* __restrict__ nodeinfo,
    const float* __restrict__ dinv, int2* __restrict__ csr2, int E) {
  int t = blockIdx.x * 256 + threadIdx.x;
  int nt = gridDim.x * 256;
#pragma unroll
  for (int q = 0; q < 4; ++q) {
    int e = t + q * nt;
    if (e < E) {
      int d = dst[e];
      int s = src[e];
      int r = rank[e];
      int2 ni = nodeinfo[d];
      float norm = dinv[s] * __int_as_float(ni.y);
      csr2[ni.x + r] = make_int2(s, __float_as_int(norm));
    }
  }
}

// ---- W prep: W (f32, K x N row-major) -> Wt (bf16, N x K row-major) -------

__global__ __launch_bounds__(256) void k_wprep(
    const float* __restrict__ W1, const float* __restrict__ W2,
    unsigned short* __restrict__ W1t, unsigned short* __restrict__ W2t) {
  const float* W = blockIdx.x ? W2 : W1;
  unsigned short* Wt = blockIdx.x ? W2t : W1t;
  __shared__ unsigned short sh[HD * 136];
#pragma unroll
  for (int i = 0; i < 16; ++i) {
    int f4 = i * 256 + threadIdx.x;     // float4 id 0..4095
    int r = f4 >> 5;                    // k row
    int c = (f4 & 31) * 4;              // n col
    float4 v = *(const float4*)(W + r * HD + c);
    sh[(c + 0) * 136 + r] = f2bf(v.x);
    sh[(c + 1) * 136 + r] = f2bf(v.y);
    sh[(c + 2) * 136 + r] = f2bf(v.z);
    sh[(c + 3) * 136 + r] = f2bf(v.w);
  }
  __syncthreads();
#pragma unroll
  for (int i = 0; i < 8; ++i) {
    int g = i * 256 + threadIdx.x;      // 16B chunk id 0..2047
    int nrow = g >> 4, k16 = g & 15;
    uint4 v = *(const uint4*)(&sh[nrow * 136 + k16 * 8]);
    *(uint4*)(Wt + (size_t)g * 8) = v;
  }
}

// ---- MFMA GEMM + int8 quant epilogue --------------------------------------
// out row r: xw8[r*128 + j] int8, xscale[r] = rowabsmax/127.

template <bool A_IS_F32>
__global__ __launch_bounds__(256) void gemm_mfma_f128(
    const float* __restrict__ Af, const unsigned short* __restrict__ Ab,
    const unsigned short* __restrict__ Wt,
    signed char* __restrict__ xw8, float* __restrict__ xscale, int n) {
  __shared__ unsigned short shWt[HD * 136];   // [n][k], pad 8 bf16/row
  {
#pragma unroll
    for (int i = 0; i < 8; ++i) {
      int g = i * 256 + threadIdx.x;          // 16B chunk 0..2047
      int nrow = g >> 4, k16 = g & 15;
      uint4 v = *(const uint4*)(Wt + (size_t)g * 8);
      *(uint4*)(&shWt[nrow * 136 + k16 * 8]) = v;
    }
  }

  const int lane = threadIdx.x & 63;
  const int w = threadIdx.x >> 6;             // wave 0..3
  const int m = blockIdx.x * 64 + w * 16 + (lane & 15);
  const int mc = min(m, n - 1);
  const int kbase = (lane >> 4) * 8;          // 0,8,16,24

  bfrag af[4];
  if constexpr (A_IS_F32) {
    const float* ap = Af + (size_t)mc * HD + kbase;
#pragma unroll
    for (int kk = 0; kk < 4; ++kk) {
      float4 lo = *(const float4*)(ap + kk * 32);
      float4 hi = *(const float4*)(ap + kk * 32 + 4);
      bfrag a;
      a[0] = (short)f2bf(lo.x); a[1] = (short)f2bf(lo.y);
      a[2] = (short)f2bf(lo.z); a[3] = (short)f2bf(lo.w);
      a[4] = (short)f2bf(hi.x); a[5] = (short)f2bf(hi.y);
      a[6] = (short)f2bf(hi.z); a[7] = (short)f2bf(hi.w);
      af[kk] = a;
    }
  } else {
    const unsigned short* ap = Ab + (size_t)mc * HD + kbase;
#pragma unroll
    for (int kk = 0; kk < 4; ++kk) af[kk] = *(const bfrag*)(ap + kk * 32);
  }

  __syncthreads();

  facc acc[8];
#pragma unroll
  for (int c = 0; c < 8; ++c) {
    acc[c][0] = 0.f; acc[c][1] = 0.f; acc[c][2] = 0.f; acc[c][3] = 0.f;
  }

#pragma unroll
  for (int kk = 0; kk < 4; ++kk) {
#pragma unroll
    for (int c = 0; c < 8; ++c) {
      bfrag bf = *(const bfrag*)(&shWt[(c * 16 + (lane & 15)) * 136 + kk * 32 + kbase]);
      acc[c] = __builtin_amdgcn_mfma_f32_16x16x32_bf16(af[kk], bf, acc[c], 0, 0, 0);
    }
  }

  // C layout: col = lane&15, row = (lane>>4)*4 + q (within each 16-row tile).
  // Row absmax: reduce over the 16 lanes of this lane-group (xor 1,2,4,8).
  float rmax[4];
#pragma unroll
  for (int q = 0; q < 4; ++q) {
    float mx = 0.f;
#pragma unroll
    for (int c = 0; c < 8; ++c) mx = fmaxf(mx, fabsf(acc[c][q]));
    rmax[q] = mx;
  }
#pragma unroll
  for (int off = 1; off < 16; off <<= 1) {
#pragma unroll
    for (int q = 0; q < 4; ++q) rmax[q] = fmaxf(rmax[q], __shfl_xor(rmax[q], off, 64));
  }

  const int rbase = blockIdx.x * 64 + w * 16 + (lane >> 4) * 4;
  const int col = lane & 15;
#pragma unroll
  for (int q = 0; q < 4; ++q) {
    int r = rbase + q;
    if (r < n) {
      float inv = (rmax[q] > 0.f) ? (127.f / rmax[q]) : 0.f;
      if (col == q) xscale[r] = rmax[q] * (1.f / 127.f);
#pragma unroll
      for (int c = 0; c < 8; ++c) {
        int v = __float2int_rn(acc[c][q] * inv);
        xw8[(size_t)r * HD + c * 16 + col] = (signed char)v;
      }
    }
  }
}

// ---- dense GEMM: out[n x 40](bf16) = A[n x 128](f32) @ W[128 x 40] --------

__global__ __launch_bounds__(320) void gemm_k128_f40(
    const float* __restrict__ A, const float* __restrict__ W,
    unsigned short* __restrict__ out, int n) {
  __shared__ float shW[HD * NC];
  {
    const float4* Wv = (const float4*)W;
    float4* shWv = (float4*)shW;
    for (int t = threadIdx.x; t < HD * NC / 4; t += 320) shWv[t] = Wv[t];
  }
  __syncthreads();

  const int cg = threadIdx.x % 10;
  const int rg = threadIdx.x / 10;             // 0..31
  const int jg = cg * 4;                       // col offset 0..36
  const int row0 = blockIdx.x * 128 + rg * 4;
  const int nm1 = n - 1;
  const float* a[4];
#pragma unroll
  for (int r = 0; r < 4; ++r) a[r] = A + (size_t)min(row0 + r, nm1) * HD;

  float4 acc[4];
#pragma unroll
  for (int r = 0; r < 4; ++r) acc[r] = make_float4(0.f, 0.f, 0.f, 0.f);

  for (int k = 0; k < HD; k += 4) {
    const float* wb = shW + k * NC + jg;
    float4 w0 = *(const float4*)(wb);
    float4 w1 = *(const float4*)(wb + NC);
    float4 w2 = *(const float4*)(wb + 2 * NC);
    float4 w3 = *(const float4*)(wb + 3 * NC);
#pragma unroll
    for (int r = 0; r < 4; ++r) {
      float4 xv = *(const float4*)(a[r] + k);
      acc[r] = fma4(xv.w, w3, fma4(xv.z, w2, fma4(xv.y, w1, fma4(xv.x, w0, acc[r]))));
    }
  }
#pragma unroll
  for (int r = 0; r < 4; ++r) {
    if (row0 + r < n) {
      uint2 p;
      p.x = packbf2(acc[r].x, acc[r].y);
      p.y = packbf2(acc[r].z, acc[r].w);
      *(uint2*)(out + (size_t)(row0 + r) * NC + jg) = p;
    }
  }
}

// ---- aggregation, F=128 (int8 gathers + per-row scale): wave per node -----

__device__ __forceinline__ float i8lo(unsigned int u) {
  return (float)(signed char)(u & 0xFF);
}
__device__ __forceinline__ float i8hi(unsigned int u) {
  return (float)(signed char)((u >> 8) & 0xFF);
}

__global__ __launch_bounds__(256) void agg_f128(
    const signed char* __restrict__ xw8, const float* __restrict__ xscale,
    const float* __restrict__ resid, const float* __restrict__ bias,
    const float* __restrict__ dinv,
    const int* __restrict__ row_start, const int* __restrict__ row_end,
    const int2* __restrict__ csr2, float* __restrict__ out,
    unsigned short* __restrict__ hb, int n) {
  int node = (blockIdx.x * 256 + threadIdx.x) >> 6;
  if (node >= n) return;
  int lane = threadIdx.x & 63;
  int f = lane * 2;
  float di = dinv[node];
  float2 bv = *(const float2*)(bias + f);
  // self term
  unsigned int su = *(const unsigned short*)(xw8 + (size_t)node * HD + f);
  float ssc = xscale[node] * di * di;
  float axA = fmaf(i8lo(su), ssc, bv.x);
  float ayA = fmaf(i8hi(su), ssc, bv.y);
  float axB = 0.f, ayB = 0.f;
  int k = row_start[node];
  const int end = row_end[node];
  for (; k + 8 <= end; k += 8) {
    int2 c0 = csr2[k],     c1 = csr2[k + 1], c2 = csr2[k + 2], c3 = csr2[k + 3];
    int2 c4 = csr2[k + 4], c5 = csr2[k + 5], c6 = csr2[k + 6], c7 = csr2[k + 7];
    unsigned int u0 = *(const unsigned short*)(xw8 + (size_t)c0.x * HD + f);
    unsigned int u1 = *(const unsigned short*)(xw8 + (size_t)c1.x * HD + f);
    unsigned int u2 = *(const unsigned short*)(xw8 + (size_t)c2.x * HD + f);
    unsigned int u3 = *(const unsigned short*)(xw8 + (size_t)c3.x * HD + f);
    unsigned int u4 = *(const unsigned short*)(xw8 + (size_t)c4.x * HD + f);
    unsigned int u5 = *(const unsigned short*)(xw8 + (size_t)c5.x * HD + f);
    unsigned int u6 = *(const unsigned short*)(xw8 + (size_t)c6.x * HD + f);
    unsigned int u7 = *(const unsigned short*)(xw8 + (size_t)c7.x * HD + f);
    float w0 = __int_as_float(c0.y) * xscale[c0.x];
    float w1 = __int_as_float(c1.y) * xscale[c1.x];
    float w2 = __int_as_float(c2.y) * xscale[c2.x];
    float w3 = __int_as_float(c3.y) * xscale[c3.x];
    float w4 = __int_as_float(c4.y) * xscale[c4.x];
    float w5 = __int_as_float(c5.y) * xscale[c5.x];
    float w6 = __int_as_float(c6.y) * xscale[c6.x];
    float w7 = __int_as_float(c7.y) * xscale[c7.x];
    axA = fmaf(i8lo(u0), w0, axA); ayA = fmaf(i8hi(u0), w0, ayA);
    axB = fmaf(i8lo(u1), w1, axB); ayB = fmaf(i8hi(u1), w1, ayB);
    axA = fmaf(i8lo(u2), w2, axA); ayA = fmaf(i8hi(u2), w2, ayA);
    axB = fmaf(i8lo(u3), w3, axB); ayB = fmaf(i8hi(u3), w3, ayB);
    axA = fmaf(i8lo(u4), w4, axA); ayA = fmaf(i8hi(u4), w4, ayA);
    axB = fmaf(i8lo(u5), w5, axB); ayB = fmaf(i8hi(u5), w5, ayB);
    axA = fmaf(i8lo(u6), w6, axA); ayA = fmaf(i8hi(u6), w6, ayA);
    axB = fmaf(i8lo(u7), w7, axB); ayB = fmaf(i8hi(u7), w7, ayB);
  }
  for (; k + 4 <= end; k += 4) {
    int2 c0 = csr2[k], c1 = csr2[k + 1], c2 = csr2[k + 2], c3 = csr2[k + 3];
    unsigned int u0 = *(const unsigned short*)(xw8 + (size_t)c0.x * HD + f);
    unsigned int u1 = *(const unsigned short*)(xw8 + (size_t)c1.x * HD + f);
    unsigned int u2 = *(const unsigned short*)(xw8 + (size_t)c2.x * HD + f);
    unsigned int u3 = *(const unsigned short*)(xw8 + (size_t)c3.x * HD + f);
    float w0 = __int_as_float(c0.y) * xscale[c0.x];
    float w1 = __int_as_float(c1.y) * xscale[c1.x];
    float w2 = __int_as_float(c2.y) * xscale[c2.x];
    float w3 = __int_as_float(c3.y) * xscale[c3.x];
    axA = fmaf(i8lo(u0), w0, axA); ayA = fmaf(i8hi(u0), w0, ayA);
    axB = fmaf(i8lo(u1), w1, axB); ayB = fmaf(i8hi(u1), w1, ayB);
    axA = fmaf(i8lo(u2), w2, axA); ayA = fmaf(i8hi(u2), w2, ayA);
    axB = fmaf(i8lo(u3), w3, axB); ayB = fmaf(i8hi(u3), w3, ayB);
  }
  for (; k < end; ++k) {
    int2 c = csr2[k];
    unsigned int u = *(const unsigned short*)(xw8 + (size_t)c.x * HD + f);
    float w = __int_as_float(c.y) * xscale[c.x];
    axA = fmaf(i8lo(u), w, axA);
    ayA = fmaf(i8hi(u), w, ayA);
  }
  float ax = axA + axB, ay = ayA + ayB;
  float2 r = *(const float2*)(resid + (size_t)node * HD + f);
  float2 o;
  o.x = fmaxf(ax, 0.f) + r.x;
  o.y = fmaxf(ay, 0.f) + r.y;
  *(float2*)(out + (size_t)node * HD + f) = o;
  if (hb) *(unsigned int*)(hb + (size_t)node * HD + f) = packbf2(o.x, o.y);
}

// ---- aggregation, F=40 (bf16, packed norm) + log_softmax ------------------

__global__ __launch_bounds__(256) void agg_f40_lsm(
    const unsigned short* __restrict__ xw, const float* __restrict__ dinv,
    const int* __restrict__ row_start, const int* __restrict__ row_end,
    const int2* __restrict__ csr2, const float* __restrict__ bias,
    float* __restrict__ out, int n) {
  int node = (blockIdx.x * 256 + threadIdx.x) >> 6;
  if (node >= n) return;
  int lane = threadIdx.x & 63;
  const bool active = lane < NC;
  float di = dinv[node];
  float acc = 0.f;
  if (active) acc = fmaf(bf2f(xw[(size_t)node * NC + lane]), di * di, bias[lane]);
  int k = row_start[node];
  const int end = row_end[node];
  for (; k + 4 <= end; k += 4) {
    int2 c0 = csr2[k], c1 = csr2[k + 1], c2 = csr2[k + 2], c3 = csr2[k + 3];
    if (active) {
      float v0 = bf2f(xw[(size_t)c0.x * NC + lane]);
      float v1 = bf2f(xw[(size_t)c1.x * NC + lane]);
      float v2 = bf2f(xw[(size_t)c2.x * NC + lane]);
      float v3 = bf2f(xw[(size_t)c3.x * NC + lane]);
      acc = fmaf(v0, __int_as_float(c0.y), acc);
      acc = fmaf(v1, __int_as_float(c1.y), acc);
      acc = fmaf(v2, __int_as_float(c2.y), acc);
      acc = fmaf(v3, __int_as_float(c3.y), acc);
    }
  }
  for (; k < end; ++k) {
    int2 c = csr2[k];
    if (active) acc = fmaf(bf2f(xw[(size_t)c.x * NC + lane]), __int_as_float(c.y), acc);
  }
  // log_softmax over lanes 0..39
  float m = active ? acc : -3.0e38f;
  for (int off = 32; off >= 1; off >>= 1) m = fmaxf(m, __shfl_xor(m, off, 64));
  float e = active ? expf(acc - m) : 0.f;
  float ssum = e;
  for (int off = 32; off >= 1; off >>= 1) ssum += __shfl_xor(ssum, off, 64);
  if (active) out[(size_t)node * NC + lane] = acc - m - logf(ssum);
}

// ---------------------------------------------------------------------------

extern "C" void kernel_launch(void* const* d_in, const int* in_sizes, int n_in,
                              void* d_out, int out_size, void* d_ws, size_t ws_size,
                              hipStream_t stream) {
  const float* x  = (const float*)d_in[0];
  const int*   ei = (const int*)d_in[1];
  const float* W1 = (const float*)d_in[2];
  const float* b1 = (const float*)d_in[3];
  const float* W2 = (const float*)d_in[4];
  const float* b2 = (const float*)d_in[5];
  const float* W3 = (const float*)d_in[6];
  const float* b3 = (const float*)d_in[7];
  float* out = (float*)d_out;

  const int n = in_sizes[0] / HD;  // 50000
  const int E = in_sizes[1] / 2;   // 800000
  const int* src = ei;
  const int* dst = ei + E;

  // workspace carve (all 256B-aligned)
  char* ws = (char*)d_ws;
  size_t off = 0;
  auto carve = [&](size_t bytes) -> void* {
    void* p = ws + off;
    off += (bytes + 255) & ~(size_t)255;
    return p;
  };
  int*   cnt       = (int*)carve((size_t)n * 4);
  int*   row_start = (int*)carve((size_t)n * 4);
  int*   row_end   = (int*)carve((size_t)n * 4);
  float* dinv      = (float*)carve((size_t)n * 4);
  int2*  nodeinfo  = (int2*)carve((size_t)n * 8);
  int*   gtotal    = (int*)carve(256);
  unsigned short* w1t = (unsigned short*)carve((size_t)HD * HD * 2);
  unsigned short* w2t = (unsigned short*)carve((size_t)HD * HD * 2);
  int2*  csr2      = (int2*)carve((size_t)E * 8);
  signed char* xw8 = (signed char*)carve((size_t)n * HD);            // int8 xw
  float* xscale    = (float*)carve((size_t)n * 4);                   // row scales
  unsigned short* xw40 = (unsigned short*)carve((size_t)n * NC * 2); // bf16 xw3
  unsigned short* hb  = (unsigned short*)carve((size_t)n * HD * 2);  // bf16 h1
  float* bufB      = (float*)carve((size_t)n * HD * 4);              // h (f32)
  // rank[] is only live before the first agg writes bufB -> alias it.
  int*   rank      = (int*)bufB;

  const int gn   = (n + 255) / 256;
  const int gE4  = (E + 1023) / 1024;     // 4 edges per thread
  const int gW   = (n + 3) / 4;           // one wave per node, 4 waves/block
  const int gM   = (n + 63) / 64;         // 64 rows per mfma gemm block
  const int g40  = (n + 127) / 128;       // 128 rows per f40 gemm block

  // CSR build + weight prep
  k_init<<<gn, 256, 0, stream>>>(cnt, gtotal, n);
  k_wprep<<<2, 256, 0, stream>>>(W1, W2, w1t, w2t);
  k_count_rank<<<gE4, 256, 0, stream>>>(dst, cnt, rank, E);
  k_alloc<<<gn, 256, 0, stream>>>(cnt, row_start, row_end, nodeinfo, dinv, gtotal, n);
  k_fill<<<gE4, 256, 0, stream>>>(src, dst, rank, nodeinfo, dinv, csr2, E);

  // layer 1: xw = x@W1 -> xw8+xscale ; h1 = relu(agg)+x -> bufB (f32) + hb (bf16)
  gemm_mfma_f128<true><<<gM, 256, 0, stream>>>(x, (const unsigned short*)nullptr, w1t, xw8, xscale, n);
  agg_f128<<<gW, 256, 0, stream>>>(xw8, xscale, x, b1, dinv, row_start, row_end, csr2, bufB, hb, n);

  // layer 2: xw = h1@W2 -> xw8+xscale ; h2 = relu(agg)+h1 -> bufB (in-place resid OK)
  gemm_mfma_f128<false><<<gM, 256, 0, stream>>>((const float*)nullptr, hb, w2t, xw8, xscale, n);
  agg_f128<<<gW, 256, 0, stream>>>(xw8, xscale, bufB, b2, dinv, row_start, row_end, csr2, bufB,
                                   (unsigned short*)nullptr, n);

  // layer 3: xw = h2@W3 -> xw40(bf16) ; out = log_softmax(agg + b3)
  gemm_k128_f40<<<g40, 320, 0, stream>>>(bufB, W3, xw40, n);
  agg_f40_lsm<<<gW, 256, 0, stream>>>(xw40, dinv, row_start, row_end, csr2, b3, out, n);
}

// Round 8
// 204.207 us; speedup vs baseline: 2.9214x; 1.1258x over previous
//
#include <hip/hip_runtime.h>
#include <math.h>

// ---------------------------------------------------------------------------
// MultiGCN: 3-layer GCN, N=50000, E=800000, D=H=128, C=40.
// Round 8: attack latency-boundness of the gather phase.
//  - agg_f128: 4 nodes per wave (16 lanes/node, uint2 = 8 int8 per lane).
//    One VMEM gather instruction now serves 4 edges -> 4x fewer gather
//    instructions and 4x fewer waves (12.5k, ~all resident).
//  - k_count_rank: 1 edge/thread, 3125 blocks (was 782 at 24% occupancy).
// GEMMs (MFMA + f40), CSR fill, agg_f40 unchanged from round 7.
// ---------------------------------------------------------------------------

#define HD 128   // hidden / input feature dim
#define NC 40    // classes

typedef __attribute__((ext_vector_type(8))) short bfrag;   // 8 bf16 = 4 VGPR
typedef __attribute__((ext_vector_type(4))) float facc;    // 4 f32

__device__ __forceinline__ float4 fma4(float s, float4 w, float4 a) {
  a.x = fmaf(s, w.x, a.x);
  a.y = fmaf(s, w.y, a.y);
  a.z = fmaf(s, w.z, a.z);
  a.w = fmaf(s, w.w, a.w);
  return a;
}

// f32 -> bf16 round-to-nearest-even (finite values only)
__device__ __forceinline__ unsigned short f2bf(float f) {
  unsigned int u = __float_as_uint(f);
  u += 0x7FFFu + ((u >> 16) & 1u);
  return (unsigned short)(u >> 16);
}
__device__ __forceinline__ unsigned int packbf2(float a, float b) {
  return (unsigned int)f2bf(a) | ((unsigned int)f2bf(b) << 16);
}
__device__ __forceinline__ float bf2f(unsigned short v) {
  return __uint_as_float((unsigned int)v << 16);
}
// signed byte i (0..3) of u, as float
__device__ __forceinline__ float db(unsigned int u, int i) {
  return (float)(signed char)((u >> (8 * i)) & 0xFFu);
}

// ---- CSR build ------------------------------------------------------------

__global__ void k_init(int* __restrict__ cnt, int* __restrict__ gtotal, int n) {
  int i = blockIdx.x * 256 + threadIdx.x;
  if (i < n) cnt[i] = 0;
  if (i == 0) *gtotal = 0;
}

// 1 edge/thread: maximize resident waves for atomic latency hiding
__global__ __launch_bounds__(256) void k_count_rank(
    const int* __restrict__ dst, int* __restrict__ cnt,
    int* __restrict__ rank, int E) {
  int e = blockIdx.x * 256 + threadIdx.x;
  if (e < E) rank[e] = atomicAdd(&cnt[dst[e]], 1);
}

__global__ __launch_bounds__(256) void k_alloc(
    const int* __restrict__ cnt, int* __restrict__ row_start,
    int* __restrict__ row_end, int2* __restrict__ nodeinfo,
    float* __restrict__ dinv, int* __restrict__ gtotal, int n) {
  __shared__ int sh[256];
  __shared__ int base_sh;
  const int tid = threadIdx.x;
  int i = blockIdx.x * 256 + tid;
  int v = (i < n) ? cnt[i] : 0;
  sh[tid] = v;
  __syncthreads();
  for (int off = 1; off < 256; off <<= 1) {
    int t = (tid >= off) ? sh[tid - off] : 0;
    __syncthreads();
    sh[tid] += t;
    __syncthreads();
  }
  if (tid == 255) base_sh = atomicAdd(gtotal, sh[255]);
  __syncthreads();
  if (i < n) {
    int start = base_sh + sh[tid] - v;
    float dv = rsqrtf((float)(v + 1));  // +1 self loop
    row_start[i] = start;
    row_end[i] = start + v;
    dinv[i] = dv;
    nodeinfo[i] = make_int2(start, __float_as_int(dv));
  }
}

__global__ __launch_bounds__(256) void k_fill(
    const int* __restrict__ src, const int* __restrict__ dst,
    const int* __restrict__ rank, const int2* __restrict__ nodeinfo,
    const float* __restrict__ dinv, int2* __restrict__ csr2, int E) {
  int t = blockIdx.x * 256 + threadIdx.x;
  int nt = gridDim.x * 256;
#pragma unroll
  for (int q = 0; q < 4; ++q) {
    int e = t + q * nt;
    if (e < E) {
      int d = dst[e];
      int s = src[e];
      int r = rank[e];
      int2 ni = nodeinfo[d];
      float norm = dinv[s] * __int_as_float(ni.y);
      csr2[ni.x + r] = make_int2(s, __float_as_int(norm));
    }
  }
}

// ---- W prep: W (f32, K x N row-major) -> Wt (bf16, N x K row-major) -------

__global__ __launch_bounds__(256) void k_wprep(
    const float* __restrict__ W1, const float* __restrict__ W2,
    unsigned short* __restrict__ W1t, unsigned short* __restrict__ W2t) {
  const float* W = blockIdx.x ? W2 : W1;
  unsigned short* Wt = blockIdx.x ? W2t : W1t;
  __shared__ unsigned short sh[HD * 136];
#pragma unroll
  for (int i = 0; i < 16; ++i) {
    int f4 = i * 256 + threadIdx.x;     // float4 id 0..4095
    int r = f4 >> 5;                    // k row
    int c = (f4 & 31) * 4;              // n col
    float4 v = *(const float4*)(W + r * HD + c);
    sh[(c + 0) * 136 + r] = f2bf(v.x);
    sh[(c + 1) * 136 + r] = f2bf(v.y);
    sh[(c + 2) * 136 + r] = f2bf(v.z);
    sh[(c + 3) * 136 + r] = f2bf(v.w);
  }
  __syncthreads();
#pragma unroll
  for (int i = 0; i < 8; ++i) {
    int g = i * 256 + threadIdx.x;      // 16B chunk id 0..2047
    int nrow = g >> 4, k16 = g & 15;
    uint4 v = *(const uint4*)(&sh[nrow * 136 + k16 * 8]);
    *(uint4*)(Wt + (size_t)g * 8) = v;
  }
}

// ---- MFMA GEMM + int8 quant epilogue --------------------------------------

template <bool A_IS_F32>
__global__ __launch_bounds__(256) void gemm_mfma_f128(
    const float* __restrict__ Af, const unsigned short* __restrict__ Ab,
    const unsigned short* __restrict__ Wt,
    signed char* __restrict__ xw8, float* __restrict__ xscale, int n) {
  __shared__ unsigned short shWt[HD * 136];   // [n][k], pad 8 bf16/row
  {
#pragma unroll
    for (int i = 0; i < 8; ++i) {
      int g = i * 256 + threadIdx.x;          // 16B chunk 0..2047
      int nrow = g >> 4, k16 = g & 15;
      uint4 v = *(const uint4*)(Wt + (size_t)g * 8);
      *(uint4*)(&shWt[nrow * 136 + k16 * 8]) = v;
    }
  }

  const int lane = threadIdx.x & 63;
  const int w = threadIdx.x >> 6;             // wave 0..3
  const int m = blockIdx.x * 64 + w * 16 + (lane & 15);
  const int mc = min(m, n - 1);
  const int kbase = (lane >> 4) * 8;          // 0,8,16,24

  bfrag af[4];
  if constexpr (A_IS_F32) {
    const float* ap = Af + (size_t)mc * HD + kbase;
#pragma unroll
    for (int kk = 0; kk < 4; ++kk) {
      float4 lo = *(const float4*)(ap + kk * 32);
      float4 hi = *(const float4*)(ap + kk * 32 + 4);
      bfrag a;
      a[0] = (short)f2bf(lo.x); a[1] = (short)f2bf(lo.y);
      a[2] = (short)f2bf(lo.z); a[3] = (short)f2bf(lo.w);
      a[4] = (short)f2bf(hi.x); a[5] = (short)f2bf(hi.y);
      a[6] = (short)f2bf(hi.z); a[7] = (short)f2bf(hi.w);
      af[kk] = a;
    }
  } else {
    const unsigned short* ap = Ab + (size_t)mc * HD + kbase;
#pragma unroll
    for (int kk = 0; kk < 4; ++kk) af[kk] = *(const bfrag*)(ap + kk * 32);
  }

  __syncthreads();

  facc acc[8];
#pragma unroll
  for (int c = 0; c < 8; ++c) {
    acc[c][0] = 0.f; acc[c][1] = 0.f; acc[c][2] = 0.f; acc[c][3] = 0.f;
  }

#pragma unroll
  for (int kk = 0; kk < 4; ++kk) {
#pragma unroll
    for (int c = 0; c < 8; ++c) {
      bfrag bf = *(const bfrag*)(&shWt[(c * 16 + (lane & 15)) * 136 + kk * 32 + kbase]);
      acc[c] = __builtin_amdgcn_mfma_f32_16x16x32_bf16(af[kk], bf, acc[c], 0, 0, 0);
    }
  }

  // C layout: col = lane&15, row = (lane>>4)*4 + q (within each 16-row tile).
  float rmax[4];
#pragma unroll
  for (int q = 0; q < 4; ++q) {
    float mx = 0.f;
#pragma unroll
    for (int c = 0; c < 8; ++c) mx = fmaxf(mx, fabsf(acc[c][q]));
    rmax[q] = mx;
  }
#pragma unroll
  for (int off = 1; off < 16; off <<= 1) {
#pragma unroll
    for (int q = 0; q < 4; ++q) rmax[q] = fmaxf(rmax[q], __shfl_xor(rmax[q], off, 64));
  }

  const int rbase = blockIdx.x * 64 + w * 16 + (lane >> 4) * 4;
  const int col = lane & 15;
#pragma unroll
  for (int q = 0; q < 4; ++q) {
    int r = rbase + q;
    if (r < n) {
      float inv = (rmax[q] > 0.f) ? (127.f / rmax[q]) : 0.f;
      if (col == q) xscale[r] = rmax[q] * (1.f / 127.f);
#pragma unroll
      for (int c = 0; c < 8; ++c) {
        int v = __float2int_rn(acc[c][q] * inv);
        xw8[(size_t)r * HD + c * 16 + col] = (signed char)v;
      }
    }
  }
}

// ---- dense GEMM: out[n x 40](bf16) = A[n x 128](f32) @ W[128 x 40] --------

__global__ __launch_bounds__(320) void gemm_k128_f40(
    const float* __restrict__ A, const float* __restrict__ W,
    unsigned short* __restrict__ out, int n) {
  __shared__ float shW[HD * NC];
  {
    const float4* Wv = (const float4*)W;
    float4* shWv = (float4*)shW;
    for (int t = threadIdx.x; t < HD * NC / 4; t += 320) shWv[t] = Wv[t];
  }
  __syncthreads();

  const int cg = threadIdx.x % 10;
  const int rg = threadIdx.x / 10;             // 0..31
  const int jg = cg * 4;                       // col offset 0..36
  const int row0 = blockIdx.x * 128 + rg * 4;
  const int nm1 = n - 1;
  const float* a[4];
#pragma unroll
  for (int r = 0; r < 4; ++r) a[r] = A + (size_t)min(row0 + r, nm1) * HD;

  float4 acc[4];
#pragma unroll
  for (int r = 0; r < 4; ++r) acc[r] = make_float4(0.f, 0.f, 0.f, 0.f);

  for (int k = 0; k < HD; k += 4) {
    const float* wb = shW + k * NC + jg;
    float4 w0 = *(const float4*)(wb);
    float4 w1 = *(const float4*)(wb + NC);
    float4 w2 = *(const float4*)(wb + 2 * NC);
    float4 w3 = *(const float4*)(wb + 3 * NC);
#pragma unroll
    for (int r = 0; r < 4; ++r) {
      float4 xv = *(const float4*)(a[r] + k);
      acc[r] = fma4(xv.w, w3, fma4(xv.z, w2, fma4(xv.y, w1, fma4(xv.x, w0, acc[r]))));
    }
  }
#pragma unroll
  for (int r = 0; r < 4; ++r) {
    if (row0 + r < n) {
      uint2 p;
      p.x = packbf2(acc[r].x, acc[r].y);
      p.y = packbf2(acc[r].z, acc[r].w);
      *(uint2*)(out + (size_t)(row0 + r) * NC + jg) = p;
    }
  }
}

// ---- aggregation, F=128: 4 nodes/wave, 16 lanes/node, uint2 (8 int8)/lane --

__global__ __launch_bounds__(256) void agg_f128(
    const signed char* __restrict__ xw8, const float* __restrict__ xscale,
    const float* __restrict__ resid, const float* __restrict__ bias,
    const float* __restrict__ dinv,
    const int* __restrict__ row_start, const int* __restrict__ row_end,
    const int2* __restrict__ csr2, float* __restrict__ out,
    unsigned short* __restrict__ hb, int n) {
  const int node = (blockIdx.x * 256 + threadIdx.x) >> 4;  // 16 threads/node
  if (node >= n) return;
  const int li = threadIdx.x & 15;
  const int f0 = li * 8;

  float di = dinv[node];
  float4 b01 = *(const float4*)(bias + f0);
  float4 b23 = *(const float4*)(bias + f0 + 4);
  // self term
  uint2 su = *(const uint2*)(xw8 + (size_t)node * HD + f0);
  float ssc = xscale[node] * di * di;
  float a0 = fmaf(db(su.x, 0), ssc, b01.x);
  float a1 = fmaf(db(su.x, 1), ssc, b01.y);
  float a2 = fmaf(db(su.x, 2), ssc, b01.z);
  float a3 = fmaf(db(su.x, 3), ssc, b01.w);
  float a4 = fmaf(db(su.y, 0), ssc, b23.x);
  float a5 = fmaf(db(su.y, 1), ssc, b23.y);
  float a6 = fmaf(db(su.y, 2), ssc, b23.z);
  float a7 = fmaf(db(su.y, 3), ssc, b23.w);

  int k = row_start[node];
  const int end = row_end[node];
  for (; k + 4 <= end; k += 4) {
    int2 c0 = csr2[k], c1 = csr2[k + 1], c2 = csr2[k + 2], c3 = csr2[k + 3];
    uint2 u0 = *(const uint2*)(xw8 + (size_t)c0.x * HD + f0);
    uint2 u1 = *(const uint2*)(xw8 + (size_t)c1.x * HD + f0);
    uint2 u2 = *(const uint2*)(xw8 + (size_t)c2.x * HD + f0);
    uint2 u3 = *(const uint2*)(xw8 + (size_t)c3.x * HD + f0);
    float w0 = __int_as_float(c0.y) * xscale[c0.x];
    float w1 = __int_as_float(c1.y) * xscale[c1.x];
    float w2 = __int_as_float(c2.y) * xscale[c2.x];
    float w3 = __int_as_float(c3.y) * xscale[c3.x];
    a0 = fmaf(db(u0.x, 0), w0, a0); a1 = fmaf(db(u0.x, 1), w0, a1);
    a2 = fmaf(db(u0.x, 2), w0, a2); a3 = fmaf(db(u0.x, 3), w0, a3);
    a4 = fmaf(db(u0.y, 0), w0, a4); a5 = fmaf(db(u0.y, 1), w0, a5);
    a6 = fmaf(db(u0.y, 2), w0, a6); a7 = fmaf(db(u0.y, 3), w0, a7);
    a0 = fmaf(db(u1.x, 0), w1, a0); a1 = fmaf(db(u1.x, 1), w1, a1);
    a2 = fmaf(db(u1.x, 2), w1, a2); a3 = fmaf(db(u1.x, 3), w1, a3);
    a4 = fmaf(db(u1.y, 0), w1, a4); a5 = fmaf(db(u1.y, 1), w1, a5);
    a6 = fmaf(db(u1.y, 2), w1, a6); a7 = fmaf(db(u1.y, 3), w1, a7);
    a0 = fmaf(db(u2.x, 0), w2, a0); a1 = fmaf(db(u2.x, 1), w2, a1);
    a2 = fmaf(db(u2.x, 2), w2, a2); a3 = fmaf(db(u2.x, 3), w2, a3);
    a4 = fmaf(db(u2.y, 0), w2, a4); a5 = fmaf(db(u2.y, 1), w2, a5);
    a6 = fmaf(db(u2.y, 2), w2, a6); a7 = fmaf(db(u2.y, 3), w2, a7);
    a0 = fmaf(db(u3.x, 0), w3, a0); a1 = fmaf(db(u3.x, 1), w3, a1);
    a2 = fmaf(db(u3.x, 2), w3, a2); a3 = fmaf(db(u3.x, 3), w3, a3);
    a4 = fmaf(db(u3.y, 0), w3, a4); a5 = fmaf(db(u3.y, 1), w3, a5);
    a6 = fmaf(db(u3.y, 2), w3, a6); a7 = fmaf(db(u3.y, 3), w3, a7);
  }
  for (; k < end; ++k) {
    int2 c = csr2[k];
    uint2 u = *(const uint2*)(xw8 + (size_t)c.x * HD + f0);
    float w = __int_as_float(c.y) * xscale[c.x];
    a0 = fmaf(db(u.x, 0), w, a0); a1 = fmaf(db(u.x, 1), w, a1);
    a2 = fmaf(db(u.x, 2), w, a2); a3 = fmaf(db(u.x, 3), w, a3);
    a4 = fmaf(db(u.y, 0), w, a4); a5 = fmaf(db(u.y, 1), w, a5);
    a6 = fmaf(db(u.y, 2), w, a6); a7 = fmaf(db(u.y, 3), w, a7);
  }

  float4 r0 = *(const float4*)(resid + (size_t)node * HD + f0);
  float4 r1 = *(const float4*)(resid + (size_t)node * HD + f0 + 4);
  float4 o0, o1;
  o0.x = fmaxf(a0, 0.f) + r0.x; o0.y = fmaxf(a1, 0.f) + r0.y;
  o0.z = fmaxf(a2, 0.f) + r0.z; o0.w = fmaxf(a3, 0.f) + r0.w;
  o1.x = fmaxf(a4, 0.f) + r1.x; o1.y = fmaxf(a5, 0.f) + r1.y;
  o1.z = fmaxf(a6, 0.f) + r1.z; o1.w = fmaxf(a7, 0.f) + r1.w;
  *(float4*)(out + (size_t)node * HD + f0) = o0;
  *(float4*)(out + (size_t)node * HD + f0 + 4) = o1;
  if (hb) {
    uint4 hv;
    hv.x = packbf2(o0.x, o0.y);
    hv.y = packbf2(o0.z, o0.w);
    hv.z = packbf2(o1.x, o1.y);
    hv.w = packbf2(o1.z, o1.w);
    *(uint4*)(hb + (size_t)node * HD + f0) = hv;
  }
}

// ---- aggregation, F=40 (bf16, packed norm) + log_softmax ------------------

__global__ __launch_bounds__(256) void agg_f40_lsm(
    const unsigned short* __restrict__ xw, const float* __restrict__ dinv,
    const int* __restrict__ row_start, const int* __restrict__ row_end,
    const int2* __restrict__ csr2, const float* __restrict__ bias,
    float* __restrict__ out, int n) {
  int node = (blockIdx.x * 256 + threadIdx.x) >> 6;
  if (node >= n) return;
  int lane = threadIdx.x & 63;
  const bool active = lane < NC;
  float di = dinv[node];
  float acc = 0.f;
  if (active) acc = fmaf(bf2f(xw[(size_t)node * NC + lane]), di * di, bias[lane]);
  int k = row_start[node];
  const int end = row_end[node];
  for (; k + 4 <= end; k += 4) {
    int2 c0 = csr2[k], c1 = csr2[k + 1], c2 = csr2[k + 2], c3 = csr2[k + 3];
    if (active) {
      float v0 = bf2f(xw[(size_t)c0.x * NC + lane]);
      float v1 = bf2f(xw[(size_t)c1.x * NC + lane]);
      float v2 = bf2f(xw[(size_t)c2.x * NC + lane]);
      float v3 = bf2f(xw[(size_t)c3.x * NC + lane]);
      acc = fmaf(v0, __int_as_float(c0.y), acc);
      acc = fmaf(v1, __int_as_float(c1.y), acc);
      acc = fmaf(v2, __int_as_float(c2.y), acc);
      acc = fmaf(v3, __int_as_float(c3.y), acc);
    }
  }
  for (; k < end; ++k) {
    int2 c = csr2[k];
    if (active) acc = fmaf(bf2f(xw[(size_t)c.x * NC + lane]), __int_as_float(c.y), acc);
  }
  // log_softmax over lanes 0..39
  float m = active ? acc : -3.0e38f;
  for (int off = 32; off >= 1; off >>= 1) m = fmaxf(m, __shfl_xor(m, off, 64));
  float e = active ? expf(acc - m) : 0.f;
  float ssum = e;
  for (int off = 32; off >= 1; off >>= 1) ssum += __shfl_xor(ssum, off, 64);
  if (active) out[(size_t)node * NC + lane] = acc - m - logf(ssum);
}

// ---------------------------------------------------------------------------

extern "C" void kernel_launch(void* const* d_in, const int* in_sizes, int n_in,
                              void* d_out, int out_size, void* d_ws, size_t ws_size,
                              hipStream_t stream) {
  const float* x  = (const float*)d_in[0];
  const int*   ei = (const int*)d_in[1];
  const float* W1 = (const float*)d_in[2];
  const float* b1 = (const float*)d_in[3];
  const float* W2 = (const float*)d_in[4];
  const float* b2 = (const float*)d_in[5];
  const float* W3 = (const float*)d_in[6];
  const float* b3 = (const float*)d_in[7];
  float* out = (float*)d_out;

  const int n = in_sizes[0] / HD;  // 50000
  const int E = in_sizes[1] / 2;   // 800000
  const int* src = ei;
  const int* dst = ei + E;

  // workspace carve (all 256B-aligned)
  char* ws = (char*)d_ws;
  size_t off = 0;
  auto carve = [&](size_t bytes) -> void* {
    void* p = ws + off;
    off += (bytes + 255) & ~(size_t)255;
    return p;
  };
  int*   cnt       = (int*)carve((size_t)n * 4);
  int*   row_start = (int*)carve((size_t)n * 4);
  int*   row_end   = (int*)carve((size_t)n * 4);
  float* dinv      = (float*)carve((size_t)n * 4);
  int2*  nodeinfo  = (int2*)carve((size_t)n * 8);
  int*   gtotal    = (int*)carve(256);
  unsigned short* w1t = (unsigned short*)carve((size_t)HD * HD * 2);
  unsigned short* w2t = (unsigned short*)carve((size_t)HD * HD * 2);
  int2*  csr2      = (int2*)carve((size_t)E * 8);
  signed char* xw8 = (signed char*)carve((size_t)n * HD);            // int8 xw
  float* xscale    = (float*)carve((size_t)n * 4);                   // row scales
  unsigned short* xw40 = (unsigned short*)carve((size_t)n * NC * 2); // bf16 xw3
  unsigned short* hb  = (unsigned short*)carve((size_t)n * HD * 2);  // bf16 h1
  float* bufB      = (float*)carve((size_t)n * HD * 4);              // h (f32)
  // rank[] is only live before the first agg writes bufB -> alias it.
  int*   rank      = (int*)bufB;

  const int gn   = (n + 255) / 256;
  const int gE1  = (E + 255) / 256;       // 1 edge per thread
  const int gE4  = (E + 1023) / 1024;     // 4 edges per thread
  const int gA   = (n + 15) / 16;         // 16 nodes per agg_f128 block
  const int gW   = (n + 3) / 4;           // one wave per node (agg_f40)
  const int gM   = (n + 63) / 64;         // 64 rows per mfma gemm block
  const int g40  = (n + 127) / 128;       // 128 rows per f40 gemm block

  // CSR build + weight prep
  k_init<<<gn, 256, 0, stream>>>(cnt, gtotal, n);
  k_wprep<<<2, 256, 0, stream>>>(W1, W2, w1t, w2t);
  k_count_rank<<<gE1, 256, 0, stream>>>(dst, cnt, rank, E);
  k_alloc<<<gn, 256, 0, stream>>>(cnt, row_start, row_end, nodeinfo, dinv, gtotal, n);
  k_fill<<<gE4, 256, 0, stream>>>(src, dst, rank, nodeinfo, dinv, csr2, E);

  // layer 1: xw = x@W1 -> xw8+xscale ; h1 = relu(agg)+x -> bufB (f32) + hb (bf16)
  gemm_mfma_f128<true><<<gM, 256, 0, stream>>>(x, (const unsigned short*)nullptr, w1t, xw8, xscale, n);
  agg_f128<<<gA, 256, 0, stream>>>(xw8, xscale, x, b1, dinv, row_start, row_end, csr2, bufB, hb, n);

  // layer 2: xw = h1@W2 -> xw8+xscale ; h2 = relu(agg)+h1 -> bufB (in-place resid OK)
  gemm_mfma_f128<false><<<gM, 256, 0, stream>>>((const float*)nullptr, hb, w2t, xw8, xscale, n);
  agg_f128<<<gA, 256, 0, stream>>>(xw8, xscale, bufB, b2, dinv, row_start, row_end, csr2, bufB,
                                   (unsigned short*)nullptr, n);

  // layer 3: xw = h2@W3 -> xw40(bf16) ; out = log_softmax(agg + b3)
  gemm_k128_f40<<<g40, 320, 0, stream>>>(bufB, W3, xw40, n);
  agg_f40_lsm<<<gW, 256, 0, stream>>>(xw40, dinv, row_start, row_end, csr2, b3, out, n);
}

// Round 9
// 186.368 us; speedup vs baseline: 3.2011x; 1.0957x over previous
//
#include <hip/hip_runtime.h>
#include <math.h>

// ---------------------------------------------------------------------------
// MultiGCN: 3-layer GCN, N=50000, E=800000, D=H=128, C=40.
// Round 9:
//  - k_count_rank: 8-way XCD-replicated counters (copy = blockIdx&7) to kill
//    cross-XCD atomic line ping-pong (round-7 PMC: 28MB WRITE for 3.2MB of
//    output). k_alloc sums copies and emits per-copy bases (cinfo); k_fill
//    derives copy = (e>>8)&7 from the edge id -- no extra loads.
//  - agg_f40_lsm re-laned: 4 nodes/wave, 16 lanes/node, lanes 0-9 gather
//    uint2 (4 bf16); log_softmax via 16-lane xor reduce.
// Everything else unchanged from round 8.
// ---------------------------------------------------------------------------

#define HD 128   // hidden / input feature dim
#define NC 40    // classes

typedef __attribute__((ext_vector_type(8))) short bfrag;   // 8 bf16 = 4 VGPR
typedef __attribute__((ext_vector_type(4))) float facc;    // 4 f32

__device__ __forceinline__ float4 fma4(float s, float4 w, float4 a) {
  a.x = fmaf(s, w.x, a.x);
  a.y = fmaf(s, w.y, a.y);
  a.z = fmaf(s, w.z, a.z);
  a.w = fmaf(s, w.w, a.w);
  return a;
}

// f32 -> bf16 round-to-nearest-even (finite values only)
__device__ __forceinline__ unsigned short f2bf(float f) {
  unsigned int u = __float_as_uint(f);
  u += 0x7FFFu + ((u >> 16) & 1u);
  return (unsigned short)(u >> 16);
}
__device__ __forceinline__ unsigned int packbf2(float a, float b) {
  return (unsigned int)f2bf(a) | ((unsigned int)f2bf(b) << 16);
}
__device__ __forceinline__ float bf2f(unsigned short v) {
  return __uint_as_float((unsigned int)v << 16);
}
__device__ __forceinline__ float2 bf2f2(unsigned int v) {
  float2 r;
  r.x = __uint_as_float(v << 16);
  r.y = __uint_as_float(v & 0xFFFF0000u);
  return r;
}
// signed byte i (0..3) of u, as float
__device__ __forceinline__ float db(unsigned int u, int i) {
  return (float)(signed char)((u >> (8 * i)) & 0xFFu);
}

#define NCOPY 8  // counter replicas (one per XCD)

// ---- CSR build ------------------------------------------------------------

__global__ void k_init(int* __restrict__ cnt8, int* __restrict__ gtotal, int n8) {
  int i = blockIdx.x * 256 + threadIdx.x;
  if (i < n8) cnt8[i] = 0;
  if (i == 0) *gtotal = 0;
}

// 1 edge/thread; atomics go to the blockIdx&7 replica (XCD-local heuristic)
__global__ __launch_bounds__(256) void k_count_rank(
    const int* __restrict__ dst, int* __restrict__ cnt8,
    int* __restrict__ rank, int E, int n) {
  int e = blockIdx.x * 256 + threadIdx.x;
  if (e < E) {
    int copy = blockIdx.x & (NCOPY - 1);
    rank[e] = atomicAdd(&cnt8[copy * n + dst[e]], 1);
  }
}

// sum 8 replicas, scan totals, emit per-copy bases (cinfo) + dinv
__global__ __launch_bounds__(256) void k_alloc(
    const int* __restrict__ cnt8, int* __restrict__ row_start,
    int* __restrict__ row_end, int2* __restrict__ cinfo,
    float* __restrict__ dinv, int* __restrict__ gtotal, int n) {
  __shared__ int sh[256];
  __shared__ int base_sh;
  const int tid = threadIdx.x;
  int i = blockIdx.x * 256 + tid;
  int c[NCOPY];
  int v = 0;
  if (i < n) {
#pragma unroll
    for (int j = 0; j < NCOPY; ++j) {
      c[j] = cnt8[j * n + i];
      v += c[j];
    }
  }
  sh[tid] = v;
  __syncthreads();
  for (int off = 1; off < 256; off <<= 1) {
    int t = (tid >= off) ? sh[tid - off] : 0;
    __syncthreads();
    sh[tid] += t;
    __syncthreads();
  }
  if (tid == 255) base_sh = atomicAdd(gtotal, sh[255]);
  __syncthreads();
  if (i < n) {
    int start = base_sh + sh[tid] - v;
    float dv = rsqrtf((float)(v + 1));  // +1 self loop
    row_start[i] = start;
    row_end[i] = start + v;
    dinv[i] = dv;
    int base = start;
#pragma unroll
    for (int j = 0; j < NCOPY; ++j) {
      cinfo[(size_t)j * n + i] = make_int2(base, __float_as_int(dv));
      base += c[j];
    }
  }
}

__global__ __launch_bounds__(256) void k_fill(
    const int* __restrict__ src, const int* __restrict__ dst,
    const int* __restrict__ rank, const int2* __restrict__ cinfo,
    const float* __restrict__ dinv, int2* __restrict__ csr2, int E, int n) {
  int t = blockIdx.x * 256 + threadIdx.x;
  int nt = gridDim.x * 256;
#pragma unroll
  for (int q = 0; q < 4; ++q) {
    int e = t + q * nt;
    if (e < E) {
      int d = dst[e];
      int s = src[e];
      int r = rank[e];
      int copy = (e >> 8) & (NCOPY - 1);   // = count kernel's blockIdx&7
      int2 ni = cinfo[(size_t)copy * n + d];
      float norm = dinv[s] * __int_as_float(ni.y);
      csr2[ni.x + r] = make_int2(s, __float_as_int(norm));
    }
  }
}

// ---- W prep: W (f32, K x N row-major) -> Wt (bf16, N x K row-major) -------

__global__ __launch_bounds__(256) void k_wprep(
    const float* __restrict__ W1, const float* __restrict__ W2,
    unsigned short* __restrict__ W1t, unsigned short* __restrict__ W2t) {
  const float* W = blockIdx.x ? W2 : W1;
  unsigned short* Wt = blockIdx.x ? W2t : W1t;
  __shared__ unsigned short sh[HD * 136];
#pragma unroll
  for (int i = 0; i < 16; ++i) {
    int f4 = i * 256 + threadIdx.x;     // float4 id 0..4095
    int r = f4 >> 5;                    // k row
    int c = (f4 & 31) * 4;              // n col
    float4 v = *(const float4*)(W + r * HD + c);
    sh[(c + 0) * 136 + r] = f2bf(v.x);
    sh[(c + 1) * 136 + r] = f2bf(v.y);
    sh[(c + 2) * 136 + r] = f2bf(v.z);
    sh[(c + 3) * 136 + r] = f2bf(v.w);
  }
  __syncthreads();
#pragma unroll
  for (int i = 0; i < 8; ++i) {
    int g = i * 256 + threadIdx.x;      // 16B chunk id 0..2047
    int nrow = g >> 4, k16 = g & 15;
    uint4 v = *(const uint4*)(&sh[nrow * 136 + k16 * 8]);
    *(uint4*)(Wt + (size_t)g * 8) = v;
  }
}

// ---- MFMA GEMM + int8 quant epilogue --------------------------------------

template <bool A_IS_F32>
__global__ __launch_bounds__(256) void gemm_mfma_f128(
    const float* __restrict__ Af, const unsigned short* __restrict__ Ab,
    const unsigned short* __restrict__ Wt,
    signed char* __restrict__ xw8, float* __restrict__ xscale, int n) {
  __shared__ unsigned short shWt[HD * 136];   // [n][k], pad 8 bf16/row
  {
#pragma unroll
    for (int i = 0; i < 8; ++i) {
      int g = i * 256 + threadIdx.x;          // 16B chunk 0..2047
      int nrow = g >> 4, k16 = g & 15;
      uint4 v = *(const uint4*)(Wt + (size_t)g * 8);
      *(uint4*)(&shWt[nrow * 136 + k16 * 8]) = v;
    }
  }

  const int lane = threadIdx.x & 63;
  const int w = threadIdx.x >> 6;             // wave 0..3
  const int m = blockIdx.x * 64 + w * 16 + (lane & 15);
  const int mc = min(m, n - 1);
  const int kbase = (lane >> 4) * 8;          // 0,8,16,24

  bfrag af[4];
  if constexpr (A_IS_F32) {
    const float* ap = Af + (size_t)mc * HD + kbase;
#pragma unroll
    for (int kk = 0; kk < 4; ++kk) {
      float4 lo = *(const float4*)(ap + kk * 32);
      float4 hi = *(const float4*)(ap + kk * 32 + 4);
      bfrag a;
      a[0] = (short)f2bf(lo.x); a[1] = (short)f2bf(lo.y);
      a[2] = (short)f2bf(lo.z); a[3] = (short)f2bf(lo.w);
      a[4] = (short)f2bf(hi.x); a[5] = (short)f2bf(hi.y);
      a[6] = (short)f2bf(hi.z); a[7] = (short)f2bf(hi.w);
      af[kk] = a;
    }
  } else {
    const unsigned short* ap = Ab + (size_t)mc * HD + kbase;
#pragma unroll
    for (int kk = 0; kk < 4; ++kk) af[kk] = *(const bfrag*)(ap + kk * 32);
  }

  __syncthreads();

  facc acc[8];
#pragma unroll
  for (int c = 0; c < 8; ++c) {
    acc[c][0] = 0.f; acc[c][1] = 0.f; acc[c][2] = 0.f; acc[c][3] = 0.f;
  }

#pragma unroll
  for (int kk = 0; kk < 4; ++kk) {
#pragma unroll
    for (int c = 0; c < 8; ++c) {
      bfrag bf = *(const bfrag*)(&shWt[(c * 16 + (lane & 15)) * 136 + kk * 32 + kbase]);
      acc[c] = __builtin_amdgcn_mfma_f32_16x16x32_bf16(af[kk], bf, acc[c], 0, 0, 0);
    }
  }

  // C layout: col = lane&15, row = (lane>>4)*4 + q (within each 16-row tile).
  float rmax[4];
#pragma unroll
  for (int q = 0; q < 4; ++q) {
    float mx = 0.f;
#pragma unroll
    for (int c = 0; c < 8; ++c) mx = fmaxf(mx, fabsf(acc[c][q]));
    rmax[q] = mx;
  }
#pragma unroll
  for (int off = 1; off < 16; off <<= 1) {
#pragma unroll
    for (int q = 0; q < 4; ++q) rmax[q] = fmaxf(rmax[q], __shfl_xor(rmax[q], off, 64));
  }

  const int rbase = blockIdx.x * 64 + w * 16 + (lane >> 4) * 4;
  const int col = lane & 15;
#pragma unroll
  for (int q = 0; q < 4; ++q) {
    int r = rbase + q;
    if (r < n) {
      float inv = (rmax[q] > 0.f) ? (127.f / rmax[q]) : 0.f;
      if (col == q) xscale[r] = rmax[q] * (1.f / 127.f);
#pragma unroll
      for (int c = 0; c < 8; ++c) {
        int v = __float2int_rn(acc[c][q] * inv);
        xw8[(size_t)r * HD + c * 16 + col] = (signed char)v;
      }
    }
  }
}

// ---- dense GEMM: out[n x 40](bf16) = A[n x 128](f32) @ W[128 x 40] --------

__global__ __launch_bounds__(320) void gemm_k128_f40(
    const float* __restrict__ A, const float* __restrict__ W,
    unsigned short* __restrict__ out, int n) {
  __shared__ float shW[HD * NC];
  {
    const float4* Wv = (const float4*)W;
    float4* shWv = (float4*)shW;
    for (int t = threadIdx.x; t < HD * NC / 4; t += 320) shWv[t] = Wv[t];
  }
  __syncthreads();

  const int cg = threadIdx.x % 10;
  const int rg = threadIdx.x / 10;             // 0..31
  const int jg = cg * 4;                       // col offset 0..36
  const int row0 = blockIdx.x * 128 + rg * 4;
  const int nm1 = n - 1;
  const float* a[4];
#pragma unroll
  for (int r = 0; r < 4; ++r) a[r] = A + (size_t)min(row0 + r, nm1) * HD;

  float4 acc[4];
#pragma unroll
  for (int r = 0; r < 4; ++r) acc[r] = make_float4(0.f, 0.f, 0.f, 0.f);

  for (int k = 0; k < HD; k += 4) {
    const float* wb = shW + k * NC + jg;
    float4 w0 = *(const float4*)(wb);
    float4 w1 = *(const float4*)(wb + NC);
    float4 w2 = *(const float4*)(wb + 2 * NC);
    float4 w3 = *(const float4*)(wb + 3 * NC);
#pragma unroll
    for (int r = 0; r < 4; ++r) {
      float4 xv = *(const float4*)(a[r] + k);
      acc[r] = fma4(xv.w, w3, fma4(xv.z, w2, fma4(xv.y, w1, fma4(xv.x, w0, acc[r]))));
    }
  }
#pragma unroll
  for (int r = 0; r < 4; ++r) {
    if (row0 + r < n) {
      uint2 p;
      p.x = packbf2(acc[r].x, acc[r].y);
      p.y = packbf2(acc[r].z, acc[r].w);
      *(uint2*)(out + (size_t)(row0 + r) * NC + jg) = p;
    }
  }
}

// ---- aggregation, F=128: 4 nodes/wave, 16 lanes/node, uint2 (8 int8)/lane --

__global__ __launch_bounds__(256) void agg_f128(
    const signed char* __restrict__ xw8, const float* __restrict__ xscale,
    const float* __restrict__ resid, const float* __restrict__ bias,
    const float* __restrict__ dinv,
    const int* __restrict__ row_start, const int* __restrict__ row_end,
    const int2* __restrict__ csr2, float* __restrict__ out,
    unsigned short* __restrict__ hb, int n) {
  const int node = (blockIdx.x * 256 + threadIdx.x) >> 4;  // 16 threads/node
  if (node >= n) return;
  const int li = threadIdx.x & 15;
  const int f0 = li * 8;

  float di = dinv[node];
  float4 b01 = *(const float4*)(bias + f0);
  float4 b23 = *(const float4*)(bias + f0 + 4);
  // self term
  uint2 su = *(const uint2*)(xw8 + (size_t)node * HD + f0);
  float ssc = xscale[node] * di * di;
  float a0 = fmaf(db(su.x, 0), ssc, b01.x);
  float a1 = fmaf(db(su.x, 1), ssc, b01.y);
  float a2 = fmaf(db(su.x, 2), ssc, b01.z);
  float a3 = fmaf(db(su.x, 3), ssc, b01.w);
  float a4 = fmaf(db(su.y, 0), ssc, b23.x);
  float a5 = fmaf(db(su.y, 1), ssc, b23.y);
  float a6 = fmaf(db(su.y, 2), ssc, b23.z);
  float a7 = fmaf(db(su.y, 3), ssc, b23.w);

  int k = row_start[node];
  const int end = row_end[node];
  for (; k + 4 <= end; k += 4) {
    int2 c0 = csr2[k], c1 = csr2[k + 1], c2 = csr2[k + 2], c3 = csr2[k + 3];
    uint2 u0 = *(const uint2*)(xw8 + (size_t)c0.x * HD + f0);
    uint2 u1 = *(const uint2*)(xw8 + (size_t)c1.x * HD + f0);
    uint2 u2 = *(const uint2*)(xw8 + (size_t)c2.x * HD + f0);
    uint2 u3 = *(const uint2*)(xw8 + (size_t)c3.x * HD + f0);
    float w0 = __int_as_float(c0.y) * xscale[c0.x];
    float w1 = __int_as_float(c1.y) * xscale[c1.x];
    float w2 = __int_as_float(c2.y) * xscale[c2.x];
    float w3 = __int_as_float(c3.y) * xscale[c3.x];
    a0 = fmaf(db(u0.x, 0), w0, a0); a1 = fmaf(db(u0.x, 1), w0, a1);
    a2 = fmaf(db(u0.x, 2), w0, a2); a3 = fmaf(db(u0.x, 3), w0, a3);
    a4 = fmaf(db(u0.y, 0), w0, a4); a5 = fmaf(db(u0.y, 1), w0, a5);
    a6 = fmaf(db(u0.y, 2), w0, a6); a7 = fmaf(db(u0.y, 3), w0, a7);
    a0 = fmaf(db(u1.x, 0), w1, a0); a1 = fmaf(db(u1.x, 1), w1, a1);
    a2 = fmaf(db(u1.x, 2), w1, a2); a3 = fmaf(db(u1.x, 3), w1, a3);
    a4 = fmaf(db(u1.y, 0), w1, a4); a5 = fmaf(db(u1.y, 1), w1, a5);
    a6 = fmaf(db(u1.y, 2), w1, a6); a7 = fmaf(db(u1.y, 3), w1, a7);
    a0 = fmaf(db(u2.x, 0), w2, a0); a1 = fmaf(db(u2.x, 1), w2, a1);
    a2 = fmaf(db(u2.x, 2), w2, a2); a3 = fmaf(db(u2.x, 3), w2, a3);
    a4 = fmaf(db(u2.y, 0), w2, a4); a5 = fmaf(db(u2.y, 1), w2, a5);
    a6 = fmaf(db(u2.y, 2), w2, a6); a7 = fmaf(db(u2.y, 3), w2, a7);
    a0 = fmaf(db(u3.x, 0), w3, a0); a1 = fmaf(db(u3.x, 1), w3, a1);
    a2 = fmaf(db(u3.x, 2), w3, a2); a3 = fmaf(db(u3.x, 3), w3, a3);
    a4 = fmaf(db(u3.y, 0), w3, a4); a5 = fmaf(db(u3.y, 1), w3, a5);
    a6 = fmaf(db(u3.y, 2), w3, a6); a7 = fmaf(db(u3.y, 3), w3, a7);
  }
  for (; k < end; ++k) {
    int2 c = csr2[k];
    uint2 u = *(const uint2*)(xw8 + (size_t)c.x * HD + f0);
    float w = __int_as_float(c.y) * xscale[c.x];
    a0 = fmaf(db(u.x, 0), w, a0); a1 = fmaf(db(u.x, 1), w, a1);
    a2 = fmaf(db(u.x, 2), w, a2); a3 = fmaf(db(u.x, 3), w, a3);
    a4 = fmaf(db(u.y, 0), w, a4); a5 = fmaf(db(u.y, 1), w, a5);
    a6 = fmaf(db(u.y, 2), w, a6); a7 = fmaf(db(u.y, 3), w, a7);
  }

  float4 r0 = *(const float4*)(resid + (size_t)node * HD + f0);
  float4 r1 = *(const float4*)(resid + (size_t)node * HD + f0 + 4);
  float4 o0, o1;
  o0.x = fmaxf(a0, 0.f) + r0.x; o0.y = fmaxf(a1, 0.f) + r0.y;
  o0.z = fmaxf(a2, 0.f) + r0.z; o0.w = fmaxf(a3, 0.f) + r0.w;
  o1.x = fmaxf(a4, 0.f) + r1.x; o1.y = fmaxf(a5, 0.f) + r1.y;
  o1.z = fmaxf(a6, 0.f) + r1.z; o1.w = fmaxf(a7, 0.f) + r1.w;
  *(float4*)(out + (size_t)node * HD + f0) = o0;
  *(float4*)(out + (size_t)node * HD + f0 + 4) = o1;
  if (hb) {
    uint4 hv;
    hv.x = packbf2(o0.x, o0.y);
    hv.y = packbf2(o0.z, o0.w);
    hv.z = packbf2(o1.x, o1.y);
    hv.w = packbf2(o1.z, o1.w);
    *(uint4*)(hb + (size_t)node * HD + f0) = hv;
  }
}

// ---- aggregation, F=40 + log_softmax: 4 nodes/wave, 16 lanes/node ---------
// lanes 0-9 of each 16-group hold 4 bf16 feats each (uint2 gathers).

__global__ __launch_bounds__(256) void agg_f40_lsm(
    const unsigned short* __restrict__ xw, const float* __restrict__ dinv,
    const int* __restrict__ row_start, const int* __restrict__ row_end,
    const int2* __restrict__ csr2, const float* __restrict__ bias,
    float* __restrict__ out, int n) {
  const int node = (blockIdx.x * 256 + threadIdx.x) >> 4;
  if (node >= n) return;
  const int li = threadIdx.x & 15;
  const bool act = li < 10;
  const int f0 = li * 4;                 // 0..36 for active lanes

  float a0 = 0.f, a1 = 0.f, a2 = 0.f, a3 = 0.f;
  float di = dinv[node];
  if (act) {
    float4 bv = *(const float4*)(bias + f0);
    uint2 su = *(const uint2*)(xw + (size_t)node * NC + f0);
    float2 s0 = bf2f2(su.x), s1 = bf2f2(su.y);
    float ssc = di * di;
    a0 = fmaf(s0.x, ssc, bv.x);
    a1 = fmaf(s0.y, ssc, bv.y);
    a2 = fmaf(s1.x, ssc, bv.z);
    a3 = fmaf(s1.y, ssc, bv.w);
  }

  int k = row_start[node];
  const int end = row_end[node];
  for (; k + 4 <= end; k += 4) {
    int2 c0 = csr2[k], c1 = csr2[k + 1], c2 = csr2[k + 2], c3 = csr2[k + 3];
    if (act) {
      uint2 u0 = *(const uint2*)(xw + (size_t)c0.x * NC + f0);
      uint2 u1 = *(const uint2*)(xw + (size_t)c1.x * NC + f0);
      uint2 u2 = *(const uint2*)(xw + (size_t)c2.x * NC + f0);
      uint2 u3 = *(const uint2*)(xw + (size_t)c3.x * NC + f0);
      float w0 = __int_as_float(c0.y), w1 = __int_as_float(c1.y);
      float w2 = __int_as_float(c2.y), w3 = __int_as_float(c3.y);
      float2 p, q;
      p = bf2f2(u0.x); q = bf2f2(u0.y);
      a0 = fmaf(p.x, w0, a0); a1 = fmaf(p.y, w0, a1);
      a2 = fmaf(q.x, w0, a2); a3 = fmaf(q.y, w0, a3);
      p = bf2f2(u1.x); q = bf2f2(u1.y);
      a0 = fmaf(p.x, w1, a0); a1 = fmaf(p.y, w1, a1);
      a2 = fmaf(q.x, w1, a2); a3 = fmaf(q.y, w1, a3);
      p = bf2f2(u2.x); q = bf2f2(u2.y);
      a0 = fmaf(p.x, w2, a0); a1 = fmaf(p.y, w2, a1);
      a2 = fmaf(q.x, w2, a2); a3 = fmaf(q.y, w2, a3);
      p = bf2f2(u3.x); q = bf2f2(u3.y);
      a0 = fmaf(p.x, w3, a0); a1 = fmaf(p.y, w3, a1);
      a2 = fmaf(q.x, w3, a2); a3 = fmaf(q.y, w3, a3);
    }
  }
  for (; k < end; ++k) {
    int2 c = csr2[k];
    if (act) {
      uint2 u = *(const uint2*)(xw + (size_t)c.x * NC + f0);
      float w = __int_as_float(c.y);
      float2 p = bf2f2(u.x), q = bf2f2(u.y);
      a0 = fmaf(p.x, w, a0); a1 = fmaf(p.y, w, a1);
      a2 = fmaf(q.x, w, a2); a3 = fmaf(q.y, w, a3);
    }
  }

  // log_softmax over the node's 40 values (10 lanes x 4), 16-lane xor reduce
  float m = act ? fmaxf(fmaxf(a0, a1), fmaxf(a2, a3)) : -3.0e38f;
  m = fmaxf(m, __shfl_xor(m, 1, 64));
  m = fmaxf(m, __shfl_xor(m, 2, 64));
  m = fmaxf(m, __shfl_xor(m, 4, 64));
  m = fmaxf(m, __shfl_xor(m, 8, 64));
  float s = act ? (expf(a0 - m) + expf(a1 - m) + expf(a2 - m) + expf(a3 - m)) : 0.f;
  s += __shfl_xor(s, 1, 64);
  s += __shfl_xor(s, 2, 64);
  s += __shfl_xor(s, 4, 64);
  s += __shfl_xor(s, 8, 64);
  if (act) {
    float lse = m + logf(s);
    float4 o;
    o.x = a0 - lse; o.y = a1 - lse; o.z = a2 - lse; o.w = a3 - lse;
    *(float4*)(out + (size_t)node * NC + f0) = o;
  }
}

// ---------------------------------------------------------------------------

extern "C" void kernel_launch(void* const* d_in, const int* in_sizes, int n_in,
                              void* d_out, int out_size, void* d_ws, size_t ws_size,
                              hipStream_t stream) {
  const float* x  = (const float*)d_in[0];
  const int*   ei = (const int*)d_in[1];
  const float* W1 = (const float*)d_in[2];
  const float* b1 = (const float*)d_in[3];
  const float* W2 = (const float*)d_in[4];
  const float* b2 = (const float*)d_in[5];
  const float* W3 = (const float*)d_in[6];
  const float* b3 = (const float*)d_in[7];
  float* out = (float*)d_out;

  const int n = in_sizes[0] / HD;  // 50000
  const int E = in_sizes[1] / 2;   // 800000
  const int* src = ei;
  const int* dst = ei + E;

  // workspace carve (all 256B-aligned)
  char* ws = (char*)d_ws;
  size_t off = 0;
  auto carve = [&](size_t bytes) -> void* {
    void* p = ws + off;
    off += (bytes + 255) & ~(size_t)255;
    return p;
  };
  int*   cnt8      = (int*)carve((size_t)n * NCOPY * 4);
  int*   row_start = (int*)carve((size_t)n * 4);
  int*   row_end   = (int*)carve((size_t)n * 4);
  float* dinv      = (float*)carve((size_t)n * 4);
  int2*  cinfo     = (int2*)carve((size_t)n * NCOPY * 8);
  int*   gtotal    = (int*)carve(256);
  unsigned short* w1t = (unsigned short*)carve((size_t)HD * HD * 2);
  unsigned short* w2t = (unsigned short*)carve((size_t)HD * HD * 2);
  int2*  csr2      = (int2*)carve((size_t)E * 8);
  signed char* xw8 = (signed char*)carve((size_t)n * HD);            // int8 xw
  float* xscale    = (float*)carve((size_t)n * 4);                   // row scales
  unsigned short* xw40 = (unsigned short*)carve((size_t)n * NC * 2); // bf16 xw3
  unsigned short* hb  = (unsigned short*)carve((size_t)n * HD * 2);  // bf16 h1
  float* bufB      = (float*)carve((size_t)n * HD * 4);              // h (f32)
  // rank[] is only live before the first agg writes bufB -> alias it.
  int*   rank      = (int*)bufB;

  const int gn8  = (n * NCOPY + 255) / 256;
  const int gE1  = (E + 255) / 256;       // 1 edge per thread
  const int gE4  = (E + 1023) / 1024;     // 4 edges per thread
  const int gA   = (n + 15) / 16;         // 16 nodes per agg block
  const int gM   = (n + 63) / 64;         // 64 rows per mfma gemm block
  const int g40  = (n + 127) / 128;       // 128 rows per f40 gemm block

  // CSR build + weight prep
  k_init<<<gn8, 256, 0, stream>>>(cnt8, gtotal, n * NCOPY);
  k_wprep<<<2, 256, 0, stream>>>(W1, W2, w1t, w2t);
  k_count_rank<<<gE1, 256, 0, stream>>>(dst, cnt8, rank, E, n);
  k_alloc<<<(n + 255) / 256, 256, 0, stream>>>(cnt8, row_start, row_end, cinfo, dinv, gtotal, n);
  k_fill<<<gE4, 256, 0, stream>>>(src, dst, rank, cinfo, dinv, csr2, E, n);

  // layer 1: xw = x@W1 -> xw8+xscale ; h1 = relu(agg)+x -> bufB (f32) + hb (bf16)
  gemm_mfma_f128<true><<<gM, 256, 0, stream>>>(x, (const unsigned short*)nullptr, w1t, xw8, xscale, n);
  agg_f128<<<gA, 256, 0, stream>>>(xw8, xscale, x, b1, dinv, row_start, row_end, csr2, bufB, hb, n);

  // layer 2: xw = h1@W2 -> xw8+xscale ; h2 = relu(agg)+h1 -> bufB (in-place resid OK)
  gemm_mfma_f128<false><<<gM, 256, 0, stream>>>((const float*)nullptr, hb, w2t, xw8, xscale, n);
  agg_f128<<<gA, 256, 0, stream>>>(xw8, xscale, bufB, b2, dinv, row_start, row_end, csr2, bufB,
                                   (unsigned short*)nullptr, n);

  // layer 3: xw = h2@W3 -> xw40(bf16) ; out = log_softmax(agg + b3)
  gemm_k128_f40<<<g40, 320, 0, stream>>>(bufB, W3, xw40, n);
  agg_f40_lsm<<<gA, 256, 0, stream>>>(xw40, dinv, row_start, row_end, csr2, b3, out, n);
}

// Round 10
// 168.217 us; speedup vs baseline: 3.5465x; 1.1079x over previous
//
#include <hip/hip_runtime.h>
#include <math.h>

// ---------------------------------------------------------------------------
// MultiGCN: 3-layer GCN, N=50000, E=800000, D=H=128, C=40.
// Round 10:
//  - layer-3 GEMM moved to MFMA (gemm_mfma_f40, 40 cols padded to 48; W3
//    prepped to bf16 [48][128] by k_wprep3). Input is hb (bf16 h2) -- agg-2
//    now writes ONLY hb (f32 h2 write was dead -> skipped, -25MB writes).
//  - k_fill: 1 edge/thread (3125 blocks; was 4-edge/782 at low occupancy --
//    same fix that won on k_count_rank in round 8).
// Everything else unchanged from round 9.
// ---------------------------------------------------------------------------

#define HD 128   // hidden / input feature dim
#define NC 40    // classes

typedef __attribute__((ext_vector_type(8))) short bfrag;   // 8 bf16 = 4 VGPR
typedef __attribute__((ext_vector_type(4))) float facc;    // 4 f32

// f32 -> bf16 round-to-nearest-even (finite values only)
__device__ __forceinline__ unsigned short f2bf(float f) {
  unsigned int u = __float_as_uint(f);
  u += 0x7FFFu + ((u >> 16) & 1u);
  return (unsigned short)(u >> 16);
}
__device__ __forceinline__ unsigned int packbf2(float a, float b) {
  return (unsigned int)f2bf(a) | ((unsigned int)f2bf(b) << 16);
}
__device__ __forceinline__ float2 bf2f2(unsigned int v) {
  float2 r;
  r.x = __uint_as_float(v << 16);
  r.y = __uint_as_float(v & 0xFFFF0000u);
  return r;
}
// signed byte i (0..3) of u, as float
__device__ __forceinline__ float db(unsigned int u, int i) {
  return (float)(signed char)((u >> (8 * i)) & 0xFFu);
}

#define NCOPY 8  // counter replicas (one per XCD)

// ---- CSR build ------------------------------------------------------------

__global__ void k_init(int* __restrict__ cnt8, int* __restrict__ gtotal, int n8) {
  int i = blockIdx.x * 256 + threadIdx.x;
  if (i < n8) cnt8[i] = 0;
  if (i == 0) *gtotal = 0;
}

// 1 edge/thread; atomics go to the blockIdx&7 replica (XCD-local heuristic)
__global__ __launch_bounds__(256) void k_count_rank(
    const int* __restrict__ dst, int* __restrict__ cnt8,
    int* __restrict__ rank, int E, int n) {
  int e = blockIdx.x * 256 + threadIdx.x;
  if (e < E) {
    int copy = blockIdx.x & (NCOPY - 1);
    rank[e] = atomicAdd(&cnt8[copy * n + dst[e]], 1);
  }
}

// sum 8 replicas, scan totals, emit per-copy bases (cinfo) + dinv
__global__ __launch_bounds__(256) void k_alloc(
    const int* __restrict__ cnt8, int* __restrict__ row_start,
    int* __restrict__ row_end, int2* __restrict__ cinfo,
    float* __restrict__ dinv, int* __restrict__ gtotal, int n) {
  __shared__ int sh[256];
  __shared__ int base_sh;
  const int tid = threadIdx.x;
  int i = blockIdx.x * 256 + tid;
  int c[NCOPY];
  int v = 0;
  if (i < n) {
#pragma unroll
    for (int j = 0; j < NCOPY; ++j) {
      c[j] = cnt8[j * n + i];
      v += c[j];
    }
  }
  sh[tid] = v;
  __syncthreads();
  for (int off = 1; off < 256; off <<= 1) {
    int t = (tid >= off) ? sh[tid - off] : 0;
    __syncthreads();
    sh[tid] += t;
    __syncthreads();
  }
  if (tid == 255) base_sh = atomicAdd(gtotal, sh[255]);
  __syncthreads();
  if (i < n) {
    int start = base_sh + sh[tid] - v;
    float dv = rsqrtf((float)(v + 1));  // +1 self loop
    row_start[i] = start;
    row_end[i] = start + v;
    dinv[i] = dv;
    int base = start;
#pragma unroll
    for (int j = 0; j < NCOPY; ++j) {
      cinfo[(size_t)j * n + i] = make_int2(base, __float_as_int(dv));
      base += c[j];
    }
  }
}

// fill: no atomics; 1 edge/thread; copy = (e>>8)&7 matches count's blockIdx&7
__global__ __launch_bounds__(256) void k_fill(
    const int* __restrict__ src, const int* __restrict__ dst,
    const int* __restrict__ rank, const int2* __restrict__ cinfo,
    const float* __restrict__ dinv, int2* __restrict__ csr2, int E, int n) {
  int e = blockIdx.x * 256 + threadIdx.x;
  if (e < E) {
    int d = dst[e];
    int s = src[e];
    int r = rank[e];
    int copy = (e >> 8) & (NCOPY - 1);
    int2 ni = cinfo[(size_t)copy * n + d];
    float norm = dinv[s] * __int_as_float(ni.y);
    csr2[ni.x + r] = make_int2(s, __float_as_int(norm));
  }
}

// ---- W prep: W (f32, K x N row-major) -> Wt (bf16, N x K row-major) -------

__global__ __launch_bounds__(256) void k_wprep(
    const float* __restrict__ W1, const float* __restrict__ W2,
    unsigned short* __restrict__ W1t, unsigned short* __restrict__ W2t) {
  const float* W = blockIdx.x ? W2 : W1;
  unsigned short* Wt = blockIdx.x ? W2t : W1t;
  __shared__ unsigned short sh[HD * 136];
#pragma unroll
  for (int i = 0; i < 16; ++i) {
    int f4 = i * 256 + threadIdx.x;     // float4 id 0..4095
    int r = f4 >> 5;                    // k row
    int c = (f4 & 31) * 4;              // n col
    float4 v = *(const float4*)(W + r * HD + c);
    sh[(c + 0) * 136 + r] = f2bf(v.x);
    sh[(c + 1) * 136 + r] = f2bf(v.y);
    sh[(c + 2) * 136 + r] = f2bf(v.z);
    sh[(c + 3) * 136 + r] = f2bf(v.w);
  }
  __syncthreads();
#pragma unroll
  for (int i = 0; i < 8; ++i) {
    int g = i * 256 + threadIdx.x;      // 16B chunk id 0..2047
    int nrow = g >> 4, k16 = g & 15;
    uint4 v = *(const uint4*)(&sh[nrow * 136 + k16 * 8]);
    *(uint4*)(Wt + (size_t)g * 8) = v;
  }
}

// W3 (f32 [128][40]) -> W3t (bf16 [48][128], rows 40..47 zero). 1 block.
__global__ __launch_bounds__(256) void k_wprep3(
    const float* __restrict__ W3, unsigned short* __restrict__ W3t) {
  __shared__ unsigned short sh[48 * 136];
  for (int i = threadIdx.x; i < 48 * 136; i += 256) sh[i] = 0;
  __syncthreads();
#pragma unroll
  for (int i = 0; i < 5; ++i) {
    int f4 = i * 256 + threadIdx.x;     // float4 id 0..1279
    if (f4 < 1280) {
      int r = f4 / 10;                  // k row 0..127
      int c = (f4 % 10) * 4;            // col 0..36
      float4 v = *(const float4*)(W3 + r * NC + c);
      sh[(c + 0) * 136 + r] = f2bf(v.x);
      sh[(c + 1) * 136 + r] = f2bf(v.y);
      sh[(c + 2) * 136 + r] = f2bf(v.z);
      sh[(c + 3) * 136 + r] = f2bf(v.w);
    }
  }
  __syncthreads();
#pragma unroll
  for (int i = 0; i < 3; ++i) {
    int g = i * 256 + threadIdx.x;      // 16B chunk id 0..767
    int nrow = g >> 4, k16 = g & 15;
    uint4 v = *(const uint4*)(&sh[nrow * 136 + k16 * 8]);
    *(uint4*)(W3t + (size_t)g * 8) = v;
  }
}

// ---- MFMA GEMM (128 cols) + int8 quant epilogue ---------------------------

template <bool A_IS_F32>
__global__ __launch_bounds__(256) void gemm_mfma_f128(
    const float* __restrict__ Af, const unsigned short* __restrict__ Ab,
    const unsigned short* __restrict__ Wt,
    signed char* __restrict__ xw8, float* __restrict__ xscale, int n) {
  __shared__ unsigned short shWt[HD * 136];   // [n][k], pad 8 bf16/row
  {
#pragma unroll
    for (int i = 0; i < 8; ++i) {
      int g = i * 256 + threadIdx.x;          // 16B chunk 0..2047
      int nrow = g >> 4, k16 = g & 15;
      uint4 v = *(const uint4*)(Wt + (size_t)g * 8);
      *(uint4*)(&shWt[nrow * 136 + k16 * 8]) = v;
    }
  }

  const int lane = threadIdx.x & 63;
  const int w = threadIdx.x >> 6;             // wave 0..3
  const int m = blockIdx.x * 64 + w * 16 + (lane & 15);
  const int mc = min(m, n - 1);
  const int kbase = (lane >> 4) * 8;          // 0,8,16,24

  bfrag af[4];
  if constexpr (A_IS_F32) {
    const float* ap = Af + (size_t)mc * HD + kbase;
#pragma unroll
    for (int kk = 0; kk < 4; ++kk) {
      float4 lo = *(const float4*)(ap + kk * 32);
      float4 hi = *(const float4*)(ap + kk * 32 + 4);
      bfrag a;
      a[0] = (short)f2bf(lo.x); a[1] = (short)f2bf(lo.y);
      a[2] = (short)f2bf(lo.z); a[3] = (short)f2bf(lo.w);
      a[4] = (short)f2bf(hi.x); a[5] = (short)f2bf(hi.y);
      a[6] = (short)f2bf(hi.z); a[7] = (short)f2bf(hi.w);
      af[kk] = a;
    }
  } else {
    const unsigned short* ap = Ab + (size_t)mc * HD + kbase;
#pragma unroll
    for (int kk = 0; kk < 4; ++kk) af[kk] = *(const bfrag*)(ap + kk * 32);
  }

  __syncthreads();

  facc acc[8];
#pragma unroll
  for (int c = 0; c < 8; ++c) {
    acc[c][0] = 0.f; acc[c][1] = 0.f; acc[c][2] = 0.f; acc[c][3] = 0.f;
  }

#pragma unroll
  for (int kk = 0; kk < 4; ++kk) {
#pragma unroll
    for (int c = 0; c < 8; ++c) {
      bfrag bf = *(const bfrag*)(&shWt[(c * 16 + (lane & 15)) * 136 + kk * 32 + kbase]);
      acc[c] = __builtin_amdgcn_mfma_f32_16x16x32_bf16(af[kk], bf, acc[c], 0, 0, 0);
    }
  }

  // C layout: col = lane&15, row = (lane>>4)*4 + q (within each 16-row tile).
  float rmax[4];
#pragma unroll
  for (int q = 0; q < 4; ++q) {
    float mx = 0.f;
#pragma unroll
    for (int c = 0; c < 8; ++c) mx = fmaxf(mx, fabsf(acc[c][q]));
    rmax[q] = mx;
  }
#pragma unroll
  for (int off = 1; off < 16; off <<= 1) {
#pragma unroll
    for (int q = 0; q < 4; ++q) rmax[q] = fmaxf(rmax[q], __shfl_xor(rmax[q], off, 64));
  }

  const int rbase = blockIdx.x * 64 + w * 16 + (lane >> 4) * 4;
  const int col = lane & 15;
#pragma unroll
  for (int q = 0; q < 4; ++q) {
    int r = rbase + q;
    if (r < n) {
      float inv = (rmax[q] > 0.f) ? (127.f / rmax[q]) : 0.f;
      if (col == q) xscale[r] = rmax[q] * (1.f / 127.f);
#pragma unroll
      for (int c = 0; c < 8; ++c) {
        int v = __float2int_rn(acc[c][q] * inv);
        xw8[(size_t)r * HD + c * 16 + col] = (signed char)v;
      }
    }
  }
}

// ---- MFMA GEMM (40 cols, padded 48): xw40(bf16) = hb @ W3t^T ---------------

__global__ __launch_bounds__(256) void gemm_mfma_f40(
    const unsigned short* __restrict__ Ab,   // bf16 h2 [n][128]
    const unsigned short* __restrict__ Wt,   // bf16 [48][128]
    unsigned short* __restrict__ out, int n) {
  __shared__ unsigned short shWt[48 * 136];
  {
#pragma unroll
    for (int i = 0; i < 3; ++i) {
      int g = i * 256 + threadIdx.x;          // 16B chunk 0..767
      int nrow = g >> 4, k16 = g & 15;
      uint4 v = *(const uint4*)(Wt + (size_t)g * 8);
      *(uint4*)(&shWt[nrow * 136 + k16 * 8]) = v;
    }
  }

  const int lane = threadIdx.x & 63;
  const int w = threadIdx.x >> 6;
  const int m = blockIdx.x * 64 + w * 16 + (lane & 15);
  const int mc = min(m, n - 1);
  const int kbase = (lane >> 4) * 8;

  bfrag af[4];
  const unsigned short* ap = Ab + (size_t)mc * HD + kbase;
#pragma unroll
  for (int kk = 0; kk < 4; ++kk) af[kk] = *(const bfrag*)(ap + kk * 32);

  __syncthreads();

  facc acc[3];
#pragma unroll
  for (int c = 0; c < 3; ++c) {
    acc[c][0] = 0.f; acc[c][1] = 0.f; acc[c][2] = 0.f; acc[c][3] = 0.f;
  }
#pragma unroll
  for (int kk = 0; kk < 4; ++kk) {
#pragma unroll
    for (int c = 0; c < 3; ++c) {
      bfrag bf = *(const bfrag*)(&shWt[(c * 16 + (lane & 15)) * 136 + kk * 32 + kbase]);
      acc[c] = __builtin_amdgcn_mfma_f32_16x16x32_bf16(af[kk], bf, acc[c], 0, 0, 0);
    }
  }

  const int rbase = blockIdx.x * 64 + w * 16 + (lane >> 4) * 4;
  const int col = lane & 15;
#pragma unroll
  for (int c = 0; c < 3; ++c) {
    int j = c * 16 + col;
    if (j < NC) {
#pragma unroll
      for (int q = 0; q < 4; ++q) {
        int r = rbase + q;
        if (r < n) out[(size_t)r * NC + j] = f2bf(acc[c][q]);
      }
    }
  }
}

// ---- aggregation, F=128: 4 nodes/wave, 16 lanes/node, uint2 (8 int8)/lane --

__global__ __launch_bounds__(256) void agg_f128(
    const signed char* __restrict__ xw8, const float* __restrict__ xscale,
    const float* __restrict__ resid, const float* __restrict__ bias,
    const float* __restrict__ dinv,
    const int* __restrict__ row_start, const int* __restrict__ row_end,
    const int2* __restrict__ csr2, float* __restrict__ out,
    unsigned short* __restrict__ hb, int n) {
  const int node = (blockIdx.x * 256 + threadIdx.x) >> 4;  // 16 threads/node
  if (node >= n) return;
  const int li = threadIdx.x & 15;
  const int f0 = li * 8;

  float di = dinv[node];
  float4 b01 = *(const float4*)(bias + f0);
  float4 b23 = *(const float4*)(bias + f0 + 4);
  // self term
  uint2 su = *(const uint2*)(xw8 + (size_t)node * HD + f0);
  float ssc = xscale[node] * di * di;
  float a0 = fmaf(db(su.x, 0), ssc, b01.x);
  float a1 = fmaf(db(su.x, 1), ssc, b01.y);
  float a2 = fmaf(db(su.x, 2), ssc, b01.z);
  float a3 = fmaf(db(su.x, 3), ssc, b01.w);
  float a4 = fmaf(db(su.y, 0), ssc, b23.x);
  float a5 = fmaf(db(su.y, 1), ssc, b23.y);
  float a6 = fmaf(db(su.y, 2), ssc, b23.z);
  float a7 = fmaf(db(su.y, 3), ssc, b23.w);

  int k = row_start[node];
  const int end = row_end[node];
  for (; k + 4 <= end; k += 4) {
    int2 c0 = csr2[k], c1 = csr2[k + 1], c2 = csr2[k + 2], c3 = csr2[k + 3];
    uint2 u0 = *(const uint2*)(xw8 + (size_t)c0.x * HD + f0);
    uint2 u1 = *(const uint2*)(xw8 + (size_t)c1.x * HD + f0);
    uint2 u2 = *(const uint2*)(xw8 + (size_t)c2.x * HD + f0);
    uint2 u3 = *(const uint2*)(xw8 + (size_t)c3.x * HD + f0);
    float w0 = __int_as_float(c0.y) * xscale[c0.x];
    float w1 = __int_as_float(c1.y) * xscale[c1.x];
    float w2 = __int_as_float(c2.y) * xscale[c2.x];
    float w3 = __int_as_float(c3.y) * xscale[c3.x];
    a0 = fmaf(db(u0.x, 0), w0, a0); a1 = fmaf(db(u0.x, 1), w0, a1);
    a2 = fmaf(db(u0.x, 2), w0, a2); a3 = fmaf(db(u0.x, 3), w0, a3);
    a4 = fmaf(db(u0.y, 0), w0, a4); a5 = fmaf(db(u0.y, 1), w0, a5);
    a6 = fmaf(db(u0.y, 2), w0, a6); a7 = fmaf(db(u0.y, 3), w0, a7);
    a0 = fmaf(db(u1.x, 0), w1, a0); a1 = fmaf(db(u1.x, 1), w1, a1);
    a2 = fmaf(db(u1.x, 2), w1, a2); a3 = fmaf(db(u1.x, 3), w1, a3);
    a4 = fmaf(db(u1.y, 0), w1, a4); a5 = fmaf(db(u1.y, 1), w1, a5);
    a6 = fmaf(db(u1.y, 2), w1, a6); a7 = fmaf(db(u1.y, 3), w1, a7);
    a0 = fmaf(db(u2.x, 0), w2, a0); a1 = fmaf(db(u2.x, 1), w2, a1);
    a2 = fmaf(db(u2.x, 2), w2, a2); a3 = fmaf(db(u2.x, 3), w2, a3);
    a4 = fmaf(db(u2.y, 0), w2, a4); a5 = fmaf(db(u2.y, 1), w2, a5);
    a6 = fmaf(db(u2.y, 2), w2, a6); a7 = fmaf(db(u2.y, 3), w2, a7);
    a0 = fmaf(db(u3.x, 0), w3, a0); a1 = fmaf(db(u3.x, 1), w3, a1);
    a2 = fmaf(db(u3.x, 2), w3, a2); a3 = fmaf(db(u3.x, 3), w3, a3);
    a4 = fmaf(db(u3.y, 0), w3, a4); a5 = fmaf(db(u3.y, 1), w3, a5);
    a6 = fmaf(db(u3.y, 2), w3, a6); a7 = fmaf(db(u3.y, 3), w3, a7);
  }
  for (; k < end; ++k) {
    int2 c = csr2[k];
    uint2 u = *(const uint2*)(xw8 + (size_t)c.x * HD + f0);
    float w = __int_as_float(c.y) * xscale[c.x];
    a0 = fmaf(db(u.x, 0), w, a0); a1 = fmaf(db(u.x, 1), w, a1);
    a2 = fmaf(db(u.x, 2), w, a2); a3 = fmaf(db(u.x, 3), w, a3);
    a4 = fmaf(db(u.y, 0), w, a4); a5 = fmaf(db(u.y, 1), w, a5);
    a6 = fmaf(db(u.y, 2), w, a6); a7 = fmaf(db(u.y, 3), w, a7);
  }

  float4 r0 = *(const float4*)(resid + (size_t)node * HD + f0);
  float4 r1 = *(const float4*)(resid + (size_t)node * HD + f0 + 4);
  float4 o0, o1;
  o0.x = fmaxf(a0, 0.f) + r0.x; o0.y = fmaxf(a1, 0.f) + r0.y;
  o0.z = fmaxf(a2, 0.f) + r0.z; o0.w = fmaxf(a3, 0.f) + r0.w;
  o1.x = fmaxf(a4, 0.f) + r1.x; o1.y = fmaxf(a5, 0.f) + r1.y;
  o1.z = fmaxf(a6, 0.f) + r1.z; o1.w = fmaxf(a7, 0.f) + r1.w;
  if (out) {
    *(float4*)(out + (size_t)node * HD + f0) = o0;
    *(float4*)(out + (size_t)node * HD + f0 + 4) = o1;
  }
  if (hb) {
    uint4 hv;
    hv.x = packbf2(o0.x, o0.y);
    hv.y = packbf2(o0.z, o0.w);
    hv.z = packbf2(o1.x, o1.y);
    hv.w = packbf2(o1.z, o1.w);
    *(uint4*)(hb + (size_t)node * HD + f0) = hv;
  }
}

// ---- aggregation, F=40 + log_softmax: 4 nodes/wave, 16 lanes/node ---------

__global__ __launch_bounds__(256) void agg_f40_lsm(
    const unsigned short* __restrict__ xw, const float* __restrict__ dinv,
    const int* __restrict__ row_start, const int* __restrict__ row_end,
    const int2* __restrict__ csr2, const float* __restrict__ bias,
    float* __restrict__ out, int n) {
  const int node = (blockIdx.x * 256 + threadIdx.x) >> 4;
  if (node >= n) return;
  const int li = threadIdx.x & 15;
  const bool act = li < 10;
  const int f0 = li * 4;                 // 0..36 for active lanes

  float a0 = 0.f, a1 = 0.f, a2 = 0.f, a3 = 0.f;
  float di = dinv[node];
  if (act) {
    float4 bv = *(const float4*)(bias + f0);
    uint2 su = *(const uint2*)(xw + (size_t)node * NC + f0);
    float2 s0 = bf2f2(su.x), s1 = bf2f2(su.y);
    float ssc = di * di;
    a0 = fmaf(s0.x, ssc, bv.x);
    a1 = fmaf(s0.y, ssc, bv.y);
    a2 = fmaf(s1.x, ssc, bv.z);
    a3 = fmaf(s1.y, ssc, bv.w);
  }

  int k = row_start[node];
  const int end = row_end[node];
  for (; k + 4 <= end; k += 4) {
    int2 c0 = csr2[k], c1 = csr2[k + 1], c2 = csr2[k + 2], c3 = csr2[k + 3];
    if (act) {
      uint2 u0 = *(const uint2*)(xw + (size_t)c0.x * NC + f0);
      uint2 u1 = *(const uint2*)(xw + (size_t)c1.x * NC + f0);
      uint2 u2 = *(const uint2*)(xw + (size_t)c2.x * NC + f0);
      uint2 u3 = *(const uint2*)(xw + (size_t)c3.x * NC + f0);
      float w0 = __int_as_float(c0.y), w1 = __int_as_float(c1.y);
      float w2 = __int_as_float(c2.y), w3 = __int_as_float(c3.y);
      float2 p, q;
      p = bf2f2(u0.x); q = bf2f2(u0.y);
      a0 = fmaf(p.x, w0, a0); a1 = fmaf(p.y, w0, a1);
      a2 = fmaf(q.x, w0, a2); a3 = fmaf(q.y, w0, a3);
      p = bf2f2(u1.x); q = bf2f2(u1.y);
      a0 = fmaf(p.x, w1, a0); a1 = fmaf(p.y, w1, a1);
      a2 = fmaf(q.x, w1, a2); a3 = fmaf(q.y, w1, a3);
      p = bf2f2(u2.x); q = bf2f2(u2.y);
      a0 = fmaf(p.x, w2, a0); a1 = fmaf(p.y, w2, a1);
      a2 = fmaf(q.x, w2, a2); a3 = fmaf(q.y, w2, a3);
      p = bf2f2(u3.x); q = bf2f2(u3.y);
      a0 = fmaf(p.x, w3, a0); a1 = fmaf(p.y, w3, a1);
      a2 = fmaf(q.x, w3, a2); a3 = fmaf(q.y, w3, a3);
    }
  }
  for (; k < end; ++k) {
    int2 c = csr2[k];
    if (act) {
      uint2 u = *(const uint2*)(xw + (size_t)c.x * NC + f0);
      float w = __int_as_float(c.y);
      float2 p = bf2f2(u.x), q = bf2f2(u.y);
      a0 = fmaf(p.x, w, a0); a1 = fmaf(p.y, w, a1);
      a2 = fmaf(q.x, w, a2); a3 = fmaf(q.y, w, a3);
    }
  }

  // log_softmax over the node's 40 values (10 lanes x 4), 16-lane xor reduce
  float m = act ? fmaxf(fmaxf(a0, a1), fmaxf(a2, a3)) : -3.0e38f;
  m = fmaxf(m, __shfl_xor(m, 1, 64));
  m = fmaxf(m, __shfl_xor(m, 2, 64));
  m = fmaxf(m, __shfl_xor(m, 4, 64));
  m = fmaxf(m, __shfl_xor(m, 8, 64));
  float s = act ? (expf(a0 - m) + expf(a1 - m) + expf(a2 - m) + expf(a3 - m)) : 0.f;
  s += __shfl_xor(s, 1, 64);
  s += __shfl_xor(s, 2, 64);
  s += __shfl_xor(s, 4, 64);
  s += __shfl_xor(s, 8, 64);
  if (act) {
    float lse = m + logf(s);
    float4 o;
    o.x = a0 - lse; o.y = a1 - lse; o.z = a2 - lse; o.w = a3 - lse;
    *(float4*)(out + (size_t)node * NC + f0) = o;
  }
}

// ---------------------------------------------------------------------------

extern "C" void kernel_launch(void* const* d_in, const int* in_sizes, int n_in,
                              void* d_out, int out_size, void* d_ws, size_t ws_size,
                              hipStream_t stream) {
  const float* x  = (const float*)d_in[0];
  const int*   ei = (const int*)d_in[1];
  const float* W1 = (const float*)d_in[2];
  const float* b1 = (const float*)d_in[3];
  const float* W2 = (const float*)d_in[4];
  const float* b2 = (const float*)d_in[5];
  const float* W3 = (const float*)d_in[6];
  const float* b3 = (const float*)d_in[7];
  float* out = (float*)d_out;

  const int n = in_sizes[0] / HD;  // 50000
  const int E = in_sizes[1] / 2;   // 800000
  const int* src = ei;
  const int* dst = ei + E;

  // workspace carve (all 256B-aligned)
  char* ws = (char*)d_ws;
  size_t off = 0;
  auto carve = [&](size_t bytes) -> void* {
    void* p = ws + off;
    off += (bytes + 255) & ~(size_t)255;
    return p;
  };
  int*   cnt8      = (int*)carve((size_t)n * NCOPY * 4);
  int*   row_start = (int*)carve((size_t)n * 4);
  int*   row_end   = (int*)carve((size_t)n * 4);
  float* dinv      = (float*)carve((size_t)n * 4);
  int2*  cinfo     = (int2*)carve((size_t)n * NCOPY * 8);
  int*   gtotal    = (int*)carve(256);
  unsigned short* w1t = (unsigned short*)carve((size_t)HD * HD * 2);
  unsigned short* w2t = (unsigned short*)carve((size_t)HD * HD * 2);
  unsigned short* w3t = (unsigned short*)carve((size_t)48 * HD * 2);
  int2*  csr2      = (int2*)carve((size_t)E * 8);
  signed char* xw8 = (signed char*)carve((size_t)n * HD);            // int8 xw
  float* xscale    = (float*)carve((size_t)n * 4);                   // row scales
  unsigned short* xw40 = (unsigned short*)carve((size_t)n * NC * 2); // bf16 xw3
  unsigned short* hb  = (unsigned short*)carve((size_t)n * HD * 2);  // bf16 h1/h2
  float* bufB      = (float*)carve((size_t)n * HD * 4);              // h1 (f32)
  // rank[] is only live before the first agg writes bufB -> alias it.
  int*   rank      = (int*)bufB;

  const int gn8  = (n * NCOPY + 255) / 256;
  const int gE1  = (E + 255) / 256;       // 1 edge per thread
  const int gA   = (n + 15) / 16;         // 16 nodes per agg block
  const int gM   = (n + 63) / 64;         // 64 rows per mfma gemm block

  // CSR build + weight prep
  k_init<<<gn8, 256, 0, stream>>>(cnt8, gtotal, n * NCOPY);
  k_wprep<<<2, 256, 0, stream>>>(W1, W2, w1t, w2t);
  k_wprep3<<<1, 256, 0, stream>>>(W3, w3t);
  k_count_rank<<<gE1, 256, 0, stream>>>(dst, cnt8, rank, E, n);
  k_alloc<<<(n + 255) / 256, 256, 0, stream>>>(cnt8, row_start, row_end, cinfo, dinv, gtotal, n);
  k_fill<<<gE1, 256, 0, stream>>>(src, dst, rank, cinfo, dinv, csr2, E, n);

  // layer 1: xw = x@W1 -> xw8+xscale ; h1 = relu(agg)+x -> bufB (f32) + hb (bf16)
  gemm_mfma_f128<true><<<gM, 256, 0, stream>>>(x, (const unsigned short*)nullptr, w1t, xw8, xscale, n);
  agg_f128<<<gA, 256, 0, stream>>>(xw8, xscale, x, b1, dinv, row_start, row_end, csr2, bufB, hb, n);

  // layer 2: xw = h1@W2 -> xw8+xscale ; h2 = relu(agg)+h1 -> hb (bf16 only)
  gemm_mfma_f128<false><<<gM, 256, 0, stream>>>((const float*)nullptr, hb, w2t, xw8, xscale, n);
  agg_f128<<<gA, 256, 0, stream>>>(xw8, xscale, bufB, b2, dinv, row_start, row_end, csr2,
                                   (float*)nullptr, hb, n);

  // layer 3: xw = h2@W3 -> xw40(bf16, MFMA) ; out = log_softmax(agg + b3)
  gemm_mfma_f40<<<gM, 256, 0, stream>>>(hb, w3t, xw40, n);
  agg_f40_lsm<<<gA, 256, 0, stream>>>(xw40, dinv, row_start, row_end, csr2, b3, out, n);
}